// Round 5
// baseline (580.253 us; speedup 1.0000x reference)
//
#include <hip/hip_runtime.h>

#define BATCH 4096
#define DDIM  512
#define HDIM  1024
#define GDIM  4096
#define FEWN  128

typedef unsigned short ushort_t;
typedef __attribute__((ext_vector_type(8))) short bf16x8;
typedef __attribute__((ext_vector_type(4))) float f32x4;

// round-to-nearest-even f32 -> bf16 (raw u16)
__device__ inline ushort_t f2bf(float f) {
  unsigned u = __float_as_uint(f);
  unsigned r = (u + 0x7FFFu + ((u >> 16) & 1u)) >> 16;
  return (ushort_t)r;
}
__device__ inline float bf2f(ushort_t h) { return __uint_as_float((unsigned)h << 16); }

__device__ inline float sigmoidf(float x) { return 1.f / (1.f + __expf(-x)); }
// stable tanh, no inf/inf
__device__ inline float tanh_fast(float x) {
  float ax = fabsf(x);
  float t = __expf(-2.f * ax);
  float r = (1.f - t) / (1.f + t);
  return copysignf(r, x);
}

__device__ inline void async_copy16(ushort_t* lds, const ushort_t* g) {
  __builtin_amdgcn_global_load_lds(
      (const __attribute__((address_space(1))) unsigned int*)g,
      (__attribute__((address_space(3))) unsigned int*)lds, 16, 0, 0);
}

// C[m][n] = A[m][k] * B[n][k]^T  (bf16 in, f32 accum), m97-style 128x128 tile, BK=32.
// EPI: 0 = acc+b1[col]+b2[col] -> Cf ; 1 = base[o]+acc -> Cf ; 2 = bf16(acc) -> Cb ; 3 = acc -> Cf
template<int EPI>
__launch_bounds__(256)
__global__ void gemm_bt(const ushort_t* __restrict__ A, const ushort_t* __restrict__ B,
                        float* __restrict__ Cf, ushort_t* __restrict__ Cb,
                        const float* __restrict__ base,
                        const float* __restrict__ b1, const float* __restrict__ b2,
                        int K, int lda, int ldb, int ldc) {
  __shared__ __align__(16) ushort_t lA[128 * 32];
  __shared__ __align__(16) ushort_t lB[128 * 32];
  const int tid = threadIdx.x;
  const int wid = tid >> 6, lane = tid & 63;
  const int wr = wid >> 1, wc = wid & 1;
  const int m0 = blockIdx.y * 128, n0 = blockIdx.x * 128;
  const int lr = lane & 15, kg = lane >> 4;

  f32x4 acc[4][4] = {};

  const int cA = wid * 2;
  const int srow = lane >> 2;
  const int scol = (lane & 3) * 8;
  const ushort_t* gA0 = A + (size_t)(m0 + cA * 16 + srow) * lda + scol;
  const ushort_t* gB0 = B + (size_t)(n0 + cA * 16 + srow) * ldb + scol;
  ushort_t* sA = &lA[cA * 512];
  ushort_t* sB = &lB[cA * 512];

  const int nIter = K >> 5;
  for (int kt = 0; kt < nIter; ++kt) {
    const int k0 = kt << 5;
    async_copy16(sA,       gA0 + k0);
    async_copy16(sA + 512, gA0 + (size_t)16 * lda + k0);
    async_copy16(sB,       gB0 + k0);
    async_copy16(sB + 512, gB0 + (size_t)16 * ldb + k0);
    __syncthreads();
    bf16x8 af[4], bfr[4];
#pragma unroll
    for (int mi = 0; mi < 4; ++mi)
      af[mi] = *(const bf16x8*)&lA[(wr * 64 + mi * 16 + lr) * 32 + kg * 8];
#pragma unroll
    for (int ni = 0; ni < 4; ++ni)
      bfr[ni] = *(const bf16x8*)&lB[(wc * 64 + ni * 16 + lr) * 32 + kg * 8];
#pragma unroll
    for (int mi = 0; mi < 4; ++mi)
#pragma unroll
      for (int ni = 0; ni < 4; ++ni)
        acc[mi][ni] = __builtin_amdgcn_mfma_f32_16x16x32_bf16(af[mi], bfr[ni], acc[mi][ni], 0, 0, 0);
    __syncthreads();
  }

#pragma unroll
  for (int mi = 0; mi < 4; ++mi) {
#pragma unroll
    for (int ni = 0; ni < 4; ++ni) {
#pragma unroll
      for (int r = 0; r < 4; ++r) {
        const int row = m0 + wr * 64 + mi * 16 + kg * 4 + r;
        const int col = n0 + wc * 64 + ni * 16 + lr;
        const float v = acc[mi][ni][r];
        const size_t o = (size_t)row * ldc + col;
        if (EPI == 0)      Cf[o] = v + b1[col] + b2[col];
        else if (EPI == 1) Cf[o] = base[o] + v;
        else if (EPI == 2) Cb[o] = f2bf(v);
        else               Cf[o] = v;
      }
    }
  }
}

// LSTM cell elementwise. MODE: 0=first (c_prev=0), 1=mid, 2=last (write f32 h to out only)
template<int MODE>
__global__ void cell_kernel(const float* __restrict__ gates,
                            const float* __restrict__ query,
                            float* __restrict__ c,
                            ushort_t* __restrict__ gatesA,   // [4096][1024], cols 0-511 = hr' hi
                            ushort_t* __restrict__ logitsA,  // [4096][1536] = [hi, lo, hi]
                            float* __restrict__ out) {
  const int idx = blockIdx.x * 256 + threadIdx.x;  // over BATCH*HDIM
  const int b = idx >> 10, j = idx & 1023;
  const float* g = gates + ((size_t)b << 12);
  const float si = sigmoidf(g[j]);
  const float sf = sigmoidf(g[j + 1024]);
  const float tg = tanh_fast(g[j + 2048]);
  const float so = sigmoidf(g[j + 3072]);
  const float cp = (MODE == 0) ? 0.f : c[idx];
  const float cn = sf * cp + si * tg;
  if (MODE != 2) c[idx] = cn;
  if (j < DDIM) {
    const float hr = so * tanh_fast(cn);  // |hr| < 1
    if (MODE == 2) {
      out[(size_t)b * DDIM + j] = query[(size_t)b * DDIM + j] + hr;
    } else {
      const ushort_t hi = f2bf(hr);
      const ushort_t lo = f2bf(hr - bf2f(hi));
      gatesA[((size_t)b << 10) + j] = hi;
      const size_t ro = (size_t)b * 1536;
      logitsA[ro + j] = hi;
      logitsA[ro + 512 + j] = lo;
      logitsA[ro + 1024 + j] = hi;
    }
  }
}

// one wave per row of 128 logits
__global__ void softmax_kernel(const float* __restrict__ logits, ushort_t* __restrict__ attn) {
  const int row = blockIdx.x * 4 + (threadIdx.x >> 6);
  const int lane = threadIdx.x & 63;
  const float* L = logits + (size_t)row * FEWN;
  const float x0 = L[lane], x1 = L[lane + 64];
  float m = fmaxf(x0, x1);
#pragma unroll
  for (int s = 32; s > 0; s >>= 1) m = fmaxf(m, __shfl_xor(m, s));
  const float e0 = __expf(x0 - m), e1 = __expf(x1 - m);
  float sum = e0 + e1;
#pragma unroll
  for (int s = 32; s > 0; s >>= 1) sum += __shfl_xor(sum, s);
  const float inv = 1.f / sum;
  attn[(size_t)row * FEWN + lane]      = f2bf(e0 * inv);
  attn[(size_t)row * FEWN + lane + 64] = f2bf(e1 * inv);
}

__global__ void cvt_bf16_kernel(const float* __restrict__ in, ushort_t* __restrict__ out, int n4) {
  const int i = blockIdx.x * 256 + threadIdx.x;
  if (i >= n4) return;
  const float4 v = ((const float4*)in)[i];
  const unsigned p0 = (unsigned)f2bf(v.x) | ((unsigned)f2bf(v.y) << 16);
  const unsigned p1 = (unsigned)f2bf(v.z) | ((unsigned)f2bf(v.w) << 16);
  uint2 o; o.x = p0; o.y = p1;
  ((uint2*)out)[i] = o;
}

// out[r][c] = out[r][c+512] = bf16(in[r*lda + c]), over 4096x512
__global__ void build_wdup(const float* __restrict__ in, ushort_t* __restrict__ out, int lda) {
  const int idx = blockIdx.x * 256 + threadIdx.x;
  const int r = idx >> 9, cc = idx & 511;
  const ushort_t v = f2bf(in[(size_t)r * lda + cc]);
  out[(size_t)r * 1024 + cc] = v;
  out[(size_t)r * 1024 + cc + 512] = v;
}

// Q_cat [4096][1536] = [q_hi, q_lo, q_hi]
__global__ void build_qcat(const float* __restrict__ q, ushort_t* __restrict__ out) {
  const int idx = blockIdx.x * 256 + threadIdx.x;  // 4096*512
  const int b = idx >> 9, cc = idx & 511;
  const float v = q[idx];
  const ushort_t hi = f2bf(v);
  const ushort_t lo = f2bf(v - bf2f(hi));
  const size_t ro = (size_t)b * 1536;
  out[ro + cc] = hi;
  out[ro + 512 + cc] = lo;
  out[ro + 1024 + cc] = hi;
}

// B_cat [128][1536] = [s_hi, s_hi, s_lo]
__global__ void build_bcat(const float* __restrict__ s, ushort_t* __restrict__ out) {
  const int idx = blockIdx.x * 256 + threadIdx.x;  // 128*512
  const int n = idx >> 9, cc = idx & 511;
  const float v = s[idx];
  const ushort_t hi = f2bf(v);
  const ushort_t lo = f2bf(v - bf2f(hi));
  const size_t ro = (size_t)n * 1536;
  out[ro + cc] = hi;
  out[ro + 512 + cc] = hi;
  out[ro + 1024 + cc] = lo;
}

// support [128][512] f32 -> supT [512][128] bf16
__global__ void transp_kernel(const float* __restrict__ in, ushort_t* __restrict__ outT) {
  const int idx = blockIdx.x * 256 + threadIdx.x;  // 65536
  const int r = idx >> 9, colv = idx & 511;
  outT[colv * FEWN + r] = f2bf(in[idx]);
}

extern "C" void kernel_launch(void* const* d_in, const int* in_sizes, int n_in,
                              void* d_out, int out_size, void* d_ws, size_t ws_size,
                              hipStream_t stream) {
  const float* support = (const float*)d_in[0];
  const float* query   = (const float*)d_in[1];
  const float* W_ih    = (const float*)d_in[2];
  const float* W_hh    = (const float*)d_in[3];
  const float* b_ih    = (const float*)d_in[4];
  const float* b_hh    = (const float*)d_in[5];
  float* out = (float*)d_out;

  char* ws = (char*)d_ws;
  size_t off = 0;
  auto alloc = [&](size_t bytes) { char* p = ws + off; off += (bytes + 255) & ~255ull; return p; };
  float*    gates_base = (float*)   alloc((size_t)BATCH * GDIM * 4);   // 64MB
  float*    gates      = (float*)   alloc((size_t)BATCH * GDIM * 4);   // 64MB
  float*    cbuf       = (float*)   alloc((size_t)BATCH * HDIM * 4);   // 16MB
  ushort_t* gatesA     = (ushort_t*)alloc((size_t)BATCH * HDIM * 2);   // 8MB  [hr' | r]
  ushort_t* logitsA    = (ushort_t*)alloc((size_t)BATCH * 1536 * 2);   // 12MB [hi,lo,hi]
  ushort_t* Q_cat      = (ushort_t*)alloc((size_t)BATCH * 1536 * 2);   // 12MB
  ushort_t* wih_dup    = (ushort_t*)alloc((size_t)GDIM * 1024 * 2);    // 8MB  [W_ih|W_ih]
  ushort_t* whhL_dup   = (ushort_t*)alloc((size_t)GDIM * 1024 * 2);    // 8MB  [W_hh[:,:512]|same]
  ushort_t* whh_bf     = (ushort_t*)alloc((size_t)GDIM * HDIM * 2);    // 8MB
  ushort_t* B_cat      = (ushort_t*)alloc((size_t)FEWN * 1536 * 2);    // 0.4MB
  ushort_t* supT_bf    = (ushort_t*)alloc((size_t)DDIM * FEWN * 2);    // 0.13MB
  float*    logits_base= (float*)   alloc((size_t)BATCH * FEWN * 4);   // 2MB
  float*    logits     = (float*)   alloc((size_t)BATCH * FEWN * 4);   // 2MB
  ushort_t* attn       = (ushort_t*)alloc((size_t)BATCH * FEWN * 2);   // 1MB

  const dim3 blk(256);

  // ---- setup ----
  build_wdup<<<GDIM * 512 / 256, blk, 0, stream>>>(W_ih, wih_dup, DDIM);
  build_wdup<<<GDIM * 512 / 256, blk, 0, stream>>>(W_hh, whhL_dup, HDIM);  // cols 0..511
  cvt_bf16_kernel<<<GDIM * HDIM / 4 / 256, blk, 0, stream>>>(W_hh, whh_bf, GDIM * HDIM / 4);
  build_qcat<<<BATCH * 512 / 256, blk, 0, stream>>>(query, Q_cat);
  build_bcat<<<FEWN * 512 / 256, blk, 0, stream>>>(support, B_cat);
  transp_kernel<<<FEWN * DDIM / 256, blk, 0, stream>>>(support, supT_bf);

  // base0 (= step-0 gates) = [q_hi,q_lo] @ [W_ih|W_ih]^T + b_ih + b_hh   -> `gates`
  gemm_bt<0><<<dim3(GDIM / 128, BATCH / 128), blk, 0, stream>>>(
      Q_cat, wih_dup, gates, nullptr, nullptr, b_ih, b_hh, 1024, 1536, 1024, GDIM);
  // gates_base = base0 + [q_hi,q_lo] @ [W_hhL|W_hhL]^T
  gemm_bt<1><<<dim3(GDIM / 128, BATCH / 128), blk, 0, stream>>>(
      Q_cat, whhL_dup, gates_base, nullptr, gates, nullptr, nullptr, 1024, 1536, 1024, GDIM);
  // logits_base = Q_cat @ B_cat^T  (= q@s^T in split precision)
  gemm_bt<3><<<dim3(FEWN / 128, BATCH / 128), blk, 0, stream>>>(
      Q_cat, B_cat, logits_base, nullptr, nullptr, nullptr, nullptr, 1536, 1536, 1536, FEWN);

  auto attn_phase = [&]() {
    // logits = logits_base + [hi,lo,hi] @ [s_hi,s_hi,s_lo]^T
    gemm_bt<1><<<dim3(FEWN / 128, BATCH / 128), blk, 0, stream>>>(
        logitsA, B_cat, logits, nullptr, logits_base, nullptr, nullptr, 1536, 1536, 1536, FEWN);
    softmax_kernel<<<BATCH / 4, blk, 0, stream>>>(logits, attn);
    // r = attn @ support -> bf16 into gatesA[:, 512:]
    gemm_bt<2><<<dim3(DDIM / 128, BATCH / 128), blk, 0, stream>>>(
        attn, supT_bf, nullptr, gatesA + DDIM, nullptr, nullptr, nullptr, FEWN, FEWN, FEWN, HDIM);
  };

  // step 0: gates = base0 (in `gates`)
  cell_kernel<0><<<BATCH * HDIM / 256, blk, 0, stream>>>(gates, query, cbuf, gatesA, logitsA, nullptr);
  attn_phase();

  // steps 1,2
  for (int s = 1; s <= 2; ++s) {
    gemm_bt<1><<<dim3(GDIM / 128, BATCH / 128), blk, 0, stream>>>(
        gatesA, whh_bf, gates, nullptr, gates_base, nullptr, nullptr, HDIM, HDIM, HDIM, GDIM);
    cell_kernel<1><<<BATCH * HDIM / 256, blk, 0, stream>>>(gates, query, cbuf, gatesA, logitsA, nullptr);
    attn_phase();
  }

  // step 3 (last): no attention; write h straight to out
  gemm_bt<1><<<dim3(GDIM / 128, BATCH / 128), blk, 0, stream>>>(
      gatesA, whh_bf, gates, nullptr, gates_base, nullptr, nullptr, HDIM, HDIM, HDIM, GDIM);
  cell_kernel<2><<<BATCH * HDIM / 256, blk, 0, stream>>>(gates, query, cbuf, nullptr, nullptr, out);
}

// Round 6
// 520.839 us; speedup vs baseline: 1.1141x; 1.1141x over previous
//
#include <hip/hip_runtime.h>

#define BATCH 4096
#define DDIM  512
#define HDIM  1024
#define GDIM  4096
#define FEWN  128

typedef unsigned short ushort_t;
typedef __attribute__((ext_vector_type(8))) short bf16x8;
typedef __attribute__((ext_vector_type(4))) float f32x4;

// round-to-nearest-even f32 -> bf16 (raw u16)
__device__ inline ushort_t f2bf(float f) {
  unsigned u = __float_as_uint(f);
  unsigned r = (u + 0x7FFFu + ((u >> 16) & 1u)) >> 16;
  return (ushort_t)r;
}
__device__ inline float bf2f(ushort_t h) { return __uint_as_float((unsigned)h << 16); }

__device__ inline float sigmoidf(float x) { return 1.f / (1.f + __expf(-x)); }
__device__ inline float tanh_fast(float x) {
  float ax = fabsf(x);
  float t = __expf(-2.f * ax);
  float r = (1.f - t) / (1.f + t);
  return copysignf(r, x);
}

// permuted gate layout: col' -> original W row
__device__ inline int orig_row(int colp) {
  return ((colp >> 4) & 3) * 1024 + ((colp >> 6) << 4) + (colp & 15);
}

__device__ inline void async_copy16(ushort_t* lds, const ushort_t* g) {
  __builtin_amdgcn_global_load_lds(
      (const __attribute__((address_space(1))) unsigned int*)g,
      (__attribute__((address_space(3))) unsigned int*)lds, 16, 0, 0);
}

// ---- shared K-loop macro body (m97 structure, 128x128 tile, BK=32) ----
#define GEMM_PROLOG()                                                        \
  __shared__ __align__(16) ushort_t lA[128 * 32];                            \
  __shared__ __align__(16) ushort_t lB[128 * 32];                            \
  const int tid = threadIdx.x;                                               \
  const int wid = tid >> 6, lane = tid & 63;                                 \
  const int wr = wid >> 1, wc = wid & 1;                                     \
  const int m0 = blockIdx.y * 128, n0 = blockIdx.x * 128;                    \
  const int lr = lane & 15, kg = lane >> 4;                                  \
  f32x4 acc[4][4] = {};                                                      \
  const int cA = wid * 2;                                                    \
  const int srow = lane >> 2;                                                \
  const int scol = (lane & 3) * 8;                                           \
  const ushort_t* gA0 = A + (size_t)(m0 + cA * 16 + srow) * lda + scol;      \
  const ushort_t* gB0 = B + (size_t)(n0 + cA * 16 + srow) * ldb + scol;      \
  ushort_t* sA = &lA[cA * 512];                                              \
  ushort_t* sB = &lB[cA * 512];                                              \
  const int nIter = K >> 5;                                                  \
  for (int kt = 0; kt < nIter; ++kt) {                                       \
    const int k0 = kt << 5;                                                  \
    async_copy16(sA,       gA0 + k0);                                        \
    async_copy16(sA + 512, gA0 + (size_t)16 * lda + k0);                     \
    async_copy16(sB,       gB0 + k0);                                        \
    async_copy16(sB + 512, gB0 + (size_t)16 * ldb + k0);                     \
    __syncthreads();                                                         \
    bf16x8 af[4], bfr[4];                                                    \
    _Pragma("unroll")                                                        \
    for (int mi = 0; mi < 4; ++mi)                                           \
      af[mi] = *(const bf16x8*)&lA[(wr * 64 + mi * 16 + lr) * 32 + kg * 8];  \
    _Pragma("unroll")                                                        \
    for (int ni = 0; ni < 4; ++ni)                                           \
      bfr[ni] = *(const bf16x8*)&lB[(wc * 64 + ni * 16 + lr) * 32 + kg * 8]; \
    _Pragma("unroll")                                                        \
    for (int mi = 0; mi < 4; ++mi)                                           \
      _Pragma("unroll")                                                      \
      for (int ni = 0; ni < 4; ++ni)                                         \
        acc[mi][ni] = __builtin_amdgcn_mfma_f32_16x16x32_bf16(af[mi], bfr[ni], acc[mi][ni], 0, 0, 0); \
    __syncthreads();                                                         \
  }

// G1: base0P = Qcat(hi,lo) @ wihP^T + bias (permuted cols), f32 out
__launch_bounds__(256)
__global__ void gemm_bias(const ushort_t* __restrict__ A, const ushort_t* __restrict__ B,
                          float* __restrict__ Cf,
                          const float* __restrict__ b1, const float* __restrict__ b2,
                          int K, int lda, int ldb) {
  GEMM_PROLOG()
#pragma unroll
  for (int mi = 0; mi < 4; ++mi)
#pragma unroll
    for (int ni = 0; ni < 4; ++ni)
#pragma unroll
      for (int r = 0; r < 4; ++r) {
        const int row = m0 + wr * 64 + mi * 16 + kg * 4 + r;
        const int col = n0 + wc * 64 + ni * 16 + lr;
        const int og = orig_row(col);
        Cf[(size_t)row * GDIM + col] = acc[mi][ni][r] + b1[og] + b2[og];
      }
}

// Fused GEMM + LSTM cell. Permuted layout: gate g of j lives in ni-register g.
// MODE 0: cell on base[] (step0 gates), write baseout = base+acc (gates_base)
// MODE 1: cell on base+acc (mid steps)
// MODE 2: cell on base+acc, write out = query + hr (grid.x halved: col'<2048)
template<int MODE>
__launch_bounds__(256)
__global__ void gemm_fused(const ushort_t* __restrict__ A, const ushort_t* __restrict__ B,
                           const float* __restrict__ base, float* __restrict__ baseout,
                           float* __restrict__ c,
                           ushort_t* __restrict__ gatesO,   // [4096][1024] hr' hi (cols 0-511)
                           ushort_t* __restrict__ logitsO,  // [4096][1536] = [hi,lo,hi]
                           const float* __restrict__ query, float* __restrict__ out,
                           int K, int lda, int ldb) {
  GEMM_PROLOG()
  const int jj = ((n0 + wc * 64) >> 6) * 16 + lr;          // j in 0..1023
  const bool do_h = (MODE == 2) || ((n0 + wc * 64) < 2048);  // j < 512
#pragma unroll
  for (int mi = 0; mi < 4; ++mi) {
#pragma unroll
    for (int r = 0; r < 4; ++r) {
      const int row = m0 + wr * 64 + mi * 16 + kg * 4 + r;
      const size_t o0 = (size_t)row * GDIM + n0 + wc * 64 + lr;
      float g0 = base[o0], g1 = base[o0 + 16], g2 = base[o0 + 32], g3 = base[o0 + 48];
      if (MODE == 0) {
        baseout[o0]      = g0 + acc[mi][0][r];
        baseout[o0 + 16] = g1 + acc[mi][1][r];
        baseout[o0 + 32] = g2 + acc[mi][2][r];
        baseout[o0 + 48] = g3 + acc[mi][3][r];
      } else {
        g0 += acc[mi][0][r]; g1 += acc[mi][1][r];
        g2 += acc[mi][2][r]; g3 += acc[mi][3][r];
      }
      const float si = sigmoidf(g0);
      const float sf = sigmoidf(g1);
      const float tg = tanh_fast(g2);
      const float so = sigmoidf(g3);
      const size_t ci = (size_t)row * HDIM + jj;
      const float cp = (MODE == 0) ? 0.f : c[ci];
      const float cn = sf * cp + si * tg;
      if (MODE != 2) c[ci] = cn;
      if (do_h) {
        const float hr = so * tanh_fast(cn);  // |hr| < 1
        if (MODE == 2) {
          out[(size_t)row * DDIM + jj] = query[(size_t)row * DDIM + jj] + hr;
        } else {
          const ushort_t hi = f2bf(hr);
          const ushort_t lo = f2bf(hr - bf2f(hi));
          gatesO[(size_t)row * HDIM + jj] = hi;
          const size_t ro = (size_t)row * 1536;
          logitsO[ro + jj] = hi;
          logitsO[ro + 512 + jj] = lo;
          logitsO[ro + 1024 + jj] = hi;
        }
      }
    }
  }
}

// plain GEMM for logits / r  (EPI: 1 = base+acc -> Cf ; 2 = bf16(acc) -> Cb ; 3 = acc -> Cf)
template<int EPI>
__launch_bounds__(256)
__global__ void gemm_bt(const ushort_t* __restrict__ A, const ushort_t* __restrict__ B,
                        float* __restrict__ Cf, ushort_t* __restrict__ Cb,
                        const float* __restrict__ base,
                        int K, int lda, int ldb, int ldc) {
  GEMM_PROLOG()
#pragma unroll
  for (int mi = 0; mi < 4; ++mi)
#pragma unroll
    for (int ni = 0; ni < 4; ++ni)
#pragma unroll
      for (int r = 0; r < 4; ++r) {
        const int row = m0 + wr * 64 + mi * 16 + kg * 4 + r;
        const int col = n0 + wc * 64 + ni * 16 + lr;
        const float v = acc[mi][ni][r];
        const size_t o = (size_t)row * ldc + col;
        if (EPI == 1)      Cf[o] = base[o] + v;
        else if (EPI == 2) Cb[o] = f2bf(v);
        else               Cf[o] = v;
      }
}

// one wave per row of 128 logits
__global__ void softmax_kernel(const float* __restrict__ logits, ushort_t* __restrict__ attn) {
  const int row = blockIdx.x * 4 + (threadIdx.x >> 6);
  const int lane = threadIdx.x & 63;
  const float* L = logits + (size_t)row * FEWN;
  const float x0 = L[lane], x1 = L[lane + 64];
  float m = fmaxf(x0, x1);
#pragma unroll
  for (int s = 32; s > 0; s >>= 1) m = fmaxf(m, __shfl_xor(m, s));
  const float e0 = __expf(x0 - m), e1 = __expf(x1 - m);
  float sum = e0 + e1;
#pragma unroll
  for (int s = 32; s > 0; s >>= 1) sum += __shfl_xor(sum, s);
  const float inv = 1.f / sum;
  attn[(size_t)row * FEWN + lane]      = f2bf(e0 * inv);
  attn[(size_t)row * FEWN + lane + 64] = f2bf(e1 * inv);
}

// wP[r][c] = wP[r][c+512] = bf16(W[orig(r)][c]), r over 4096, c over 512
__global__ void build_wP_dup(const float* __restrict__ W, ushort_t* __restrict__ out, int lda) {
  const int idx = blockIdx.x * 256 + threadIdx.x;  // 4096*512
  const int r = idx >> 9, cc = idx & 511;
  const ushort_t v = f2bf(W[(size_t)orig_row(r) * lda + cc]);
  out[(size_t)r * 1024 + cc] = v;
  out[(size_t)r * 1024 + cc + 512] = v;
}

// whhP[r][k] = bf16(W_hh[orig(r)][k]), full K=1024
__global__ void build_whhP(const float* __restrict__ W, ushort_t* __restrict__ out) {
  const int idx = blockIdx.x * 256 + threadIdx.x;  // 4096*1024
  const int r = idx >> 10, k = idx & 1023;
  out[idx] = f2bf(W[(size_t)orig_row(r) * 1024 + k]);
}

// Q_cat [4096][1536] = [q_hi, q_lo, q_hi]
__global__ void build_qcat(const float* __restrict__ q, ushort_t* __restrict__ out) {
  const int idx = blockIdx.x * 256 + threadIdx.x;  // 4096*512
  const int b = idx >> 9, cc = idx & 511;
  const float v = q[idx];
  const ushort_t hi = f2bf(v);
  const ushort_t lo = f2bf(v - bf2f(hi));
  const size_t ro = (size_t)b * 1536;
  out[ro + cc] = hi;
  out[ro + 512 + cc] = lo;
  out[ro + 1024 + cc] = hi;
}

// B_cat [128][1536] = [s_hi, s_hi, s_lo]
__global__ void build_bcat(const float* __restrict__ s, ushort_t* __restrict__ out) {
  const int idx = blockIdx.x * 256 + threadIdx.x;  // 128*512
  const int n = idx >> 9, cc = idx & 511;
  const float v = s[idx];
  const ushort_t hi = f2bf(v);
  const ushort_t lo = f2bf(v - bf2f(hi));
  const size_t ro = (size_t)n * 1536;
  out[ro + cc] = hi;
  out[ro + 512 + cc] = hi;
  out[ro + 1024 + cc] = lo;
}

// support [128][512] f32 -> supT [512][128] bf16
__global__ void transp_kernel(const float* __restrict__ in, ushort_t* __restrict__ outT) {
  const int idx = blockIdx.x * 256 + threadIdx.x;  // 65536
  const int r = idx >> 9, colv = idx & 511;
  outT[colv * FEWN + r] = f2bf(in[idx]);
}

extern "C" void kernel_launch(void* const* d_in, const int* in_sizes, int n_in,
                              void* d_out, int out_size, void* d_ws, size_t ws_size,
                              hipStream_t stream) {
  const float* support = (const float*)d_in[0];
  const float* query   = (const float*)d_in[1];
  const float* W_ih    = (const float*)d_in[2];
  const float* W_hh    = (const float*)d_in[3];
  const float* b_ih    = (const float*)d_in[4];
  const float* b_hh    = (const float*)d_in[5];
  float* out = (float*)d_out;

  char* ws = (char*)d_ws;
  size_t off = 0;
  auto alloc = [&](size_t bytes) { char* p = ws + off; off += (bytes + 255) & ~255ull; return p; };
  float*    gates_baseP = (float*)   alloc((size_t)BATCH * GDIM * 4);   // 64MB (permuted cols)
  float*    base0P      = (float*)   alloc((size_t)BATCH * GDIM * 4);   // 64MB (dead after G2)
  float*    cbuf        = (float*)   alloc((size_t)BATCH * HDIM * 4);   // 16MB
  ushort_t* gatesA      = (ushort_t*)alloc((size_t)BATCH * HDIM * 2);   // 8MB  [hr' | r]
  ushort_t* logitsA     = (ushort_t*)alloc((size_t)BATCH * 1536 * 2);   // 12MB [hi,lo,hi]
  ushort_t* Q_cat       = (ushort_t*)alloc((size_t)BATCH * 1536 * 2);   // 12MB
  ushort_t* wihP        = (ushort_t*)alloc((size_t)GDIM * 1024 * 2);    // 8MB
  ushort_t* whhLP       = (ushort_t*)alloc((size_t)GDIM * 1024 * 2);    // 8MB
  ushort_t* whhP        = (ushort_t*)alloc((size_t)GDIM * HDIM * 2);    // 8MB
  ushort_t* B_cat       = (ushort_t*)alloc((size_t)FEWN * 1536 * 2);
  ushort_t* supT_bf     = (ushort_t*)alloc((size_t)DDIM * FEWN * 2);
  float*    logits_base = (float*)   alloc((size_t)BATCH * FEWN * 4);
  float*    logits      = (float*)   alloc((size_t)BATCH * FEWN * 4);
  ushort_t* attn        = (ushort_t*)alloc((size_t)BATCH * FEWN * 2);
  // ping-pong second hr buffer aliases dead base0P (base0P unused after G2)
  ushort_t* gatesB      = (ushort_t*)base0P;

  const dim3 blk(256);

  // ---- setup ----
  build_wP_dup<<<GDIM * 512 / 256, blk, 0, stream>>>(W_ih, wihP, DDIM);
  build_wP_dup<<<GDIM * 512 / 256, blk, 0, stream>>>(W_hh, whhLP, HDIM);
  build_whhP<<<GDIM * 1024 / 256, blk, 0, stream>>>(W_hh, whhP);
  build_qcat<<<BATCH * 512 / 256, blk, 0, stream>>>(query, Q_cat);
  build_bcat<<<FEWN * 512 / 256, blk, 0, stream>>>(support, B_cat);
  transp_kernel<<<FEWN * DDIM / 256, blk, 0, stream>>>(support, supT_bf);

  // G1: base0P = q @ W_ih^T + b_ih + b_hh  (permuted cols, exact-q via [hi,lo] dup-W)
  gemm_bias<<<dim3(32, 32), blk, 0, stream>>>(Q_cat, wihP, base0P, b_ih, b_hh, 1024, 1536, 1024);
  // logits_base = Q_cat @ B_cat^T (split-precision q@s^T)
  gemm_bt<3><<<dim3(1, 32), blk, 0, stream>>>(Q_cat, B_cat, logits_base, nullptr, nullptr,
                                              1536, 1536, 1536, FEWN);

  auto attn_phase = [&](ushort_t* gOut) {
    gemm_bt<1><<<dim3(1, 32), blk, 0, stream>>>(logitsA, B_cat, logits, nullptr, logits_base,
                                                1536, 1536, 1536, FEWN);
    softmax_kernel<<<BATCH / 4, blk, 0, stream>>>(logits, attn);
    gemm_bt<2><<<dim3(4, 32), blk, 0, stream>>>(attn, supT_bf, nullptr, gOut + DDIM, nullptr,
                                                FEWN, FEWN, FEWN, HDIM);
  };

  // G2 (fused step0): gates_baseP = base0P + q @ WhhL^T ; cell0 on base0P -> c, gatesA, logitsA
  gemm_fused<0><<<dim3(32, 32), blk, 0, stream>>>(
      Q_cat, whhLP, base0P, gates_baseP, cbuf, gatesA, logitsA, nullptr, nullptr, 1024, 1536, 1024);
  attn_phase(gatesA);

  // step 1: read gatesA -> write gatesB (ping-pong avoids A-read/epilogue-write race)
  gemm_fused<1><<<dim3(32, 32), blk, 0, stream>>>(
      gatesA, whhP, gates_baseP, nullptr, cbuf, gatesB, logitsA, nullptr, nullptr, 1024, 1024, 1024);
  attn_phase(gatesB);

  // step 2: read gatesB -> write gatesA
  gemm_fused<1><<<dim3(32, 32), blk, 0, stream>>>(
      gatesB, whhP, gates_baseP, nullptr, cbuf, gatesA, logitsA, nullptr, nullptr, 1024, 1024, 1024);
  attn_phase(gatesA);

  // step 3 (last): only j<512 needed -> half grid (col'<2048 keeps all 4 gates)
  gemm_fused<2><<<dim3(16, 32), blk, 0, stream>>>(
      gatesA, whhP, gates_baseP, nullptr, cbuf, nullptr, nullptr, query, out, 1024, 1024, 1024);
}

// Round 7
// 493.334 us; speedup vs baseline: 1.1762x; 1.0558x over previous
//
#include <hip/hip_runtime.h>

#define BATCH 4096
#define DDIM  512
#define HDIM  1024
#define GDIM  4096
#define FEWN  128

typedef unsigned short ushort_t;
typedef __attribute__((ext_vector_type(8))) short bf16x8;
typedef __attribute__((ext_vector_type(4))) float f32x4;

__device__ inline ushort_t f2bf(float f) {
  unsigned u = __float_as_uint(f);
  unsigned r = (u + 0x7FFFu + ((u >> 16) & 1u)) >> 16;
  return (ushort_t)r;
}
__device__ inline float bf2f(ushort_t h) { return __uint_as_float((unsigned)h << 16); }

__device__ inline float sigmoidf(float x) { return 1.f / (1.f + __expf(-x)); }
__device__ inline float tanh_fast(float x) {
  float ax = fabsf(x);
  float t = __expf(-2.f * ax);
  float r = (1.f - t) / (1.f + t);
  return copysignf(r, x);
}

// permuted gate layout: col' -> original W row; gate g of j at col' with ((col'>>4)&3)=g
__device__ inline int orig_row(int colp) {
  return ((colp >> 4) & 3) * 1024 + ((colp >> 6) << 4) + (colp & 15);
}

__device__ inline void async_copy16(ushort_t* lds, const ushort_t* g) {
  __builtin_amdgcn_global_load_lds(
      (const __attribute__((address_space(1))) unsigned int*)g,
      (__attribute__((address_space(3))) unsigned int*)lds, 16, 0, 0);
}

// bijective XCD swizzle (m204): nwg % 8 == 0 for every grid we launch
#define XCD_SWZ()                                                            \
  int bx = blockIdx.x, by = blockIdx.y;                                      \
  {                                                                          \
    const int gx = gridDim.x;                                                \
    const int nwg = gx * gridDim.y;                                          \
    const int id = by * gx + bx;                                             \
    const int qq = nwg >> 3;                                                 \
    const int nid = (id & 7) * qq + (id >> 3);                               \
    bx = nid % gx; by = nid / gx;                                            \
  }

// ---- shared K-loop (m97 structure, 128x128 tile, BK=32) ----
#define GEMM_PROLOG()                                                        \
  __shared__ __align__(16) ushort_t lA[128 * 32];                            \
  __shared__ __align__(16) ushort_t lB[128 * 32];                            \
  const int tid = threadIdx.x;                                               \
  const int wid = tid >> 6, lane = tid & 63;                                 \
  const int wr = wid >> 1, wc = wid & 1;                                     \
  XCD_SWZ()                                                                  \
  const int m0 = by * 128, n0 = bx * 128;                                    \
  const int lr = lane & 15, kg = lane >> 4;                                  \
  f32x4 acc[4][4] = {};                                                      \
  const int cA = wid * 2;                                                    \
  const int srow = lane >> 2;                                                \
  const int scol = (lane & 3) * 8;                                           \
  const ushort_t* gA0 = A + (size_t)(m0 + cA * 16 + srow) * lda + scol;      \
  const ushort_t* gB0 = B + (size_t)(n0 + cA * 16 + srow) * ldb + scol;      \
  ushort_t* sA = &lA[cA * 512];                                              \
  ushort_t* sB = &lB[cA * 512];                                              \
  const int nIter = K >> 5;                                                  \
  for (int kt = 0; kt < nIter; ++kt) {                                       \
    const int k0 = kt << 5;                                                  \
    async_copy16(sA,       gA0 + k0);                                        \
    async_copy16(sA + 512, gA0 + (size_t)16 * lda + k0);                     \
    async_copy16(sB,       gB0 + k0);                                        \
    async_copy16(sB + 512, gB0 + (size_t)16 * ldb + k0);                     \
    __syncthreads();                                                         \
    bf16x8 af[4], bfr[4];                                                    \
    _Pragma("unroll")                                                        \
    for (int mi = 0; mi < 4; ++mi)                                           \
      af[mi] = *(const bf16x8*)&lA[(wr * 64 + mi * 16 + lr) * 32 + kg * 8];  \
    _Pragma("unroll")                                                        \
    for (int ni = 0; ni < 4; ++ni)                                           \
      bfr[ni] = *(const bf16x8*)&lB[(wc * 64 + ni * 16 + lr) * 32 + kg * 8]; \
    _Pragma("unroll")                                                        \
    for (int mi = 0; mi < 4; ++mi)                                           \
      _Pragma("unroll")                                                      \
      for (int ni = 0; ni < 4; ++ni)                                         \
        acc[mi][ni] = __builtin_amdgcn_mfma_f32_16x16x32_bf16(af[mi], bfr[ni], acc[mi][ni], 0, 0, 0); \
    __syncthreads();                                                         \
  }

// ONE wide GEMM: C = Qcat(hi,lo) @ [wihP | wsumP]^T, N=8192.
// Left half (n0<4096): step-0 gates -> run cell0 in epilogue (c, A1.hi, A2.lo). No base0 store.
// Right half: gates_baseP = acc + bias.
__launch_bounds__(256)
__global__ void gemm_wide(const ushort_t* __restrict__ A, const ushort_t* __restrict__ B,
                          float* __restrict__ gbase, float* __restrict__ c,
                          ushort_t* __restrict__ A1out, ushort_t* __restrict__ A2out,
                          const float* __restrict__ b1, const float* __restrict__ b2,
                          int K, int lda, int ldb) {
  GEMM_PROLOG()
  if (n0 < 4096) {
    const int jj = ((n0 + wc * 64) >> 6) * 16 + lr;   // 0..1023
    const bool do_h = (n0 + wc * 64) < 2048;          // j < 512
    const float bi0 = b1[jj]        + b2[jj];
    const float bi1 = b1[1024 + jj] + b2[1024 + jj];
    const float bi2 = b1[2048 + jj] + b2[2048 + jj];
    const float bi3 = b1[3072 + jj] + b2[3072 + jj];
#pragma unroll
    for (int mi = 0; mi < 4; ++mi) {
#pragma unroll
      for (int r = 0; r < 4; ++r) {
        const int row = m0 + wr * 64 + mi * 16 + kg * 4 + r;
        const float si = sigmoidf(acc[mi][0][r] + bi0);
        const float sf = sigmoidf(acc[mi][1][r] + bi1);
        const float tg = tanh_fast(acc[mi][2][r] + bi2);
        const float so = sigmoidf(acc[mi][3][r] + bi3);
        const float cn = si * tg;                      // c_prev = 0; sf unused but matches ref
        (void)sf;
        c[(size_t)row * HDIM + jj] = cn;
        if (do_h) {
          const float hr = so * tanh_fast(cn);
          const ushort_t hi = f2bf(hr);
          const ushort_t lo = f2bf(hr - bf2f(hi));
          A1out[(size_t)row * HDIM + jj] = hi;
          A2out[(size_t)row * DDIM + jj] = lo;
        }
      }
    }
  } else {
    const int nloc = n0 - 4096;
#pragma unroll
    for (int mi = 0; mi < 4; ++mi)
#pragma unroll
      for (int ni = 0; ni < 4; ++ni)
#pragma unroll
        for (int r = 0; r < 4; ++r) {
          const int row = m0 + wr * 64 + mi * 16 + kg * 4 + r;
          const int col = nloc + wc * 64 + ni * 16 + lr;
          const int og = orig_row(col);
          gbase[(size_t)row * GDIM + col] = acc[mi][ni][r] + b1[og] + b2[og];
        }
  }
}

// Fused recurrent GEMM + LSTM cell (mid/last steps). Permuted cols: gate g in ni-reg g.
// MODE 1: cell on base+acc -> c, A1.hi, A2.lo.  MODE 2: out = query + hr (grid.x = 16).
template<int MODE>
__launch_bounds__(256)
__global__ void gemm_fused(const ushort_t* __restrict__ A, const ushort_t* __restrict__ B,
                           const float* __restrict__ base, float* __restrict__ c,
                           ushort_t* __restrict__ A1out, ushort_t* __restrict__ A2out,
                           const float* __restrict__ query, float* __restrict__ out,
                           int K, int lda, int ldb) {
  GEMM_PROLOG()
  const int jj = ((n0 + wc * 64) >> 6) * 16 + lr;
  const bool do_h = (MODE == 2) || ((n0 + wc * 64) < 2048);
#pragma unroll
  for (int mi = 0; mi < 4; ++mi) {
#pragma unroll
    for (int r = 0; r < 4; ++r) {
      const int row = m0 + wr * 64 + mi * 16 + kg * 4 + r;
      const size_t o0 = (size_t)row * GDIM + n0 + wc * 64 + lr;
      const float g0 = base[o0]      + acc[mi][0][r];
      const float g1 = base[o0 + 16] + acc[mi][1][r];
      const float g2 = base[o0 + 32] + acc[mi][2][r];
      const float g3 = base[o0 + 48] + acc[mi][3][r];
      const float si = sigmoidf(g0);
      const float sf = sigmoidf(g1);
      const float tg = tanh_fast(g2);
      const float so = sigmoidf(g3);
      const size_t ci = (size_t)row * HDIM + jj;
      const float cn = sf * c[ci] + si * tg;
      if (MODE != 2) c[ci] = cn;
      if (do_h) {
        const float hr = so * tanh_fast(cn);
        if (MODE == 2) {
          out[(size_t)row * DDIM + jj] = query[(size_t)row * DDIM + jj] + hr;
        } else {
          const ushort_t hi = f2bf(hr);
          const ushort_t lo = f2bf(hr - bf2f(hi));
          A1out[(size_t)row * HDIM + jj] = hi;
          A2out[(size_t)row * DDIM + jj] = lo;
        }
      }
    }
  }
}

// logits = logits_base + [hi, lo, hi] @ [s_hi, s_hi, s_lo]^T
// A staged from A1 (hi, lda 1024) / A2 (lo, lda 512) / A1 again, per k-range.
__launch_bounds__(256)
__global__ void gemm_logits(const ushort_t* __restrict__ A1, const ushort_t* __restrict__ A2,
                            const ushort_t* __restrict__ B,
                            float* __restrict__ Cf, const float* __restrict__ base) {
  __shared__ __align__(16) ushort_t lA[128 * 32];
  __shared__ __align__(16) ushort_t lB[128 * 32];
  const int tid = threadIdx.x;
  const int wid = tid >> 6, lane = tid & 63;
  const int wr = wid >> 1, wc = wid & 1;
  XCD_SWZ()
  const int m0 = by * 128, n0 = bx * 128;
  const int lr = lane & 15, kg = lane >> 4;
  f32x4 acc[4][4] = {};
  const int cA = wid * 2;
  const int srow = lane >> 2;
  const int scol = (lane & 3) * 8;
  const ushort_t* gA1 = A1 + (size_t)(m0 + cA * 16 + srow) * 1024 + scol;
  const ushort_t* gA2 = A2 + (size_t)(m0 + cA * 16 + srow) * 512 + scol;
  const ushort_t* gB0 = B + (size_t)(n0 + cA * 16 + srow) * 1536 + scol;
  ushort_t* sA = &lA[cA * 512];
  ushort_t* sB = &lB[cA * 512];
  for (int kt = 0; kt < 48; ++kt) {
    const int k0 = kt << 5;
    const ushort_t* srcA = (kt < 16) ? gA1 + k0
                         : (kt < 32) ? gA2 + (k0 - 512)
                                     : gA1 + (k0 - 1024);
    const int ldax = (kt >= 16 && kt < 32) ? 512 : 1024;
    async_copy16(sA,       srcA);
    async_copy16(sA + 512, srcA + (size_t)16 * ldax);
    async_copy16(sB,       gB0 + k0);
    async_copy16(sB + 512, gB0 + (size_t)16 * 1536 + k0);
    __syncthreads();
    bf16x8 af[4], bfr[4];
#pragma unroll
    for (int mi = 0; mi < 4; ++mi)
      af[mi] = *(const bf16x8*)&lA[(wr * 64 + mi * 16 + lr) * 32 + kg * 8];
#pragma unroll
    for (int ni = 0; ni < 4; ++ni)
      bfr[ni] = *(const bf16x8*)&lB[(wc * 64 + ni * 16 + lr) * 32 + kg * 8];
#pragma unroll
    for (int mi = 0; mi < 4; ++mi)
#pragma unroll
      for (int ni = 0; ni < 4; ++ni)
        acc[mi][ni] = __builtin_amdgcn_mfma_f32_16x16x32_bf16(af[mi], bfr[ni], acc[mi][ni], 0, 0, 0);
    __syncthreads();
  }
#pragma unroll
  for (int mi = 0; mi < 4; ++mi)
#pragma unroll
    for (int ni = 0; ni < 4; ++ni)
#pragma unroll
      for (int r = 0; r < 4; ++r) {
        const int row = m0 + wr * 64 + mi * 16 + kg * 4 + r;
        const int col = n0 + wc * 64 + ni * 16 + lr;
        const size_t o = (size_t)row * FEWN + col;
        Cf[o] = base[o] + acc[mi][ni][r];
      }
}

// generic (EPI: 2 = bf16(acc) -> Cb ; 3 = acc -> Cf)
template<int EPI>
__launch_bounds__(256)
__global__ void gemm_bt(const ushort_t* __restrict__ A, const ushort_t* __restrict__ B,
                        float* __restrict__ Cf, ushort_t* __restrict__ Cb,
                        int K, int lda, int ldb, int ldc) {
  GEMM_PROLOG()
#pragma unroll
  for (int mi = 0; mi < 4; ++mi)
#pragma unroll
    for (int ni = 0; ni < 4; ++ni)
#pragma unroll
      for (int r = 0; r < 4; ++r) {
        const int row = m0 + wr * 64 + mi * 16 + kg * 4 + r;
        const int col = n0 + wc * 64 + ni * 16 + lr;
        const float v = acc[mi][ni][r];
        const size_t o = (size_t)row * ldc + col;
        if (EPI == 2) Cb[o] = f2bf(v);
        else          Cf[o] = v;
      }
}

__global__ void softmax_kernel(const float* __restrict__ logits, ushort_t* __restrict__ attn) {
  const int row = blockIdx.x * 4 + (threadIdx.x >> 6);
  const int lane = threadIdx.x & 63;
  const float* L = logits + (size_t)row * FEWN;
  const float x0 = L[lane], x1 = L[lane + 64];
  float m = fmaxf(x0, x1);
#pragma unroll
  for (int s = 32; s > 0; s >>= 1) m = fmaxf(m, __shfl_xor(m, s));
  const float e0 = __expf(x0 - m), e1 = __expf(x1 - m);
  float sum = e0 + e1;
#pragma unroll
  for (int s = 32; s > 0; s >>= 1) sum += __shfl_xor(sum, s);
  const float inv = 1.f / sum;
  attn[(size_t)row * FEWN + lane]      = f2bf(e0 * inv);
  attn[(size_t)row * FEWN + lane + 64] = f2bf(e1 * inv);
}

// wcomb [8192][1024]: rows 0-4095 = dup bf16(W_ih[og]); rows 4096-8191 = dup bf16(W_ih[og]+W_hhL[og])
__global__ void build_wcomb(const float* __restrict__ Wih, const float* __restrict__ Whh,
                            ushort_t* __restrict__ out) {
  const int idx = blockIdx.x * 256 + threadIdx.x;  // 8192*512
  const int r = idx >> 9, cc = idx & 511;
  ushort_t v;
  if (r < 4096) {
    v = f2bf(Wih[(size_t)orig_row(r) * 512 + cc]);
  } else {
    const int og = orig_row(r - 4096);
    v = f2bf(Wih[(size_t)og * 512 + cc] + Whh[(size_t)og * 1024 + cc]);
  }
  out[(size_t)r * 1024 + cc] = v;
  out[(size_t)r * 1024 + cc + 512] = v;
}

// whhP[r][k] = bf16(W_hh[orig(r)][k]), K=1024
__global__ void build_whhP(const float* __restrict__ W, ushort_t* __restrict__ out) {
  const int idx = blockIdx.x * 256 + threadIdx.x;  // 4096*1024
  const int r = idx >> 10, k = idx & 1023;
  out[idx] = f2bf(W[(size_t)orig_row(r) * 1024 + k]);
}

// Q_cat [4096][1536] = [q_hi, q_lo, q_hi]
__global__ void build_qcat(const float* __restrict__ q, ushort_t* __restrict__ out) {
  const int idx = blockIdx.x * 256 + threadIdx.x;  // 4096*512
  const int b = idx >> 9, cc = idx & 511;
  const float v = q[idx];
  const ushort_t hi = f2bf(v);
  const ushort_t lo = f2bf(v - bf2f(hi));
  const size_t ro = (size_t)b * 1536;
  out[ro + cc] = hi;
  out[ro + 512 + cc] = lo;
  out[ro + 1024 + cc] = hi;
}

// B_cat [128][1536] = [s_hi, s_hi, s_lo]
__global__ void build_bcat(const float* __restrict__ s, ushort_t* __restrict__ out) {
  const int idx = blockIdx.x * 256 + threadIdx.x;  // 128*512
  const int n = idx >> 9, cc = idx & 511;
  const float v = s[idx];
  const ushort_t hi = f2bf(v);
  const ushort_t lo = f2bf(v - bf2f(hi));
  const size_t ro = (size_t)n * 1536;
  out[ro + cc] = hi;
  out[ro + 512 + cc] = hi;
  out[ro + 1024 + cc] = lo;
}

// support [128][512] f32 -> supT [512][128] bf16
__global__ void transp_kernel(const float* __restrict__ in, ushort_t* __restrict__ outT) {
  const int idx = blockIdx.x * 256 + threadIdx.x;  // 65536
  const int r = idx >> 9, colv = idx & 511;
  outT[colv * FEWN + r] = f2bf(in[idx]);
}

extern "C" void kernel_launch(void* const* d_in, const int* in_sizes, int n_in,
                              void* d_out, int out_size, void* d_ws, size_t ws_size,
                              hipStream_t stream) {
  const float* support = (const float*)d_in[0];
  const float* query   = (const float*)d_in[1];
  const float* W_ih    = (const float*)d_in[2];
  const float* W_hh    = (const float*)d_in[3];
  const float* b_ih    = (const float*)d_in[4];
  const float* b_hh    = (const float*)d_in[5];
  float* out = (float*)d_out;

  char* ws = (char*)d_ws;
  size_t off = 0;
  auto alloc = [&](size_t bytes) { char* p = ws + off; off += (bytes + 255) & ~255ull; return p; };
  float*    gates_baseP = (float*)   alloc((size_t)BATCH * GDIM * 4);   // 64MB
  float*    cbuf        = (float*)   alloc((size_t)BATCH * HDIM * 4);   // 16MB
  ushort_t* A1a         = (ushort_t*)alloc((size_t)BATCH * HDIM * 2);   // 8MB  [hi | r]
  ushort_t* A1b         = (ushort_t*)alloc((size_t)BATCH * HDIM * 2);   // 8MB
  ushort_t* A2a         = (ushort_t*)alloc((size_t)BATCH * DDIM * 2);   // 4MB  lo
  ushort_t* A2b         = (ushort_t*)alloc((size_t)BATCH * DDIM * 2);   // 4MB
  ushort_t* Q_cat       = (ushort_t*)alloc((size_t)BATCH * 1536 * 2);   // 12MB
  ushort_t* wcomb       = (ushort_t*)alloc((size_t)8192 * 1024 * 2);    // 16MB
  ushort_t* whhP        = (ushort_t*)alloc((size_t)GDIM * HDIM * 2);    // 8MB
  ushort_t* B_cat       = (ushort_t*)alloc((size_t)FEWN * 1536 * 2);
  ushort_t* supT_bf     = (ushort_t*)alloc((size_t)DDIM * FEWN * 2);
  float*    logits_base = (float*)   alloc((size_t)BATCH * FEWN * 4);
  float*    logits      = (float*)   alloc((size_t)BATCH * FEWN * 4);
  ushort_t* attn        = (ushort_t*)alloc((size_t)BATCH * FEWN * 2);

  const dim3 blk(256);

  // ---- setup ----
  build_wcomb<<<8192 * 512 / 256, blk, 0, stream>>>(W_ih, W_hh, wcomb);
  build_whhP<<<GDIM * 1024 / 256, blk, 0, stream>>>(W_hh, whhP);
  build_qcat<<<BATCH * 512 / 256, blk, 0, stream>>>(query, Q_cat);
  build_bcat<<<FEWN * 512 / 256, blk, 0, stream>>>(support, B_cat);
  transp_kernel<<<FEWN * DDIM / 256, blk, 0, stream>>>(support, supT_bf);

  // logits_base = Q_cat @ B_cat^T (split-precision q@s^T)
  gemm_bt<3><<<dim3(1, 32), blk, 0, stream>>>(Q_cat, B_cat, logits_base, nullptr,
                                              1536, 1536, 1536, FEWN);

  // wide GEMM: left half = step-0 gates + cell0 (-> cbuf, A1a, A2a); right half = gates_baseP
  gemm_wide<<<dim3(64, 32), blk, 0, stream>>>(
      Q_cat, wcomb, gates_baseP, cbuf, A1a, A2a, b_ih, b_hh, 1024, 1536, 1024);

  auto attn_phase = [&](ushort_t* A1, ushort_t* A2) {
    gemm_logits<<<dim3(1, 32), blk, 0, stream>>>(A1, A2, B_cat, logits, logits_base);
    softmax_kernel<<<BATCH / 4, blk, 0, stream>>>(logits, attn);
    gemm_bt<2><<<dim3(4, 32), blk, 0, stream>>>(attn, supT_bf, nullptr, A1 + DDIM,
                                                FEWN, FEWN, FEWN, HDIM);
  };

  attn_phase(A1a, A2a);

  // step 1: read A1a -> write A1b/A2b (ping-pong)
  gemm_fused<1><<<dim3(32, 32), blk, 0, stream>>>(
      A1a, whhP, gates_baseP, cbuf, A1b, A2b, nullptr, nullptr, 1024, 1024, 1024);
  attn_phase(A1b, A2b);

  // step 2: read A1b -> write A1a/A2a
  gemm_fused<1><<<dim3(32, 32), blk, 0, stream>>>(
      A1b, whhP, gates_baseP, cbuf, A1a, A2a, nullptr, nullptr, 1024, 1024, 1024);
  attn_phase(A1a, A2a);

  // step 3 (last): only j<512 -> half grid; out = query + hr
  gemm_fused<2><<<dim3(16, 32), blk, 0, stream>>>(
      A1a, whhP, gates_baseP, cbuf, nullptr, nullptr, query, out, 1024, 1024, 1024);
}

// Round 9
// 467.239 us; speedup vs baseline: 1.2419x; 1.0558x over previous
//
#include <hip/hip_runtime.h>

#define BATCH 4096
#define DDIM  512
#define HDIM  1024
#define GDIM  4096
#define FEWN  128

typedef unsigned short ushort_t;
typedef __attribute__((ext_vector_type(8))) short bf16x8;
typedef __attribute__((ext_vector_type(4))) float f32x4;

__device__ inline ushort_t f2bf(float f) {
  unsigned u = __float_as_uint(f);
  unsigned r = (u + 0x7FFFu + ((u >> 16) & 1u)) >> 16;
  return (ushort_t)r;
}
__device__ inline float bf2f(ushort_t h) { return __uint_as_float((unsigned)h << 16); }

__device__ inline float sigmoidf(float x) { return 1.f / (1.f + __expf(-x)); }
__device__ inline float tanh_fast(float x) {
  float ax = fabsf(x);
  float t = __expf(-2.f * ax);
  float r = (1.f - t) / (1.f + t);
  return copysignf(r, x);
}

// permuted gate layout: col' -> original W row; gate g of j at col' with ((col'>>4)&3)=g
__device__ inline int orig_row(int colp) {
  return ((colp >> 4) & 3) * 1024 + ((colp >> 6) << 4) + (colp & 15);
}

__device__ inline void async_copy16(ushort_t* lds, const ushort_t* g) {
  __builtin_amdgcn_global_load_lds(
      (const __attribute__((address_space(1))) unsigned int*)g,
      (__attribute__((address_space(3))) unsigned int*)lds, 16, 0, 0);
}

// XCD-aware swizzle. gx%8==0: column-slice — XCD x owns bx in [x*cpx,(x+1)*cpx),
// sweeping bx fastest (A-panel reuse) then by (B slice stays in 4MB L2).
// Else: bijective 1D (m204).
#define XCD_SWZ()                                                            \
  int bx = blockIdx.x, by = blockIdx.y;                                      \
  {                                                                          \
    const int gx = gridDim.x;                                                \
    const int id = by * gx + bx;                                             \
    if ((gx & 7) == 0) {                                                     \
      const int cpx = gx >> 3;                                               \
      const int x = id & 7, s = id >> 3;                                     \
      bx = x * cpx + (s % cpx);                                              \
      by = s / cpx;                                                          \
    } else {                                                                 \
      const int nwg = gx * gridDim.y;                                        \
      const int qq = nwg >> 3, rr = nwg & 7;                                 \
      const int x = id & 7, s = id >> 3;                                     \
      const int nid = (x < rr ? x * (qq + 1) : rr * (qq + 1) + (x - rr) * qq) + s; \
      bx = nid % gx; by = nid / gx;                                          \
    }                                                                        \
  }

// ---- shared K-loop (m97 structure, 128x128 tile, BK=32) ----
#define GEMM_PROLOG()                                                        \
  __shared__ __align__(16) ushort_t lA[128 * 32];                            \
  __shared__ __align__(16) ushort_t lB[128 * 32];                            \
  const int tid = threadIdx.x;                                               \
  const int wid = tid >> 6, lane = tid & 63;                                 \
  const int wr = wid >> 1, wc = wid & 1;                                     \
  XCD_SWZ()                                                                  \
  const int m0 = by * 128, n0 = bx * 128;                                    \
  const int lr = lane & 15, kg = lane >> 4;                                  \
  f32x4 acc[4][4] = {};                                                      \
  const int cA = wid * 2;                                                    \
  const int srow = lane >> 2;                                                \
  const int scol = (lane & 3) * 8;                                           \
  const ushort_t* gA0 = A + (size_t)(m0 + cA * 16 + srow) * lda + scol;      \
  const ushort_t* gB0 = B + (size_t)(n0 + cA * 16 + srow) * ldb + scol;      \
  ushort_t* sA = &lA[cA * 512];                                              \
  ushort_t* sB = &lB[cA * 512];                                              \
  const int nIter = K >> 5;                                                  \
  for (int kt = 0; kt < nIter; ++kt) {                                       \
    const int k0 = kt << 5;                                                  \
    async_copy16(sA,       gA0 + k0);                                        \
    async_copy16(sA + 512, gA0 + (size_t)16 * lda + k0);                     \
    async_copy16(sB,       gB0 + k0);                                        \
    async_copy16(sB + 512, gB0 + (size_t)16 * ldb + k0);                     \
    __syncthreads();                                                         \
    bf16x8 af[4], bfr[4];                                                    \
    _Pragma("unroll")                                                        \
    for (int mi = 0; mi < 4; ++mi)                                           \
      af[mi] = *(const bf16x8*)&lA[(wr * 64 + mi * 16 + lr) * 32 + kg * 8];  \
    _Pragma("unroll")                                                        \
    for (int ni = 0; ni < 4; ++ni)                                           \
      bfr[ni] = *(const bf16x8*)&lB[(wc * 64 + ni * 16 + lr) * 32 + kg * 8]; \
    _Pragma("unroll")                                                        \
    for (int mi = 0; mi < 4; ++mi)                                           \
      _Pragma("unroll")                                                      \
      for (int ni = 0; ni < 4; ++ni)                                         \
        acc[mi][ni] = __builtin_amdgcn_mfma_f32_16x16x32_bf16(af[mi], bfr[ni], acc[mi][ni], 0, 0, 0); \
    __syncthreads();                                                         \
  }

// Wide GEMM: C = Qcat(hi,lo) @ [wihP | wsumP]^T, N=8192, K=1024.
// B rows are 512 wide (un-duplicated); K-half k>=512 wraps to the same 512 cols (L2 hit).
// Left half (n0<4096): step-0 gates -> cell0 in epilogue (c, A1.hi, A2.lo).
// Right half: gates_baseP = bf16(acc + bias).
__launch_bounds__(256)
__global__ void gemm_wide(const ushort_t* __restrict__ A, const ushort_t* __restrict__ B,
                          ushort_t* __restrict__ gbase, float* __restrict__ c,
                          ushort_t* __restrict__ A1out, ushort_t* __restrict__ A2out,
                          const float* __restrict__ b1, const float* __restrict__ b2) {
  __shared__ __align__(16) ushort_t lA[128 * 32];
  __shared__ __align__(16) ushort_t lB[128 * 32];
  const int tid = threadIdx.x;
  const int wid = tid >> 6, lane = tid & 63;
  const int wr = wid >> 1, wc = wid & 1;
  XCD_SWZ()
  const int m0 = by * 128, n0 = bx * 128;
  const int lr = lane & 15, kg = lane >> 4;
  f32x4 acc[4][4] = {};
  const int cA = wid * 2;
  const int srow = lane >> 2;
  const int scol = (lane & 3) * 8;
  const ushort_t* gA0 = A + (size_t)(m0 + cA * 16 + srow) * 1536 + scol;
  const ushort_t* gB0 = B + (size_t)(n0 + cA * 16 + srow) * 512 + scol;
  ushort_t* sA = &lA[cA * 512];
  ushort_t* sB = &lB[cA * 512];
  for (int kt = 0; kt < 32; ++kt) {
    const int k0 = kt << 5;
    const int bk = k0 & 511;   // B wraps: hi and lo halves of A hit the same B cols
    async_copy16(sA,       gA0 + k0);
    async_copy16(sA + 512, gA0 + (size_t)16 * 1536 + k0);
    async_copy16(sB,       gB0 + bk);
    async_copy16(sB + 512, gB0 + (size_t)16 * 512 + bk);
    __syncthreads();
    bf16x8 af[4], bfr[4];
#pragma unroll
    for (int mi = 0; mi < 4; ++mi)
      af[mi] = *(const bf16x8*)&lA[(wr * 64 + mi * 16 + lr) * 32 + kg * 8];
#pragma unroll
    for (int ni = 0; ni < 4; ++ni)
      bfr[ni] = *(const bf16x8*)&lB[(wc * 64 + ni * 16 + lr) * 32 + kg * 8];
#pragma unroll
    for (int mi = 0; mi < 4; ++mi)
#pragma unroll
      for (int ni = 0; ni < 4; ++ni)
        acc[mi][ni] = __builtin_amdgcn_mfma_f32_16x16x32_bf16(af[mi], bfr[ni], acc[mi][ni], 0, 0, 0);
    __syncthreads();
  }
  if (n0 < 4096) {
    const int jj = ((n0 + wc * 64) >> 6) * 16 + lr;   // 0..1023
    const bool do_h = (n0 + wc * 64) < 2048;          // j < 512
    const float bi0 = b1[jj]        + b2[jj];
    const float bi1 = b1[1024 + jj] + b2[1024 + jj];
    const float bi2 = b1[2048 + jj] + b2[2048 + jj];
    const float bi3 = b1[3072 + jj] + b2[3072 + jj];
#pragma unroll
    for (int mi = 0; mi < 4; ++mi) {
#pragma unroll
      for (int r = 0; r < 4; ++r) {
        const int row = m0 + wr * 64 + mi * 16 + kg * 4 + r;
        const float si = sigmoidf(acc[mi][0][r] + bi0);
        const float tg = tanh_fast(acc[mi][2][r] + bi2);
        const float so = sigmoidf(acc[mi][3][r] + bi3);
        (void)bi1;
        const float cn = si * tg;                      // c_prev = 0
        c[(size_t)row * HDIM + jj] = cn;
        if (do_h) {
          const float hr = so * tanh_fast(cn);
          const ushort_t hi = f2bf(hr);
          const ushort_t lo = f2bf(hr - bf2f(hi));
          A1out[(size_t)row * HDIM + jj] = hi;
          A2out[(size_t)row * DDIM + jj] = lo;
        }
      }
    }
  } else {
    const int nloc = n0 - 4096;
#pragma unroll
    for (int mi = 0; mi < 4; ++mi)
#pragma unroll
      for (int ni = 0; ni < 4; ++ni)
#pragma unroll
        for (int r = 0; r < 4; ++r) {
          const int row = m0 + wr * 64 + mi * 16 + kg * 4 + r;
          const int col = nloc + wc * 64 + ni * 16 + lr;
          const int og = orig_row(col);
          gbase[(size_t)row * GDIM + col] = f2bf(acc[mi][ni][r] + b1[og] + b2[og]);
        }
  }
}

// Fused recurrent GEMM + LSTM cell. base is bf16 now.
// MODE 1: cell -> c, A1.hi, A2.lo.  MODE 2: out = query + hr (grid.x = 16).
template<int MODE>
__launch_bounds__(256)
__global__ void gemm_fused(const ushort_t* __restrict__ A, const ushort_t* __restrict__ B,
                           const ushort_t* __restrict__ base, float* __restrict__ c,
                           ushort_t* __restrict__ A1out, ushort_t* __restrict__ A2out,
                           const float* __restrict__ query, float* __restrict__ out,
                           int K, int lda, int ldb) {
  GEMM_PROLOG()
  const int jj = ((n0 + wc * 64) >> 6) * 16 + lr;
  const bool do_h = (MODE == 2) || ((n0 + wc * 64) < 2048);
#pragma unroll
  for (int mi = 0; mi < 4; ++mi) {
#pragma unroll
    for (int r = 0; r < 4; ++r) {
      const int row = m0 + wr * 64 + mi * 16 + kg * 4 + r;
      const size_t o0 = (size_t)row * GDIM + n0 + wc * 64 + lr;
      const float g0 = bf2f(base[o0])      + acc[mi][0][r];
      const float g1 = bf2f(base[o0 + 16]) + acc[mi][1][r];
      const float g2 = bf2f(base[o0 + 32]) + acc[mi][2][r];
      const float g3 = bf2f(base[o0 + 48]) + acc[mi][3][r];
      const float si = sigmoidf(g0);
      const float sf = sigmoidf(g1);
      const float tg = tanh_fast(g2);
      const float so = sigmoidf(g3);
      const size_t ci = (size_t)row * HDIM + jj;
      const float cn = sf * c[ci] + si * tg;
      if (MODE != 2) c[ci] = cn;
      if (do_h) {
        const float hr = so * tanh_fast(cn);
        if (MODE == 2) {
          out[(size_t)row * DDIM + jj] = query[(size_t)row * DDIM + jj] + hr;
        } else {
          const ushort_t hi = f2bf(hr);
          const ushort_t lo = f2bf(hr - bf2f(hi));
          A1out[(size_t)row * HDIM + jj] = hi;
          A2out[(size_t)row * DDIM + jj] = lo;
        }
      }
    }
  }
}

// logits = logits_base + [hi, lo, hi] @ [s_hi, s_hi, s_lo]^T
__launch_bounds__(256)
__global__ void gemm_logits(const ushort_t* __restrict__ A1, const ushort_t* __restrict__ A2,
                            const ushort_t* __restrict__ B,
                            float* __restrict__ Cf, const float* __restrict__ base) {
  __shared__ __align__(16) ushort_t lA[128 * 32];
  __shared__ __align__(16) ushort_t lB[128 * 32];
  const int tid = threadIdx.x;
  const int wid = tid >> 6, lane = tid & 63;
  const int wr = wid >> 1, wc = wid & 1;
  XCD_SWZ()
  const int m0 = by * 128, n0 = bx * 128;
  const int lr = lane & 15, kg = lane >> 4;
  f32x4 acc[4][4] = {};
  const int cA = wid * 2;
  const int srow = lane >> 2;
  const int scol = (lane & 3) * 8;
  const ushort_t* gA1 = A1 + (size_t)(m0 + cA * 16 + srow) * 1024 + scol;
  const ushort_t* gA2 = A2 + (size_t)(m0 + cA * 16 + srow) * 512 + scol;
  const ushort_t* gB0 = B + (size_t)(n0 + cA * 16 + srow) * 1536 + scol;
  ushort_t* sA = &lA[cA * 512];
  ushort_t* sB = &lB[cA * 512];
  for (int kt = 0; kt < 48; ++kt) {
    const int k0 = kt << 5;
    const ushort_t* srcA = (kt < 16) ? gA1 + k0
                         : (kt < 32) ? gA2 + (k0 - 512)
                                     : gA1 + (k0 - 1024);
    const int ldax = (kt >= 16 && kt < 32) ? 512 : 1024;
    async_copy16(sA,       srcA);
    async_copy16(sA + 512, srcA + (size_t)16 * ldax);
    async_copy16(sB,       gB0 + k0);
    async_copy16(sB + 512, gB0 + (size_t)16 * 1536 + k0);
    __syncthreads();
    bf16x8 af[4], bfr[4];
#pragma unroll
    for (int mi = 0; mi < 4; ++mi)
      af[mi] = *(const bf16x8*)&lA[(wr * 64 + mi * 16 + lr) * 32 + kg * 8];
#pragma unroll
    for (int ni = 0; ni < 4; ++ni)
      bfr[ni] = *(const bf16x8*)&lB[(wc * 64 + ni * 16 + lr) * 32 + kg * 8];
#pragma unroll
    for (int mi = 0; mi < 4; ++mi)
#pragma unroll
      for (int ni = 0; ni < 4; ++ni)
        acc[mi][ni] = __builtin_amdgcn_mfma_f32_16x16x32_bf16(af[mi], bfr[ni], acc[mi][ni], 0, 0, 0);
    __syncthreads();
  }
#pragma unroll
  for (int mi = 0; mi < 4; ++mi)
#pragma unroll
    for (int ni = 0; ni < 4; ++ni)
#pragma unroll
      for (int r = 0; r < 4; ++r) {
        const int row = m0 + wr * 64 + mi * 16 + kg * 4 + r;
        const int col = n0 + wc * 64 + ni * 16 + lr;
        const size_t o = (size_t)row * FEWN + col;
        Cf[o] = base[o] + acc[mi][ni][r];
      }
}

// generic (EPI: 2 = bf16(acc) -> Cb ; 3 = acc -> Cf)
template<int EPI>
__launch_bounds__(256)
__global__ void gemm_bt(const ushort_t* __restrict__ A, const ushort_t* __restrict__ B,
                        float* __restrict__ Cf, ushort_t* __restrict__ Cb,
                        int K, int lda, int ldb, int ldc) {
  GEMM_PROLOG()
#pragma unroll
  for (int mi = 0; mi < 4; ++mi)
#pragma unroll
    for (int ni = 0; ni < 4; ++ni)
#pragma unroll
      for (int r = 0; r < 4; ++r) {
        const int row = m0 + wr * 64 + mi * 16 + kg * 4 + r;
        const int col = n0 + wc * 64 + ni * 16 + lr;
        const float v = acc[mi][ni][r];
        const size_t o = (size_t)row * ldc + col;
        if (EPI == 2) Cb[o] = f2bf(v);
        else          Cf[o] = v;
      }
}

__global__ void softmax_kernel(const float* __restrict__ logits, ushort_t* __restrict__ attn) {
  const int row = blockIdx.x * 4 + (threadIdx.x >> 6);
  const int lane = threadIdx.x & 63;
  const float* L = logits + (size_t)row * FEWN;
  const float x0 = L[lane], x1 = L[lane + 64];
  float m = fmaxf(x0, x1);
#pragma unroll
  for (int s = 32; s > 0; s >>= 1) m = fmaxf(m, __shfl_xor(m, s));
  const float e0 = __expf(x0 - m), e1 = __expf(x1 - m);
  float sum = e0 + e1;
#pragma unroll
  for (int s = 32; s > 0; s >>= 1) sum += __shfl_xor(sum, s);
  const float inv = 1.f / sum;
  attn[(size_t)row * FEWN + lane]      = f2bf(e0 * inv);
  attn[(size_t)row * FEWN + lane + 64] = f2bf(e1 * inv);
}

// wcomb [8192][512] (un-duplicated): rows 0-4095 = bf16(W_ih[og]); 4096-8191 = bf16(W_ih[og]+W_hhL[og])
__global__ void build_wcomb(const float* __restrict__ Wih, const float* __restrict__ Whh,
                            ushort_t* __restrict__ out) {
  const int idx = blockIdx.x * 256 + threadIdx.x;  // 8192*512
  const int r = idx >> 9, cc = idx & 511;
  ushort_t v;
  if (r < 4096) {
    v = f2bf(Wih[(size_t)orig_row(r) * 512 + cc]);
  } else {
    const int og = orig_row(r - 4096);
    v = f2bf(Wih[(size_t)og * 512 + cc] + Whh[(size_t)og * 1024 + cc]);
  }
  out[idx] = v;
}

// whhP[r][k] = bf16(W_hh[orig(r)][k]), K=1024
__global__ void build_whhP(const float* __restrict__ W, ushort_t* __restrict__ out) {
  const int idx = blockIdx.x * 256 + threadIdx.x;  // 4096*1024
  const int r = idx >> 10, k = idx & 1023;
  out[idx] = f2bf(W[(size_t)orig_row(r) * 1024 + k]);
}

// Q_cat [4096][1536] = [q_hi, q_lo, q_hi]
__global__ void build_qcat(const float* __restrict__ q, ushort_t* __restrict__ out) {
  const int idx = blockIdx.x * 256 + threadIdx.x;  // 4096*512
  const int b = idx >> 9, cc = idx & 511;
  const float v = q[idx];
  const ushort_t hi = f2bf(v);
  const ushort_t lo = f2bf(v - bf2f(hi));
  const size_t ro = (size_t)b * 1536;
  out[ro + cc] = hi;
  out[ro + 512 + cc] = lo;
  out[ro + 1024 + cc] = hi;
}

// B_cat [128][1536] = [s_hi, s_hi, s_lo]
__global__ void build_bcat(const float* __restrict__ s, ushort_t* __restrict__ out) {
  const int idx = blockIdx.x * 256 + threadIdx.x;  // 128*512
  const int n = idx >> 9, cc = idx & 511;
  const float v = s[idx];
  const ushort_t hi = f2bf(v);
  const ushort_t lo = f2bf(v - bf2f(hi));
  const size_t ro = (size_t)n * 1536;
  out[ro + cc] = hi;
  out[ro + 512 + cc] = hi;
  out[ro + 1024 + cc] = lo;
}

// support [128][512] f32 -> supT [512][128] bf16
__global__ void transp_kernel(const float* __restrict__ in, ushort_t* __restrict__ outT) {
  const int idx = blockIdx.x * 256 + threadIdx.x;  // 65536
  const int r = idx >> 9, colv = idx & 511;
  outT[colv * FEWN + r] = f2bf(in[idx]);
}

extern "C" void kernel_launch(void* const* d_in, const int* in_sizes, int n_in,
                              void* d_out, int out_size, void* d_ws, size_t ws_size,
                              hipStream_t stream) {
  const float* support = (const float*)d_in[0];
  const float* query   = (const float*)d_in[1];
  const float* W_ih    = (const float*)d_in[2];
  const float* W_hh    = (const float*)d_in[3];
  const float* b_ih    = (const float*)d_in[4];
  const float* b_hh    = (const float*)d_in[5];
  float* out = (float*)d_out;

  char* ws = (char*)d_ws;
  size_t off = 0;
  auto alloc = [&](size_t bytes) { char* p = ws + off; off += (bytes + 255) & ~255ull; return p; };
  ushort_t* gates_baseP = (ushort_t*)alloc((size_t)BATCH * GDIM * 2);   // 32MB bf16
  float*    cbuf        = (float*)   alloc((size_t)BATCH * HDIM * 4);   // 16MB
  ushort_t* A1a         = (ushort_t*)alloc((size_t)BATCH * HDIM * 2);   // 8MB  [hi | r]
  ushort_t* A1b         = (ushort_t*)alloc((size_t)BATCH * HDIM * 2);   // 8MB
  ushort_t* A2a         = (ushort_t*)alloc((size_t)BATCH * DDIM * 2);   // 4MB  lo
  ushort_t* A2b         = (ushort_t*)alloc((size_t)BATCH * DDIM * 2);   // 4MB
  ushort_t* Q_cat       = (ushort_t*)alloc((size_t)BATCH * 1536 * 2);   // 12MB
  ushort_t* wcomb       = (ushort_t*)alloc((size_t)8192 * 512 * 2);     // 8MB (un-dup)
  ushort_t* whhP        = (ushort_t*)alloc((size_t)GDIM * HDIM * 2);    // 8MB
  ushort_t* B_cat       = (ushort_t*)alloc((size_t)FEWN * 1536 * 2);
  ushort_t* supT_bf     = (ushort_t*)alloc((size_t)DDIM * FEWN * 2);
  float*    logits_base = (float*)   alloc((size_t)BATCH * FEWN * 4);
  float*    logits      = (float*)   alloc((size_t)BATCH * FEWN * 4);
  ushort_t* attn        = (ushort_t*)alloc((size_t)BATCH * FEWN * 2);

  const dim3 blk(256);

  // ---- setup ----
  build_wcomb<<<8192 * 512 / 256, blk, 0, stream>>>(W_ih, W_hh, wcomb);
  build_whhP<<<GDIM * 1024 / 256, blk, 0, stream>>>(W_hh, whhP);
  build_qcat<<<BATCH * 512 / 256, blk, 0, stream>>>(query, Q_cat);
  build_bcat<<<FEWN * 512 / 256, blk, 0, stream>>>(support, B_cat);
  transp_kernel<<<FEWN * DDIM / 256, blk, 0, stream>>>(support, supT_bf);

  // logits_base = Q_cat @ B_cat^T (split-precision q@s^T)
  gemm_bt<3><<<dim3(1, 32), blk, 0, stream>>>(Q_cat, B_cat, logits_base, nullptr,
                                              1536, 1536, 1536, FEWN);

  // wide GEMM: left = step-0 gates + cell0 (cbuf, A1a, A2a); right = gates_baseP (bf16)
  gemm_wide<<<dim3(64, 32), blk, 0, stream>>>(
      Q_cat, wcomb, gates_baseP, cbuf, A1a, A2a, b_ih, b_hh);

  auto attn_phase = [&](ushort_t* A1, ushort_t* A2) {
    gemm_logits<<<dim3(1, 32), blk, 0, stream>>>(A1, A2, B_cat, logits, logits_base);
    softmax_kernel<<<BATCH / 4, blk, 0, stream>>>(logits, attn);
    gemm_bt<2><<<dim3(4, 32), blk, 0, stream>>>(attn, supT_bf, nullptr, A1 + DDIM,
                                                FEWN, FEWN, FEWN, HDIM);
  };

  attn_phase(A1a, A2a);

  // step 1: read A1a -> write A1b/A2b (ping-pong)
  gemm_fused<1><<<dim3(32, 32), blk, 0, stream>>>(
      A1a, whhP, gates_baseP, cbuf, A1b, A2b, nullptr, nullptr, 1024, 1024, 1024);
  attn_phase(A1b, A2b);

  // step 2: read A1b -> write A1a/A2a
  gemm_fused<1><<<dim3(32, 32), blk, 0, stream>>>(
      A1b, whhP, gates_baseP, cbuf, A1a, A2a, nullptr, nullptr, 1024, 1024, 1024);
  attn_phase(A1a, A2a);

  // step 3 (last): only j<512 -> half grid; out = query + hr
  gemm_fused<2><<<dim3(16, 32), blk, 0, stream>>>(
      A1a, whhP, gates_baseP, cbuf, nullptr, nullptr, query, out, 1024, 1024, 1024);
}

// Round 10
// 387.859 us; speedup vs baseline: 1.4960x; 1.2047x over previous
//
#include <hip/hip_runtime.h>

#define BATCH 4096
#define DDIM  512
#define HDIM  1024
#define GDIM  4096
#define FEWN  128

typedef unsigned short ushort_t;
typedef __attribute__((ext_vector_type(8))) short bf16x8;
typedef __attribute__((ext_vector_type(4))) float f32x4;

__device__ inline ushort_t f2bf(float f) {
  unsigned u = __float_as_uint(f);
  unsigned r = (u + 0x7FFFu + ((u >> 16) & 1u)) >> 16;
  return (ushort_t)r;
}
__device__ inline float bf2f(ushort_t h) { return __uint_as_float((unsigned)h << 16); }

__device__ inline float sigmoidf(float x) { return 1.f / (1.f + __expf(-x)); }
__device__ inline float tanh_fast(float x) {
  float ax = fabsf(x);
  float t = __expf(-2.f * ax);
  float r = (1.f - t) / (1.f + t);
  return copysignf(r, x);
}

// permuted gate layout: col' -> original W row; gate g of j at col' with ((col'>>4)&3)=g
__device__ inline int orig_row(int colp) {
  return ((colp >> 4) & 3) * 1024 + ((colp >> 6) << 4) + (colp & 15);
}

__device__ inline void async_copy16(ushort_t* lds, const ushort_t* g) {
  __builtin_amdgcn_global_load_lds(
      (const __attribute__((address_space(1))) unsigned int*)g,
      (__attribute__((address_space(3))) unsigned int*)lds, 16, 0, 0);
}

// XCD-aware swizzle. gx%8==0: column-slice — XCD x owns bx in [x*cpx,(x+1)*cpx).
// Else: bijective 1D (m204).
#define XCD_SWZ()                                                            \
  int bx = blockIdx.x, by = blockIdx.y;                                      \
  {                                                                          \
    const int gx = gridDim.x;                                                \
    const int id = by * gx + bx;                                             \
    if ((gx & 7) == 0) {                                                     \
      const int cpx = gx >> 3;                                               \
      const int x = id & 7, s = id >> 3;                                     \
      bx = x * cpx + (s % cpx);                                              \
      by = s / cpx;                                                          \
    } else {                                                                 \
      const int nwg = gx * gridDim.y;                                        \
      const int qq = nwg >> 3, rr = nwg & 7;                                 \
      const int x = id & 7, s = id >> 3;                                     \
      const int nid = (x < rr ? x * (qq + 1) : rr * (qq + 1) + (x - rr) * qq) + s; \
      bx = nid % gx; by = nid / gx;                                          \
    }                                                                        \
  }

// ---- shared K-loop (m97 structure, 128x128 tile, BK=32) ----
#define GEMM_PROLOG()                                                        \
  __shared__ __align__(16) ushort_t lA[128 * 32];                            \
  __shared__ __align__(16) ushort_t lB[128 * 32];                            \
  const int tid = threadIdx.x;                                               \
  const int wid = tid >> 6, lane = tid & 63;                                 \
  const int wr = wid >> 1, wc = wid & 1;                                     \
  XCD_SWZ()                                                                  \
  const int m0 = by * 128, n0 = bx * 128;                                    \
  const int lr = lane & 15, kg = lane >> 4;                                  \
  f32x4 acc[4][4] = {};                                                      \
  const int cA = wid * 2;                                                    \
  const int srow = lane >> 2;                                                \
  const int scol = (lane & 3) * 8;                                           \
  const ushort_t* gA0 = A + (size_t)(m0 + cA * 16 + srow) * lda + scol;      \
  const ushort_t* gB0 = B + (size_t)(n0 + cA * 16 + srow) * ldb + scol;      \
  ushort_t* sA = &lA[cA * 512];                                              \
  ushort_t* sB = &lB[cA * 512];                                              \
  const int nIter = K >> 5;                                                  \
  for (int kt = 0; kt < nIter; ++kt) {                                       \
    const int k0 = kt << 5;                                                  \
    async_copy16(sA,       gA0 + k0);                                        \
    async_copy16(sA + 512, gA0 + (size_t)16 * lda + k0);                     \
    async_copy16(sB,       gB0 + k0);                                        \
    async_copy16(sB + 512, gB0 + (size_t)16 * ldb + k0);                     \
    __syncthreads();                                                         \
    bf16x8 af[4], bfr[4];                                                    \
    _Pragma("unroll")                                                        \
    for (int mi = 0; mi < 4; ++mi)                                           \
      af[mi] = *(const bf16x8*)&lA[(wr * 64 + mi * 16 + lr) * 32 + kg * 8];  \
    _Pragma("unroll")                                                        \
    for (int ni = 0; ni < 4; ++ni)                                           \
      bfr[ni] = *(const bf16x8*)&lB[(wc * 64 + ni * 16 + lr) * 32 + kg * 8]; \
    _Pragma("unroll")                                                        \
    for (int mi = 0; mi < 4; ++mi)                                           \
      _Pragma("unroll")                                                      \
      for (int ni = 0; ni < 4; ++ni)                                         \
        acc[mi][ni] = __builtin_amdgcn_mfma_f32_16x16x32_bf16(af[mi], bfr[ni], acc[mi][ni], 0, 0, 0); \
    __syncthreads();                                                         \
  }

// Wide GEMM: C = q_hi @ [wihP | wsumP]^T, N=8192, K=512 (q_lo dropped: gates path
// tolerates bf16 q; error ~1.4e-3 pre-sigmoid). A = Q_cat cols 0-511 (lda 1536).
// Left half (n0<4096): step-0 gates -> cell0 in epilogue (c bf16, A1.hi, A2.lo).
// Right half: gates_baseP = bf16(acc + bias).
__launch_bounds__(256)
__global__ void gemm_wide(const ushort_t* __restrict__ A, const ushort_t* __restrict__ B,
                          ushort_t* __restrict__ gbase, ushort_t* __restrict__ c,
                          ushort_t* __restrict__ A1out, ushort_t* __restrict__ A2out,
                          const float* __restrict__ b1, const float* __restrict__ b2) {
  __shared__ __align__(16) ushort_t lA[128 * 32];
  __shared__ __align__(16) ushort_t lB[128 * 32];
  const int tid = threadIdx.x;
  const int wid = tid >> 6, lane = tid & 63;
  const int wr = wid >> 1, wc = wid & 1;
  XCD_SWZ()
  const int m0 = by * 128, n0 = bx * 128;
  const int lr = lane & 15, kg = lane >> 4;
  f32x4 acc[4][4] = {};
  const int cA = wid * 2;
  const int srow = lane >> 2;
  const int scol = (lane & 3) * 8;
  const ushort_t* gA0 = A + (size_t)(m0 + cA * 16 + srow) * 1536 + scol;
  const ushort_t* gB0 = B + (size_t)(n0 + cA * 16 + srow) * 512 + scol;
  ushort_t* sA = &lA[cA * 512];
  ushort_t* sB = &lB[cA * 512];
  for (int kt = 0; kt < 16; ++kt) {
    const int k0 = kt << 5;
    async_copy16(sA,       gA0 + k0);
    async_copy16(sA + 512, gA0 + (size_t)16 * 1536 + k0);
    async_copy16(sB,       gB0 + k0);
    async_copy16(sB + 512, gB0 + (size_t)16 * 512 + k0);
    __syncthreads();
    bf16x8 af[4], bfr[4];
#pragma unroll
    for (int mi = 0; mi < 4; ++mi)
      af[mi] = *(const bf16x8*)&lA[(wr * 64 + mi * 16 + lr) * 32 + kg * 8];
#pragma unroll
    for (int ni = 0; ni < 4; ++ni)
      bfr[ni] = *(const bf16x8*)&lB[(wc * 64 + ni * 16 + lr) * 32 + kg * 8];
#pragma unroll
    for (int mi = 0; mi < 4; ++mi)
#pragma unroll
      for (int ni = 0; ni < 4; ++ni)
        acc[mi][ni] = __builtin_amdgcn_mfma_f32_16x16x32_bf16(af[mi], bfr[ni], acc[mi][ni], 0, 0, 0);
    __syncthreads();
  }
  if (n0 < 4096) {
    const int jj = ((n0 + wc * 64) >> 6) * 16 + lr;   // 0..1023
    const bool do_h = (n0 + wc * 64) < 2048;          // j < 512
    const float bi0 = b1[jj]        + b2[jj];
    const float bi2 = b1[2048 + jj] + b2[2048 + jj];
    const float bi3 = b1[3072 + jj] + b2[3072 + jj];
#pragma unroll
    for (int mi = 0; mi < 4; ++mi) {
#pragma unroll
      for (int r = 0; r < 4; ++r) {
        const int row = m0 + wr * 64 + mi * 16 + kg * 4 + r;
        const float si = sigmoidf(acc[mi][0][r] + bi0);
        const float tg = tanh_fast(acc[mi][2][r] + bi2);
        const float so = sigmoidf(acc[mi][3][r] + bi3);
        const float cn = si * tg;                      // c_prev = 0
        c[(size_t)row * HDIM + jj] = f2bf(cn);
        if (do_h) {
          const float hr = so * tanh_fast(cn);
          const ushort_t hi = f2bf(hr);
          const ushort_t lo = f2bf(hr - bf2f(hi));
          A1out[(size_t)row * HDIM + jj] = hi;
          A2out[(size_t)row * DDIM + jj] = lo;
        }
      }
    }
  } else {
    const int nloc = n0 - 4096;
#pragma unroll
    for (int mi = 0; mi < 4; ++mi)
#pragma unroll
      for (int ni = 0; ni < 4; ++ni)
#pragma unroll
        for (int r = 0; r < 4; ++r) {
          const int row = m0 + wr * 64 + mi * 16 + kg * 4 + r;
          const int col = nloc + wc * 64 + ni * 16 + lr;
          const int og = orig_row(col);
          gbase[(size_t)row * GDIM + col] = f2bf(acc[mi][ni][r] + b1[og] + b2[og]);
        }
  }
}

// Fused recurrent GEMM + LSTM cell. base bf16, c bf16.
// MODE 1: cell -> c, A1.hi, A2.lo.  MODE 2: out = query + hr (grid.x = 16).
template<int MODE>
__launch_bounds__(256)
__global__ void gemm_fused(const ushort_t* __restrict__ A, const ushort_t* __restrict__ B,
                           const ushort_t* __restrict__ base, ushort_t* __restrict__ c,
                           ushort_t* __restrict__ A1out, ushort_t* __restrict__ A2out,
                           const float* __restrict__ query, float* __restrict__ out,
                           int K, int lda, int ldb) {
  GEMM_PROLOG()
  const int jj = ((n0 + wc * 64) >> 6) * 16 + lr;
  const bool do_h = (MODE == 2) || ((n0 + wc * 64) < 2048);
#pragma unroll
  for (int mi = 0; mi < 4; ++mi) {
#pragma unroll
    for (int r = 0; r < 4; ++r) {
      const int row = m0 + wr * 64 + mi * 16 + kg * 4 + r;
      const size_t o0 = (size_t)row * GDIM + n0 + wc * 64 + lr;
      const float g0 = bf2f(base[o0])      + acc[mi][0][r];
      const float g1 = bf2f(base[o0 + 16]) + acc[mi][1][r];
      const float g2 = bf2f(base[o0 + 32]) + acc[mi][2][r];
      const float g3 = bf2f(base[o0 + 48]) + acc[mi][3][r];
      const float si = sigmoidf(g0);
      const float sf = sigmoidf(g1);
      const float tg = tanh_fast(g2);
      const float so = sigmoidf(g3);
      const size_t ci = (size_t)row * HDIM + jj;
      const float cn = sf * bf2f(c[ci]) + si * tg;
      if (MODE != 2) c[ci] = f2bf(cn);
      if (do_h) {
        const float hr = so * tanh_fast(cn);
        if (MODE == 2) {
          out[(size_t)row * DDIM + jj] = query[(size_t)row * DDIM + jj] + hr;
        } else {
          const ushort_t hi = f2bf(hr);
          const ushort_t lo = f2bf(hr - bf2f(hi));
          A1out[(size_t)row * HDIM + jj] = hi;
          A2out[(size_t)row * DDIM + jj] = lo;
        }
      }
    }
  }
}

// Split-K logits: grid (3, 32). Chunk k: A-seg {A1.hi, A2.lo, A1.hi} x B-seg
// {s_hi, s_hi, s_lo}; atomicAdd into logits (pre-filled with logits_base).
__launch_bounds__(256)
__global__ void gemm_logits_splitk(const ushort_t* __restrict__ A1, const ushort_t* __restrict__ A2,
                                   const ushort_t* __restrict__ B, float* __restrict__ Cf) {
  __shared__ __align__(16) ushort_t lA[128 * 32];
  __shared__ __align__(16) ushort_t lB[128 * 32];
  const int tid = threadIdx.x;
  const int wid = tid >> 6, lane = tid & 63;
  const int wr = wid >> 1, wc = wid & 1;
  XCD_SWZ()
  const int chunk = bx;
  const int m0 = by * 128;
  const int lr = lane & 15, kg = lane >> 4;
  f32x4 acc[4][4] = {};
  const int cA = wid * 2;
  const int srow = lane >> 2;
  const int scol = (lane & 3) * 8;
  const ushort_t* Asrc = (chunk == 1) ? A2 : A1;
  const int lda = (chunk == 1) ? 512 : 1024;
  const ushort_t* gA0 = Asrc + (size_t)(m0 + cA * 16 + srow) * lda + scol;
  const ushort_t* gB0 = B + (size_t)(cA * 16 + srow) * 1536 + chunk * 512 + scol;
  ushort_t* sA = &lA[cA * 512];
  ushort_t* sB = &lB[cA * 512];
  for (int kt = 0; kt < 16; ++kt) {
    const int k0 = kt << 5;
    async_copy16(sA,       gA0 + k0);
    async_copy16(sA + 512, gA0 + (size_t)16 * lda + k0);
    async_copy16(sB,       gB0 + k0);
    async_copy16(sB + 512, gB0 + (size_t)16 * 1536 + k0);
    __syncthreads();
    bf16x8 af[4], bfr[4];
#pragma unroll
    for (int mi = 0; mi < 4; ++mi)
      af[mi] = *(const bf16x8*)&lA[(wr * 64 + mi * 16 + lr) * 32 + kg * 8];
#pragma unroll
    for (int ni = 0; ni < 4; ++ni)
      bfr[ni] = *(const bf16x8*)&lB[(wc * 64 + ni * 16 + lr) * 32 + kg * 8];
#pragma unroll
    for (int mi = 0; mi < 4; ++mi)
#pragma unroll
      for (int ni = 0; ni < 4; ++ni)
        acc[mi][ni] = __builtin_amdgcn_mfma_f32_16x16x32_bf16(af[mi], bfr[ni], acc[mi][ni], 0, 0, 0);
    __syncthreads();
  }
#pragma unroll
  for (int mi = 0; mi < 4; ++mi)
#pragma unroll
    for (int ni = 0; ni < 4; ++ni)
#pragma unroll
      for (int r = 0; r < 4; ++r) {
        const int row = m0 + wr * 64 + mi * 16 + kg * 4 + r;
        const int col = wc * 64 + ni * 16 + lr;
        atomicAdd(&Cf[(size_t)row * FEWN + col], acc[mi][ni][r]);
      }
}

// generic (EPI: 2 = bf16(acc) -> Cb ; 3 = acc -> Cf)
template<int EPI>
__launch_bounds__(256)
__global__ void gemm_bt(const ushort_t* __restrict__ A, const ushort_t* __restrict__ B,
                        float* __restrict__ Cf, ushort_t* __restrict__ Cb,
                        int K, int lda, int ldb, int ldc) {
  GEMM_PROLOG()
#pragma unroll
  for (int mi = 0; mi < 4; ++mi)
#pragma unroll
    for (int ni = 0; ni < 4; ++ni)
#pragma unroll
      for (int r = 0; r < 4; ++r) {
        const int row = m0 + wr * 64 + mi * 16 + kg * 4 + r;
        const int col = n0 + wc * 64 + ni * 16 + lr;
        const float v = acc[mi][ni][r];
        const size_t o = (size_t)row * ldc + col;
        if (EPI == 2) Cb[o] = f2bf(v);
        else          Cf[o] = v;
      }
}

__global__ void softmax_kernel(const float* __restrict__ logits, ushort_t* __restrict__ attn) {
  const int row = blockIdx.x * 4 + (threadIdx.x >> 6);
  const int lane = threadIdx.x & 63;
  const float* L = logits + (size_t)row * FEWN;
  const float x0 = L[lane], x1 = L[lane + 64];
  float m = fmaxf(x0, x1);
#pragma unroll
  for (int s = 32; s > 0; s >>= 1) m = fmaxf(m, __shfl_xor(m, s));
  const float e0 = __expf(x0 - m), e1 = __expf(x1 - m);
  float sum = e0 + e1;
#pragma unroll
  for (int s = 32; s > 0; s >>= 1) sum += __shfl_xor(sum, s);
  const float inv = 1.f / sum;
  attn[(size_t)row * FEWN + lane]      = f2bf(e0 * inv);
  attn[(size_t)row * FEWN + lane + 64] = f2bf(e1 * inv);
}

// wcomb [8192][512]: rows 0-4095 = bf16(W_ih[og]); 4096-8191 = bf16(W_ih[og]+W_hhL[og])
__global__ void build_wcomb(const float* __restrict__ Wih, const float* __restrict__ Whh,
                            ushort_t* __restrict__ out) {
  const int idx = blockIdx.x * 256 + threadIdx.x;  // 8192*512
  const int r = idx >> 9, cc = idx & 511;
  ushort_t v;
  if (r < 4096) {
    v = f2bf(Wih[(size_t)orig_row(r) * 512 + cc]);
  } else {
    const int og = orig_row(r - 4096);
    v = f2bf(Wih[(size_t)og * 512 + cc] + Whh[(size_t)og * 1024 + cc]);
  }
  out[idx] = v;
}

// whhP[r][k] = bf16(W_hh[orig(r)][k]), K=1024
__global__ void build_whhP(const float* __restrict__ W, ushort_t* __restrict__ out) {
  const int idx = blockIdx.x * 256 + threadIdx.x;  // 4096*1024
  const int r = idx >> 10, k = idx & 1023;
  out[idx] = f2bf(W[(size_t)orig_row(r) * 1024 + k]);
}

// Q_cat [4096][1536] = [q_hi, q_lo, q_hi]
__global__ void build_qcat(const float* __restrict__ q, ushort_t* __restrict__ out) {
  const int idx = blockIdx.x * 256 + threadIdx.x;  // 4096*512
  const int b = idx >> 9, cc = idx & 511;
  const float v = q[idx];
  const ushort_t hi = f2bf(v);
  const ushort_t lo = f2bf(v - bf2f(hi));
  const size_t ro = (size_t)b * 1536;
  out[ro + cc] = hi;
  out[ro + 512 + cc] = lo;
  out[ro + 1024 + cc] = hi;
}

// B_cat [128][1536] = [s_hi, s_hi, s_lo]
__global__ void build_bcat(const float* __restrict__ s, ushort_t* __restrict__ out) {
  const int idx = blockIdx.x * 256 + threadIdx.x;  // 128*512
  const int n = idx >> 9, cc = idx & 511;
  const float v = s[idx];
  const ushort_t hi = f2bf(v);
  const ushort_t lo = f2bf(v - bf2f(hi));
  const size_t ro = (size_t)n * 1536;
  out[ro + cc] = hi;
  out[ro + 512 + cc] = hi;
  out[ro + 1024 + cc] = lo;
}

// support [128][512] f32 -> supT [512][128] bf16
__global__ void transp_kernel(const float* __restrict__ in, ushort_t* __restrict__ outT) {
  const int idx = blockIdx.x * 256 + threadIdx.x;  // 65536
  const int r = idx >> 9, colv = idx & 511;
  outT[colv * FEWN + r] = f2bf(in[idx]);
}

extern "C" void kernel_launch(void* const* d_in, const int* in_sizes, int n_in,
                              void* d_out, int out_size, void* d_ws, size_t ws_size,
                              hipStream_t stream) {
  const float* support = (const float*)d_in[0];
  const float* query   = (const float*)d_in[1];
  const float* W_ih    = (const float*)d_in[2];
  const float* W_hh    = (const float*)d_in[3];
  const float* b_ih    = (const float*)d_in[4];
  const float* b_hh    = (const float*)d_in[5];
  float* out = (float*)d_out;

  char* ws = (char*)d_ws;
  size_t off = 0;
  auto alloc = [&](size_t bytes) { char* p = ws + off; off += (bytes + 255) & ~255ull; return p; };
  ushort_t* gates_baseP = (ushort_t*)alloc((size_t)BATCH * GDIM * 2);   // 32MB bf16
  ushort_t* cbuf        = (ushort_t*)alloc((size_t)BATCH * HDIM * 2);   // 8MB bf16
  ushort_t* A1a         = (ushort_t*)alloc((size_t)BATCH * HDIM * 2);   // 8MB  [hi | r]
  ushort_t* A1b         = (ushort_t*)alloc((size_t)BATCH * HDIM * 2);   // 8MB
  ushort_t* A2a         = (ushort_t*)alloc((size_t)BATCH * DDIM * 2);   // 4MB  lo
  ushort_t* A2b         = (ushort_t*)alloc((size_t)BATCH * DDIM * 2);   // 4MB
  ushort_t* Q_cat       = (ushort_t*)alloc((size_t)BATCH * 1536 * 2);   // 12MB
  ushort_t* wcomb       = (ushort_t*)alloc((size_t)8192 * 512 * 2);     // 8MB
  ushort_t* whhP        = (ushort_t*)alloc((size_t)GDIM * HDIM * 2);    // 8MB
  ushort_t* B_cat       = (ushort_t*)alloc((size_t)FEWN * 1536 * 2);
  ushort_t* supT_bf     = (ushort_t*)alloc((size_t)DDIM * FEWN * 2);
  float*    logits_base = (float*)   alloc((size_t)BATCH * FEWN * 4);
  float*    logits      = (float*)   alloc((size_t)BATCH * FEWN * 4);
  ushort_t* attn        = (ushort_t*)alloc((size_t)BATCH * FEWN * 2);

  const dim3 blk(256);

  // ---- setup ----
  build_wcomb<<<8192 * 512 / 256, blk, 0, stream>>>(W_ih, W_hh, wcomb);
  build_whhP<<<GDIM * 1024 / 256, blk, 0, stream>>>(W_hh, whhP);
  build_qcat<<<BATCH * 512 / 256, blk, 0, stream>>>(query, Q_cat);
  build_bcat<<<FEWN * 512 / 256, blk, 0, stream>>>(support, B_cat);
  transp_kernel<<<FEWN * DDIM / 256, blk, 0, stream>>>(support, supT_bf);

  // logits_base = Q_cat @ B_cat^T (split-precision q@s^T, one-time)
  gemm_bt<3><<<dim3(1, 32), blk, 0, stream>>>(Q_cat, B_cat, logits_base, nullptr,
                                              1536, 1536, 1536, FEWN);

  // wide GEMM (K=512): left = step-0 gates + cell0 (cbuf, A1a, A2a); right = gates_baseP
  gemm_wide<<<dim3(64, 32), blk, 0, stream>>>(
      Q_cat, wcomb, gates_baseP, cbuf, A1a, A2a, b_ih, b_hh);

  auto attn_phase = [&](ushort_t* A1, ushort_t* A2) {
    hipMemcpyAsync(logits, logits_base, (size_t)BATCH * FEWN * 4,
                   hipMemcpyDeviceToDevice, stream);
    gemm_logits_splitk<<<dim3(3, 32), blk, 0, stream>>>(A1, A2, B_cat, logits);
    softmax_kernel<<<BATCH / 4, blk, 0, stream>>>(logits, attn);
    gemm_bt<2><<<dim3(4, 32), blk, 0, stream>>>(attn, supT_bf, nullptr, A1 + DDIM,
                                                FEWN, FEWN, FEWN, HDIM);
  };

  attn_phase(A1a, A2a);

  // step 1: read A1a -> write A1b/A2b (ping-pong)
  gemm_fused<1><<<dim3(32, 32), blk, 0, stream>>>(
      A1a, whhP, gates_baseP, cbuf, A1b, A2b, nullptr, nullptr, 1024, 1024, 1024);
  attn_phase(A1b, A2b);

  // step 2: read A1b -> write A1a/A2a
  gemm_fused<1><<<dim3(32, 32), blk, 0, stream>>>(
      A1b, whhP, gates_baseP, cbuf, A1a, A2a, nullptr, nullptr, 1024, 1024, 1024);
  attn_phase(A1a, A2a);

  // step 3 (last): only j<512 -> half grid; out = query + hr
  gemm_fused<2><<<dim3(16, 32), blk, 0, stream>>>(
      A1a, whhP, gates_baseP, cbuf, nullptr, nullptr, query, out, 1024, 1024, 1024);
}

// Round 12
// 357.897 us; speedup vs baseline: 1.6213x; 1.0837x over previous
//
#include <hip/hip_runtime.h>

#define BATCH 4096
#define DDIM  512
#define HDIM  1024
#define GDIM  4096
#define FEWN  128

typedef unsigned short ushort_t;
typedef __attribute__((ext_vector_type(8))) short bf16x8;
typedef __attribute__((ext_vector_type(4))) float f32x4;

__device__ inline ushort_t f2bf(float f) {
  unsigned u = __float_as_uint(f);
  unsigned r = (u + 0x7FFFu + ((u >> 16) & 1u)) >> 16;
  return (ushort_t)r;
}
__device__ inline float bf2f(ushort_t h) { return __uint_as_float((unsigned)h << 16); }

__device__ inline float sigmoidf(float x) { return 1.f / (1.f + __expf(-x)); }
__device__ inline float tanh_fast(float x) {
  float ax = fabsf(x);
  float t = __expf(-2.f * ax);
  float r = (1.f - t) / (1.f + t);
  return copysignf(r, x);
}

// permuted gate layout: col' -> original W row; gate g of j at col' with ((col'>>4)&3)=g
__device__ inline int orig_row(int colp) {
  return ((colp >> 4) & 3) * 1024 + ((colp >> 6) << 4) + (colp & 15);
}

__device__ inline void async_copy16(ushort_t* lds, const ushort_t* g) {
  __builtin_amdgcn_global_load_lds(
      (const __attribute__((address_space(1))) unsigned int*)g,
      (__attribute__((address_space(3))) unsigned int*)lds, 16, 0, 0);
}

// XCD-aware swizzle. gx%8==0: column-slice; else bijective 1D (m204).
#define XCD_SWZ()                                                            \
  int bx = blockIdx.x, by = blockIdx.y;                                      \
  {                                                                          \
    const int gx = gridDim.x;                                                \
    const int id = by * gx + bx;                                             \
    if ((gx & 7) == 0) {                                                     \
      const int cpx = gx >> 3;                                               \
      const int x = id & 7, s = id >> 3;                                     \
      bx = x * cpx + (s % cpx);                                              \
      by = s / cpx;                                                          \
    } else {                                                                 \
      const int nwg = gx * gridDim.y;                                        \
      const int qq = nwg >> 3, rr = nwg & 7;                                 \
      const int x = id & 7, s = id >> 3;                                     \
      const int nid = (x < rr ? x * (qq + 1) : rr * (qq + 1) + (x - rr) * qq) + s; \
      bx = nid % gx; by = nid / gx;                                          \
    }                                                                        \
  }

// ---- shared K-loop: BK=64 as two [128][32] halves (byte-layout identical to the
// verified BK=32 tile per half); one barrier pair per 64-K. LDS 32 KB/block.
#define GEMM_PROLOG()                                                        \
  __shared__ __align__(16) ushort_t lA[2 * 128 * 32];                        \
  __shared__ __align__(16) ushort_t lB[2 * 128 * 32];                        \
  const int tid = threadIdx.x;                                               \
  const int wid = tid >> 6, lane = tid & 63;                                 \
  const int wr = wid >> 1, wc = wid & 1;                                     \
  XCD_SWZ()                                                                  \
  const int m0 = by * 128, n0 = bx * 128;                                    \
  const int lr = lane & 15, kg = lane >> 4;                                  \
  f32x4 acc[4][4] = {};                                                      \
  const int srow = lane >> 2;                                                \
  const int scol = (lane & 3) * 8;                                           \
  const ushort_t* gA0 = A + (size_t)(m0 + wid * 32 + srow) * lda + scol;     \
  const ushort_t* gB0 = B + (size_t)(n0 + wid * 32 + srow) * ldb + scol;     \
  ushort_t* sA = &lA[wid * 1024];                                            \
  ushort_t* sB = &lB[wid * 1024];                                            \
  const int nIter = K >> 6;                                                  \
  for (int kt = 0; kt < nIter; ++kt) {                                       \
    const int k0 = kt << 6;                                                  \
    async_copy16(sA,              gA0 + k0);                                 \
    async_copy16(sA + 512,        gA0 + (size_t)16 * lda + k0);              \
    async_copy16(sA + 4096,       gA0 + k0 + 32);                            \
    async_copy16(sA + 4096 + 512, gA0 + (size_t)16 * lda + k0 + 32);         \
    async_copy16(sB,              gB0 + k0);                                 \
    async_copy16(sB + 512,        gB0 + (size_t)16 * ldb + k0);              \
    async_copy16(sB + 4096,       gB0 + k0 + 32);                            \
    async_copy16(sB + 4096 + 512, gB0 + (size_t)16 * ldb + k0 + 32);         \
    __syncthreads();                                                         \
    _Pragma("unroll")                                                        \
    for (int h = 0; h < 2; ++h) {                                            \
      bf16x8 af[4], bfr[4];                                                  \
      _Pragma("unroll")                                                      \
      for (int mi = 0; mi < 4; ++mi)                                         \
        af[mi] = *(const bf16x8*)&lA[h * 4096 + (wr * 64 + mi * 16 + lr) * 32 + kg * 8]; \
      _Pragma("unroll")                                                      \
      for (int ni = 0; ni < 4; ++ni)                                         \
        bfr[ni] = *(const bf16x8*)&lB[h * 4096 + (wc * 64 + ni * 16 + lr) * 32 + kg * 8]; \
      _Pragma("unroll")                                                      \
      for (int mi = 0; mi < 4; ++mi)                                         \
        _Pragma("unroll")                                                    \
        for (int ni = 0; ni < 4; ++ni)                                       \
          acc[mi][ni] = __builtin_amdgcn_mfma_f32_16x16x32_bf16(af[mi], bfr[ni], acc[mi][ni], 0, 0, 0); \
    }                                                                        \
    __syncthreads();                                                         \
  }

// Wide GEMM: C = q_hi @ [wihP | wsumP]^T, N=8192, K=512.
// Left half (n0<4096): step-0 gates -> cell0 in epilogue (c f32, A1.hi, A2.lo).
// Right half: gates_baseP = bf16(acc + bias).
__launch_bounds__(256)
__global__ void gemm_wide(const ushort_t* __restrict__ A, const ushort_t* __restrict__ B,
                          ushort_t* __restrict__ gbase, float* __restrict__ c,
                          ushort_t* __restrict__ A1out, ushort_t* __restrict__ A2out,
                          const float* __restrict__ b1, const float* __restrict__ b2,
                          int K, int lda, int ldb) {
  GEMM_PROLOG()
  if (n0 < 4096) {
    const int jj = ((n0 + wc * 64) >> 6) * 16 + lr;   // 0..1023
    const bool do_h = (n0 + wc * 64) < 2048;          // j < 512
    const float bi0 = b1[jj]        + b2[jj];
    const float bi2 = b1[2048 + jj] + b2[2048 + jj];
    const float bi3 = b1[3072 + jj] + b2[3072 + jj];
#pragma unroll
    for (int mi = 0; mi < 4; ++mi) {
#pragma unroll
      for (int r = 0; r < 4; ++r) {
        const int row = m0 + wr * 64 + mi * 16 + kg * 4 + r;
        const float si = sigmoidf(acc[mi][0][r] + bi0);
        const float tg = tanh_fast(acc[mi][2][r] + bi2);
        const float so = sigmoidf(acc[mi][3][r] + bi3);
        const float cn = si * tg;                      // c_prev = 0
        c[(size_t)row * HDIM + jj] = cn;
        if (do_h) {
          const float hr = so * tanh_fast(cn);
          const ushort_t hi = f2bf(hr);
          const ushort_t lo = f2bf(hr - bf2f(hi));
          A1out[(size_t)row * HDIM + jj] = hi;
          A2out[(size_t)row * DDIM + jj] = lo;
        }
      }
    }
  } else {
    const int nloc = n0 - 4096;
#pragma unroll
    for (int mi = 0; mi < 4; ++mi)
#pragma unroll
      for (int ni = 0; ni < 4; ++ni)
#pragma unroll
        for (int r = 0; r < 4; ++r) {
          const int row = m0 + wr * 64 + mi * 16 + kg * 4 + r;
          const int col = nloc + wc * 64 + ni * 16 + lr;
          const int og = orig_row(col);
          gbase[(size_t)row * GDIM + col] = f2bf(acc[mi][ni][r] + b1[og] + b2[og]);
        }
  }
}

// Fused recurrent GEMM + LSTM cell. base bf16, c f32.
// MODE 1: cell -> c, A1.hi, A2.lo.  MODE 2: out = query + hr (grid.x = 16).
template<int MODE>
__launch_bounds__(256)
__global__ void gemm_fused(const ushort_t* __restrict__ A, const ushort_t* __restrict__ B,
                           const ushort_t* __restrict__ base, float* __restrict__ c,
                           ushort_t* __restrict__ A1out, ushort_t* __restrict__ A2out,
                           const float* __restrict__ query, float* __restrict__ out,
                           int K, int lda, int ldb) {
  GEMM_PROLOG()
  const int jj = ((n0 + wc * 64) >> 6) * 16 + lr;
  const bool do_h = (MODE == 2) || ((n0 + wc * 64) < 2048);
#pragma unroll
  for (int mi = 0; mi < 4; ++mi) {
#pragma unroll
    for (int r = 0; r < 4; ++r) {
      const int row = m0 + wr * 64 + mi * 16 + kg * 4 + r;
      const size_t o0 = (size_t)row * GDIM + n0 + wc * 64 + lr;
      const float g0 = bf2f(base[o0])      + acc[mi][0][r];
      const float g1 = bf2f(base[o0 + 16]) + acc[mi][1][r];
      const float g2 = bf2f(base[o0 + 32]) + acc[mi][2][r];
      const float g3 = bf2f(base[o0 + 48]) + acc[mi][3][r];
      const float si = sigmoidf(g0);
      const float sf = sigmoidf(g1);
      const float tg = tanh_fast(g2);
      const float so = sigmoidf(g3);
      const size_t ci = (size_t)row * HDIM + jj;
      const float cn = sf * c[ci] + si * tg;
      if (MODE != 2) c[ci] = cn;
      if (do_h) {
        const float hr = so * tanh_fast(cn);
        if (MODE == 2) {
          out[(size_t)row * DDIM + jj] = query[(size_t)row * DDIM + jj] + hr;
        } else {
          const ushort_t hi = f2bf(hr);
          const ushort_t lo = f2bf(hr - bf2f(hi));
          A1out[(size_t)row * HDIM + jj] = hi;
          A2out[(size_t)row * DDIM + jj] = lo;
        }
      }
    }
  }
}

// Split-K logits: grid (3, 32), DEDICATED body (no XCD swizzle, no n0 in B rows).
// chunk k: A-seg {A1.hi, A2.lo, A1.hi} x B-seg {s_hi, s_hi, s_lo};
// atomicAdd into logits (pre-filled with logits_base). B rows 0..127 only.
__launch_bounds__(256)
__global__ void gemm_logits_splitk(const ushort_t* __restrict__ A1, const ushort_t* __restrict__ A2,
                                   const ushort_t* __restrict__ Bc, float* __restrict__ Cf) {
  __shared__ __align__(16) ushort_t lA[2 * 128 * 32];
  __shared__ __align__(16) ushort_t lB[2 * 128 * 32];
  const int tid = threadIdx.x;
  const int wid = tid >> 6, lane = tid & 63;
  const int wr = wid >> 1, wc = wid & 1;
  const int chunk = blockIdx.x;          // 0..2
  const int m0 = blockIdx.y * 128;
  const int lr = lane & 15, kg = lane >> 4;
  f32x4 acc[4][4] = {};
  const int srow = lane >> 2;
  const int scol = (lane & 3) * 8;
  const ushort_t* A = (chunk == 1) ? A2 : A1;
  const int lda = (chunk == 1) ? 512 : 1024;
  const ushort_t* gA0 = A + (size_t)(m0 + wid * 32 + srow) * lda + scol;
  const ushort_t* gB0 = Bc + (size_t)(wid * 32 + srow) * 1536 + chunk * 512 + scol;
  ushort_t* sA = &lA[wid * 1024];
  ushort_t* sB = &lB[wid * 1024];
  for (int kt = 0; kt < 8; ++kt) {       // K=512, BK=64
    const int k0 = kt << 6;
    async_copy16(sA,              gA0 + k0);
    async_copy16(sA + 512,        gA0 + (size_t)16 * lda + k0);
    async_copy16(sA + 4096,       gA0 + k0 + 32);
    async_copy16(sA + 4096 + 512, gA0 + (size_t)16 * lda + k0 + 32);
    async_copy16(sB,              gB0 + k0);
    async_copy16(sB + 512,        gB0 + (size_t)16 * 1536 + k0);
    async_copy16(sB + 4096,       gB0 + k0 + 32);
    async_copy16(sB + 4096 + 512, gB0 + (size_t)16 * 1536 + k0 + 32);
    __syncthreads();
#pragma unroll
    for (int h = 0; h < 2; ++h) {
      bf16x8 af[4], bfr[4];
#pragma unroll
      for (int mi = 0; mi < 4; ++mi)
        af[mi] = *(const bf16x8*)&lA[h * 4096 + (wr * 64 + mi * 16 + lr) * 32 + kg * 8];
#pragma unroll
      for (int ni = 0; ni < 4; ++ni)
        bfr[ni] = *(const bf16x8*)&lB[h * 4096 + (wc * 64 + ni * 16 + lr) * 32 + kg * 8];
#pragma unroll
      for (int mi = 0; mi < 4; ++mi)
#pragma unroll
        for (int ni = 0; ni < 4; ++ni)
          acc[mi][ni] = __builtin_amdgcn_mfma_f32_16x16x32_bf16(af[mi], bfr[ni], acc[mi][ni], 0, 0, 0);
    }
    __syncthreads();
  }
#pragma unroll
  for (int mi = 0; mi < 4; ++mi)
#pragma unroll
    for (int ni = 0; ni < 4; ++ni)
#pragma unroll
      for (int r = 0; r < 4; ++r) {
        const int row = m0 + wr * 64 + mi * 16 + kg * 4 + r;
        const int col = wc * 64 + ni * 16 + lr;
        atomicAdd(&Cf[(size_t)row * FEWN + col], acc[mi][ni][r]);
      }
}

// generic (EPI: 2 = bf16(acc) -> Cb ; 3 = acc -> Cf)
template<int EPI>
__launch_bounds__(256)
__global__ void gemm_bt(const ushort_t* __restrict__ A, const ushort_t* __restrict__ B,
                        float* __restrict__ Cf, ushort_t* __restrict__ Cb,
                        int K, int lda, int ldb, int ldc) {
  GEMM_PROLOG()
#pragma unroll
  for (int mi = 0; mi < 4; ++mi)
#pragma unroll
    for (int ni = 0; ni < 4; ++ni)
#pragma unroll
      for (int r = 0; r < 4; ++r) {
        const int row = m0 + wr * 64 + mi * 16 + kg * 4 + r;
        const int col = n0 + wc * 64 + ni * 16 + lr;
        const float v = acc[mi][ni][r];
        const size_t o = (size_t)row * ldc + col;
        if (EPI == 2) Cb[o] = f2bf(v);
        else          Cf[o] = v;
      }
}

__global__ void softmax_kernel(const float* __restrict__ logits, ushort_t* __restrict__ attn) {
  const int row = blockIdx.x * 4 + (threadIdx.x >> 6);
  const int lane = threadIdx.x & 63;
  const float* L = logits + (size_t)row * FEWN;
  const float x0 = L[lane], x1 = L[lane + 64];
  float m = fmaxf(x0, x1);
#pragma unroll
  for (int s = 32; s > 0; s >>= 1) m = fmaxf(m, __shfl_xor(m, s));
  const float e0 = __expf(x0 - m), e1 = __expf(x1 - m);
  float sum = e0 + e1;
#pragma unroll
  for (int s = 32; s > 0; s >>= 1) sum += __shfl_xor(sum, s);
  const float inv = 1.f / sum;
  attn[(size_t)row * FEWN + lane]      = f2bf(e0 * inv);
  attn[(size_t)row * FEWN + lane + 64] = f2bf(e1 * inv);
}

// wcomb [8192][512]: rows 0-4095 = bf16(W_ih[og]); 4096-8191 = bf16(W_ih[og]+W_hhL[og])
__global__ void build_wcomb(const float* __restrict__ Wih, const float* __restrict__ Whh,
                            ushort_t* __restrict__ out) {
  const int idx = blockIdx.x * 256 + threadIdx.x;  // 8192*512
  const int r = idx >> 9, cc = idx & 511;
  ushort_t v;
  if (r < 4096) {
    v = f2bf(Wih[(size_t)orig_row(r) * 512 + cc]);
  } else {
    const int og = orig_row(r - 4096);
    v = f2bf(Wih[(size_t)og * 512 + cc] + Whh[(size_t)og * 1024 + cc]);
  }
  out[idx] = v;
}

// whhP[r][k] = bf16(W_hh[orig(r)][k]), K=1024
__global__ void build_whhP(const float* __restrict__ W, ushort_t* __restrict__ out) {
  const int idx = blockIdx.x * 256 + threadIdx.x;  // 4096*1024
  const int r = idx >> 10, k = idx & 1023;
  out[idx] = f2bf(W[(size_t)orig_row(r) * 1024 + k]);
}

// Q_cat [4096][1536] = [q_hi, q_lo, q_hi]
__global__ void build_qcat(const float* __restrict__ q, ushort_t* __restrict__ out) {
  const int idx = blockIdx.x * 256 + threadIdx.x;  // 4096*512
  const int b = idx >> 9, cc = idx & 511;
  const float v = q[idx];
  const ushort_t hi = f2bf(v);
  const ushort_t lo = f2bf(v - bf2f(hi));
  const size_t ro = (size_t)b * 1536;
  out[ro + cc] = hi;
  out[ro + 512 + cc] = lo;
  out[ro + 1024 + cc] = hi;
}

// B_cat [128][1536] = [s_hi, s_hi, s_lo]
__global__ void build_bcat(const float* __restrict__ s, ushort_t* __restrict__ out) {
  const int idx = blockIdx.x * 256 + threadIdx.x;  // 128*512
  const int n = idx >> 9, cc = idx & 511;
  const float v = s[idx];
  const ushort_t hi = f2bf(v);
  const ushort_t lo = f2bf(v - bf2f(hi));
  const size_t ro = (size_t)n * 1536;
  out[ro + cc] = hi;
  out[ro + 512 + cc] = hi;
  out[ro + 1024 + cc] = lo;
}

// support [128][512] f32 -> supT [512][128] bf16
__global__ void transp_kernel(const float* __restrict__ in, ushort_t* __restrict__ outT) {
  const int idx = blockIdx.x * 256 + threadIdx.x;  // 65536
  const int r = idx >> 9, colv = idx & 511;
  outT[colv * FEWN + r] = f2bf(in[idx]);
}

extern "C" void kernel_launch(void* const* d_in, const int* in_sizes, int n_in,
                              void* d_out, int out_size, void* d_ws, size_t ws_size,
                              hipStream_t stream) {
  const float* support = (const float*)d_in[0];
  const float* query   = (const float*)d_in[1];
  const float* W_ih    = (const float*)d_in[2];
  const float* W_hh    = (const float*)d_in[3];
  const float* b_ih    = (const float*)d_in[4];
  const float* b_hh    = (const float*)d_in[5];
  float* out = (float*)d_out;

  char* ws = (char*)d_ws;
  size_t off = 0;
  auto alloc = [&](size_t bytes) { char* p = ws + off; off += (bytes + 255) & ~255ull; return p; };
  ushort_t* gates_baseP = (ushort_t*)alloc((size_t)BATCH * GDIM * 2);   // 32MB bf16
  float*    cbuf        = (float*)   alloc((size_t)BATCH * HDIM * 4);   // 16MB f32
  ushort_t* A1a         = (ushort_t*)alloc((size_t)BATCH * HDIM * 2);   // 8MB  [hi | r]
  ushort_t* A1b         = (ushort_t*)alloc((size_t)BATCH * HDIM * 2);   // 8MB
  ushort_t* A2a         = (ushort_t*)alloc((size_t)BATCH * DDIM * 2);   // 4MB  lo
  ushort_t* A2b         = (ushort_t*)alloc((size_t)BATCH * DDIM * 2);   // 4MB
  ushort_t* Q_cat       = (ushort_t*)alloc((size_t)BATCH * 1536 * 2);   // 12MB
  ushort_t* wcomb       = (ushort_t*)alloc((size_t)8192 * 512 * 2);     // 8MB
  ushort_t* whhP        = (ushort_t*)alloc((size_t)GDIM * HDIM * 2);    // 8MB
  ushort_t* B_cat       = (ushort_t*)alloc((size_t)FEWN * 1536 * 2);
  ushort_t* supT_bf     = (ushort_t*)alloc((size_t)DDIM * FEWN * 2);
  float*    logits_base = (float*)   alloc((size_t)BATCH * FEWN * 4);
  float*    logits      = (float*)   alloc((size_t)BATCH * FEWN * 4);
  ushort_t* attn        = (ushort_t*)alloc((size_t)BATCH * FEWN * 2);

  const dim3 blk(256);

  // ---- setup ----
  build_wcomb<<<8192 * 512 / 256, blk, 0, stream>>>(W_ih, W_hh, wcomb);
  build_whhP<<<GDIM * 1024 / 256, blk, 0, stream>>>(W_hh, whhP);
  build_qcat<<<BATCH * 512 / 256, blk, 0, stream>>>(query, Q_cat);
  build_bcat<<<FEWN * 512 / 256, blk, 0, stream>>>(support, B_cat);
  transp_kernel<<<FEWN * DDIM / 256, blk, 0, stream>>>(support, supT_bf);

  // logits_base = Q_cat @ B_cat^T (split-precision q@s^T, one-time)
  gemm_bt<3><<<dim3(1, 32), blk, 0, stream>>>(Q_cat, B_cat, logits_base, nullptr,
                                              1536, 1536, 1536, FEWN);

  // wide GEMM (K=512): left = step-0 gates + cell0 (cbuf f32, A1a, A2a); right = gates_baseP
  gemm_wide<<<dim3(64, 32), blk, 0, stream>>>(
      Q_cat, wcomb, gates_baseP, cbuf, A1a, A2a, b_ih, b_hh, 512, 1536, 512);

  auto attn_phase = [&](ushort_t* A1, ushort_t* A2) {
    hipMemcpyAsync(logits, logits_base, (size_t)BATCH * FEWN * 4,
                   hipMemcpyDeviceToDevice, stream);
    gemm_logits_splitk<<<dim3(3, 32), blk, 0, stream>>>(A1, A2, B_cat, logits);
    softmax_kernel<<<BATCH / 4, blk, 0, stream>>>(logits, attn);
    gemm_bt<2><<<dim3(4, 32), blk, 0, stream>>>(attn, supT_bf, nullptr, A1 + DDIM,
                                                FEWN, FEWN, FEWN, HDIM);
  };

  attn_phase(A1a, A2a);

  // step 1: read A1a -> write A1b/A2b (ping-pong)
  gemm_fused<1><<<dim3(32, 32), blk, 0, stream>>>(
      A1a, whhP, gates_baseP, cbuf, A1b, A2b, nullptr, nullptr, 1024, 1024, 1024);
  attn_phase(A1b, A2b);

  // step 2: read A1b -> write A1a/A2a
  gemm_fused<1><<<dim3(32, 32), blk, 0, stream>>>(
      A1b, whhP, gates_baseP, cbuf, A1a, A2a, nullptr, nullptr, 1024, 1024, 1024);
  attn_phase(A1a, A2a);

  // step 3 (last): only j<512 -> half grid; out = query + hr
  gemm_fused<2><<<dim3(16, 32), blk, 0, stream>>>(
      A1a, whhP, gates_baseP, cbuf, nullptr, nullptr, query, out, 1024, 1024, 1024);
}

// Round 13
// 305.512 us; speedup vs baseline: 1.8993x; 1.1715x over previous
//
#include <hip/hip_runtime.h>

#define BATCH 4096
#define DDIM  512
#define HDIM  1024
#define GDIM  4096
#define FEWN  128
#define LDA1  640     // A1 = [hr'(512) | attn(128)]

typedef unsigned short ushort_t;
typedef __attribute__((ext_vector_type(8))) short bf16x8;
typedef __attribute__((ext_vector_type(4))) float f32x4;

__device__ inline ushort_t f2bf(float f) {
  unsigned u = __float_as_uint(f);
  unsigned r = (u + 0x7FFFu + ((u >> 16) & 1u)) >> 16;
  return (ushort_t)r;
}
__device__ inline float bf2f(ushort_t h) { return __uint_as_float((unsigned)h << 16); }
__device__ inline float bf2f_u(unsigned h16) { return __uint_as_float(h16 << 16); }

__device__ inline float sigmoidf(float x) { return 1.f / (1.f + __expf(-x)); }
__device__ inline float tanh_fast(float x) {
  float ax = fabsf(x);
  float t = __expf(-2.f * ax);
  float r = (1.f - t) / (1.f + t);
  return copysignf(r, x);
}

// permuted gate layout: col' -> original W row; gate g of j at col' with ((col'>>4)&3)=g
__device__ inline int orig_row(int colp) {
  return ((colp >> 4) & 3) * 1024 + ((colp >> 6) << 4) + (colp & 15);
}

__device__ inline void async_copy16(ushort_t* lds, const ushort_t* g) {
  __builtin_amdgcn_global_load_lds(
      (const __attribute__((address_space(1))) unsigned int*)g,
      (__attribute__((address_space(3))) unsigned int*)lds, 16, 0, 0);
}

// XCD-aware swizzle. gx%8==0: column-slice; else bijective 1D (m204).
#define XCD_SWZ()                                                            \
  int bx = blockIdx.x, by = blockIdx.y;                                      \
  {                                                                          \
    const int gx = gridDim.x;                                                \
    const int id = by * gx + bx;                                             \
    if ((gx & 7) == 0) {                                                     \
      const int cpx = gx >> 3;                                               \
      const int x = id & 7, s = id >> 3;                                     \
      bx = x * cpx + (s % cpx);                                              \
      by = s / cpx;                                                          \
    } else {                                                                 \
      const int nwg = gx * gridDim.y;                                        \
      const int qq = nwg >> 3, rr = nwg & 7;                                 \
      const int x = id & 7, s = id >> 3;                                     \
      const int nid = (x < rr ? x * (qq + 1) : rr * (qq + 1) + (x - rr) * qq) + s; \
      bx = nid % gx; by = nid / gx;                                          \
    }                                                                        \
  }

// ---- shared K-loop: BK=64 as two [128][32] halves; one barrier pair per 64-K.
#define GEMM_PROLOG()                                                        \
  __shared__ __align__(16) ushort_t lA[2 * 128 * 32];                        \
  __shared__ __align__(16) ushort_t lB[2 * 128 * 32];                        \
  const int tid = threadIdx.x;                                               \
  const int wid = tid >> 6, lane = tid & 63;                                 \
  const int wr = wid >> 1, wc = wid & 1;                                     \
  XCD_SWZ()                                                                  \
  const int m0 = by * 128, n0 = bx * 128;                                    \
  const int lr = lane & 15, kg = lane >> 4;                                  \
  f32x4 acc[4][4] = {};                                                      \
  const int srow = lane >> 2;                                                \
  const int scol = (lane & 3) * 8;                                           \
  const ushort_t* gA0 = A + (size_t)(m0 + wid * 32 + srow) * lda + scol;     \
  const ushort_t* gB0 = B + (size_t)(n0 + wid * 32 + srow) * ldb + scol;     \
  ushort_t* sA = &lA[wid * 1024];                                            \
  ushort_t* sB = &lB[wid * 1024];                                            \
  const int nIter = K >> 6;                                                  \
  for (int kt = 0; kt < nIter; ++kt) {                                       \
    const int k0 = kt << 6;                                                  \
    async_copy16(sA,              gA0 + k0);                                 \
    async_copy16(sA + 512,        gA0 + (size_t)16 * lda + k0);              \
    async_copy16(sA + 4096,       gA0 + k0 + 32);                            \
    async_copy16(sA + 4096 + 512, gA0 + (size_t)16 * lda + k0 + 32);         \
    async_copy16(sB,              gB0 + k0);                                 \
    async_copy16(sB + 512,        gB0 + (size_t)16 * ldb + k0);              \
    async_copy16(sB + 4096,       gB0 + k0 + 32);                            \
    async_copy16(sB + 4096 + 512, gB0 + (size_t)16 * ldb + k0 + 32);         \
    __syncthreads();                                                         \
    _Pragma("unroll")                                                        \
    for (int h = 0; h < 2; ++h) {                                            \
      bf16x8 af[4], bfr[4];                                                  \
      _Pragma("unroll")                                                      \
      for (int mi = 0; mi < 4; ++mi)                                         \
        af[mi] = *(const bf16x8*)&lA[h * 4096 + (wr * 64 + mi * 16 + lr) * 32 + kg * 8]; \
      _Pragma("unroll")                                                      \
      for (int ni = 0; ni < 4; ++ni)                                         \
        bfr[ni] = *(const bf16x8*)&lB[h * 4096 + (wc * 64 + ni * 16 + lr) * 32 + kg * 8]; \
      _Pragma("unroll")                                                      \
      for (int mi = 0; mi < 4; ++mi)                                         \
        _Pragma("unroll")                                                    \
        for (int ni = 0; ni < 4; ++ni)                                       \
          acc[mi][ni] = __builtin_amdgcn_mfma_f32_16x16x32_bf16(af[mi], bfr[ni], acc[mi][ni], 0, 0, 0); \
    }                                                                        \
    __syncthreads();                                                         \
  }

// Wide GEMM: C = q_hi @ [wihP | wsumP]^T, N=8192, K=512.
// Left (n0<4096): step-0 gates -> cell0 (c f32, A1.hi lda640, A2.lo).
// Right: gates_base 4-gate-INTERLEAVED: gbase[row*4096 + jj*4 + g] (one 8B store).
__launch_bounds__(256)
__global__ void gemm_wide(const ushort_t* __restrict__ A, const ushort_t* __restrict__ B,
                          ushort_t* __restrict__ gbase, float* __restrict__ c,
                          ushort_t* __restrict__ A1out, ushort_t* __restrict__ A2out,
                          const float* __restrict__ b1, const float* __restrict__ b2,
                          int K, int lda, int ldb) {
  GEMM_PROLOG()
  if (n0 < 4096) {
    const int jj = ((n0 + wc * 64) >> 6) * 16 + lr;   // 0..1023
    const bool do_h = (n0 + wc * 64) < 2048;          // j < 512
    const float bi0 = b1[jj]        + b2[jj];
    const float bi2 = b1[2048 + jj] + b2[2048 + jj];
    const float bi3 = b1[3072 + jj] + b2[3072 + jj];
#pragma unroll
    for (int mi = 0; mi < 4; ++mi) {
#pragma unroll
      for (int r = 0; r < 4; ++r) {
        const int row = m0 + wr * 64 + mi * 16 + kg * 4 + r;
        const float si = sigmoidf(acc[mi][0][r] + bi0);
        const float tg = tanh_fast(acc[mi][2][r] + bi2);
        const float so = sigmoidf(acc[mi][3][r] + bi3);
        const float cn = si * tg;                      // c_prev = 0
        c[(size_t)row * HDIM + jj] = cn;
        if (do_h) {
          const float hr = so * tanh_fast(cn);
          const ushort_t hi = f2bf(hr);
          const ushort_t lo = f2bf(hr - bf2f(hi));
          A1out[(size_t)row * LDA1 + jj] = hi;
          A2out[(size_t)row * DDIM + jj] = lo;
        }
      }
    }
  } else {
    const int jj = ((n0 - 4096 + wc * 64) >> 6) * 16 + lr;  // 0..1023
    const float bi0 = b1[jj]        + b2[jj];
    const float bi1 = b1[1024 + jj] + b2[1024 + jj];
    const float bi2 = b1[2048 + jj] + b2[2048 + jj];
    const float bi3 = b1[3072 + jj] + b2[3072 + jj];
#pragma unroll
    for (int mi = 0; mi < 4; ++mi)
#pragma unroll
      for (int r = 0; r < 4; ++r) {
        const int row = m0 + wr * 64 + mi * 16 + kg * 4 + r;
        uint2 p;
        p.x = (unsigned)f2bf(acc[mi][0][r] + bi0) | ((unsigned)f2bf(acc[mi][1][r] + bi1) << 16);
        p.y = (unsigned)f2bf(acc[mi][2][r] + bi2) | ((unsigned)f2bf(acc[mi][3][r] + bi3) << 16);
        *(uint2*)&gbase[(size_t)row * GDIM + jj * 4] = p;
      }
  }
}

// Fused recurrent GEMM + LSTM cell. K=640: A=[hr'|attn], B=[WhhL|SW]. base interleaved.
// MODE 1: cell -> c, A1.hi, A2.lo.  MODE 2: out = query + hr (grid.x = 16).
template<int MODE>
__launch_bounds__(256)
__global__ void gemm_fused(const ushort_t* __restrict__ A, const ushort_t* __restrict__ B,
                           const ushort_t* __restrict__ base, float* __restrict__ c,
                           ushort_t* __restrict__ A1out, ushort_t* __restrict__ A2out,
                           const float* __restrict__ query, float* __restrict__ out,
                           int K, int lda, int ldb) {
  GEMM_PROLOG()
  const int jj = ((n0 + wc * 64) >> 6) * 16 + lr;
  const bool do_h = (MODE == 2) || ((n0 + wc * 64) < 2048);
#pragma unroll
  for (int mi = 0; mi < 4; ++mi) {
#pragma unroll
    for (int r = 0; r < 4; ++r) {
      const int row = m0 + wr * 64 + mi * 16 + kg * 4 + r;
      const uint2 p = *(const uint2*)&base[(size_t)row * GDIM + jj * 4];
      const float g0 = bf2f_u(p.x & 0xFFFFu) + acc[mi][0][r];
      const float g1 = bf2f_u(p.x >> 16)     + acc[mi][1][r];
      const float g2 = bf2f_u(p.y & 0xFFFFu) + acc[mi][2][r];
      const float g3 = bf2f_u(p.y >> 16)     + acc[mi][3][r];
      const float si = sigmoidf(g0);
      const float sf = sigmoidf(g1);
      const float tg = tanh_fast(g2);
      const float so = sigmoidf(g3);
      const size_t ci = (size_t)row * HDIM + jj;
      const float cn = sf * c[ci] + si * tg;
      if (MODE != 2) c[ci] = cn;
      if (do_h) {
        const float hr = so * tanh_fast(cn);
        if (MODE == 2) {
          out[(size_t)row * DDIM + jj] = query[(size_t)row * DDIM + jj] + hr;
        } else {
          const ushort_t hi = f2bf(hr);
          const ushort_t lo = f2bf(hr - bf2f(hi));
          A1out[(size_t)row * LDA1 + jj] = hi;
          A2out[(size_t)row * DDIM + jj] = lo;
        }
      }
    }
  }
}

// Split-K logits: grid (3, 32), dedicated body. chunk k: A-seg {A1.hi, A2.lo, A1.hi}
// x B-seg {s_hi, s_hi, s_lo}; atomicAdd into prefilled logits. B rows 0..127.
__launch_bounds__(256)
__global__ void gemm_logits_splitk(const ushort_t* __restrict__ A1, const ushort_t* __restrict__ A2,
                                   const ushort_t* __restrict__ Bc, float* __restrict__ Cf) {
  __shared__ __align__(16) ushort_t lA[2 * 128 * 32];
  __shared__ __align__(16) ushort_t lB[2 * 128 * 32];
  const int tid = threadIdx.x;
  const int wid = tid >> 6, lane = tid & 63;
  const int wr = wid >> 1, wc = wid & 1;
  const int chunk = blockIdx.x;          // 0..2
  const int m0 = blockIdx.y * 128;
  const int lr = lane & 15, kg = lane >> 4;
  f32x4 acc[4][4] = {};
  const int srow = lane >> 2;
  const int scol = (lane & 3) * 8;
  const ushort_t* A = (chunk == 1) ? A2 : A1;
  const int lda = (chunk == 1) ? DDIM : LDA1;
  const ushort_t* gA0 = A + (size_t)(m0 + wid * 32 + srow) * lda + scol;
  const ushort_t* gB0 = Bc + (size_t)(wid * 32 + srow) * 1536 + chunk * 512 + scol;
  ushort_t* sA = &lA[wid * 1024];
  ushort_t* sB = &lB[wid * 1024];
  for (int kt = 0; kt < 8; ++kt) {       // K=512, BK=64
    const int k0 = kt << 6;
    async_copy16(sA,              gA0 + k0);
    async_copy16(sA + 512,        gA0 + (size_t)16 * lda + k0);
    async_copy16(sA + 4096,       gA0 + k0 + 32);
    async_copy16(sA + 4096 + 512, gA0 + (size_t)16 * lda + k0 + 32);
    async_copy16(sB,              gB0 + k0);
    async_copy16(sB + 512,        gB0 + (size_t)16 * 1536 + k0);
    async_copy16(sB + 4096,       gB0 + k0 + 32);
    async_copy16(sB + 4096 + 512, gB0 + (size_t)16 * 1536 + k0 + 32);
    __syncthreads();
#pragma unroll
    for (int h = 0; h < 2; ++h) {
      bf16x8 af[4], bfr[4];
#pragma unroll
      for (int mi = 0; mi < 4; ++mi)
        af[mi] = *(const bf16x8*)&lA[h * 4096 + (wr * 64 + mi * 16 + lr) * 32 + kg * 8];
#pragma unroll
      for (int ni = 0; ni < 4; ++ni)
        bfr[ni] = *(const bf16x8*)&lB[h * 4096 + (wc * 64 + ni * 16 + lr) * 32 + kg * 8];
#pragma unroll
      for (int mi = 0; mi < 4; ++mi)
#pragma unroll
        for (int ni = 0; ni < 4; ++ni)
          acc[mi][ni] = __builtin_amdgcn_mfma_f32_16x16x32_bf16(af[mi], bfr[ni], acc[mi][ni], 0, 0, 0);
    }
    __syncthreads();
  }
#pragma unroll
  for (int mi = 0; mi < 4; ++mi)
#pragma unroll
    for (int ni = 0; ni < 4; ++ni)
#pragma unroll
      for (int r = 0; r < 4; ++r) {
        const int row = m0 + wr * 64 + mi * 16 + kg * 4 + r;
        const int col = wc * 64 + ni * 16 + lr;
        atomicAdd(&Cf[(size_t)row * FEWN + col], acc[mi][ni][r]);
      }
}

// generic: EPI 2 = bf16(acc) -> Cb ; EPI 4 = acc -> Cf, Cf+OFS, Cf+2*OFS (triple prefill)
template<int EPI>
__launch_bounds__(256)
__global__ void gemm_bt(const ushort_t* __restrict__ A, const ushort_t* __restrict__ B,
                        float* __restrict__ Cf, ushort_t* __restrict__ Cb,
                        int K, int lda, int ldb, int ldc) {
  GEMM_PROLOG()
  const size_t OFS = (size_t)BATCH * FEWN;
#pragma unroll
  for (int mi = 0; mi < 4; ++mi)
#pragma unroll
    for (int ni = 0; ni < 4; ++ni)
#pragma unroll
      for (int r = 0; r < 4; ++r) {
        const int row = m0 + wr * 64 + mi * 16 + kg * 4 + r;
        const int col = n0 + wc * 64 + ni * 16 + lr;
        const float v = acc[mi][ni][r];
        const size_t o = (size_t)row * ldc + col;
        if (EPI == 2) {
          Cb[o] = f2bf(v);
        } else {
          Cf[o] = v; Cf[o + OFS] = v; Cf[o + 2 * OFS] = v;
        }
      }
}

// softmax: reads logits row, writes attn bf16 directly into A1[:, 512:640]
__global__ void softmax_kernel(const float* __restrict__ logits, ushort_t* __restrict__ A1) {
  const int row = blockIdx.x * 4 + (threadIdx.x >> 6);
  const int lane = threadIdx.x & 63;
  const float* L = logits + (size_t)row * FEWN;
  const float x0 = L[lane], x1 = L[lane + 64];
  float m = fmaxf(x0, x1);
#pragma unroll
  for (int s = 32; s > 0; s >>= 1) m = fmaxf(m, __shfl_xor(m, s));
  const float e0 = __expf(x0 - m), e1 = __expf(x1 - m);
  float sum = e0 + e1;
#pragma unroll
  for (int s = 32; s > 0; s >>= 1) sum += __shfl_xor(sum, s);
  const float inv = 1.f / sum;
  A1[(size_t)row * LDA1 + 512 + lane]      = f2bf(e0 * inv);
  A1[(size_t)row * LDA1 + 512 + 64 + lane] = f2bf(e1 * inv);
}

// wcomb [8192][512]: rows 0-4095 = bf16(W_ih[og]); 4096-8191 = bf16(W_ih[og]+W_hhL[og])
__global__ void build_wcomb(const float* __restrict__ Wih, const float* __restrict__ Whh,
                            ushort_t* __restrict__ out) {
  const int idx = blockIdx.x * 256 + threadIdx.x;  // 8192*512
  const int r = idx >> 9, cc = idx & 511;
  ushort_t v;
  if (r < 4096) {
    v = f2bf(Wih[(size_t)orig_row(r) * 512 + cc]);
  } else {
    const int og = orig_row(r - 4096);
    v = f2bf(Wih[(size_t)og * 512 + cc] + Whh[(size_t)og * 1024 + cc]);
  }
  out[idx] = v;
}

// B2 left: B2[r*640 + k] = bf16(W_hh[orig(r)][k]), k<512
__global__ void build_B2left(const float* __restrict__ W, ushort_t* __restrict__ B2) {
  const int idx = blockIdx.x * 256 + threadIdx.x;  // 4096*512
  const int r = idx >> 9, k = idx & 511;
  B2[(size_t)r * LDA1 + k] = f2bf(W[(size_t)orig_row(r) * 1024 + k]);
}

// whhRP[r*512 + d] = bf16(W_hh[orig(r)][512+d])
__global__ void build_whhRP(const float* __restrict__ W, ushort_t* __restrict__ out) {
  const int idx = blockIdx.x * 256 + threadIdx.x;  // 4096*512
  const int r = idx >> 9, d = idx & 511;
  out[idx] = f2bf(W[(size_t)orig_row(r) * 1024 + 512 + d]);
}

// Q_cat [4096][1536] = [q_hi, q_lo, q_hi]
__global__ void build_qcat(const float* __restrict__ q, ushort_t* __restrict__ out) {
  const int idx = blockIdx.x * 256 + threadIdx.x;  // 4096*512
  const int b = idx >> 9, cc = idx & 511;
  const float v = q[idx];
  const ushort_t hi = f2bf(v);
  const ushort_t lo = f2bf(v - bf2f(hi));
  const size_t ro = (size_t)b * 1536;
  out[ro + cc] = hi;
  out[ro + 512 + cc] = lo;
  out[ro + 1024 + cc] = hi;
}

// B_cat [128][1536] = [s_hi, s_hi, s_lo]
__global__ void build_bcat(const float* __restrict__ s, ushort_t* __restrict__ out) {
  const int idx = blockIdx.x * 256 + threadIdx.x;  // 128*512
  const int n = idx >> 9, cc = idx & 511;
  const float v = s[idx];
  const ushort_t hi = f2bf(v);
  const ushort_t lo = f2bf(v - bf2f(hi));
  const size_t ro = (size_t)n * 1536;
  out[ro + cc] = hi;
  out[ro + 512 + cc] = hi;
  out[ro + 1024 + cc] = lo;
}

extern "C" void kernel_launch(void* const* d_in, const int* in_sizes, int n_in,
                              void* d_out, int out_size, void* d_ws, size_t ws_size,
                              hipStream_t stream) {
  const float* support = (const float*)d_in[0];
  const float* query   = (const float*)d_in[1];
  const float* W_ih    = (const float*)d_in[2];
  const float* W_hh    = (const float*)d_in[3];
  const float* b_ih    = (const float*)d_in[4];
  const float* b_hh    = (const float*)d_in[5];
  float* out = (float*)d_out;

  char* ws = (char*)d_ws;
  size_t off = 0;
  auto alloc = [&](size_t bytes) { char* p = ws + off; off += (bytes + 255) & ~255ull; return p; };
  ushort_t* gates_baseP = (ushort_t*)alloc((size_t)BATCH * GDIM * 2);   // 32MB (interleaved)
  float*    cbuf        = (float*)   alloc((size_t)BATCH * HDIM * 4);   // 16MB f32
  ushort_t* A1a         = (ushort_t*)alloc((size_t)BATCH * LDA1 * 2);   // 5MB [hr | attn]
  ushort_t* A1b         = (ushort_t*)alloc((size_t)BATCH * LDA1 * 2);   // 5MB
  ushort_t* A2a         = (ushort_t*)alloc((size_t)BATCH * DDIM * 2);   // 4MB lo
  ushort_t* A2b         = (ushort_t*)alloc((size_t)BATCH * DDIM * 2);   // 4MB
  ushort_t* Q_cat       = (ushort_t*)alloc((size_t)BATCH * 1536 * 2);   // 12MB
  ushort_t* wcomb       = (ushort_t*)alloc((size_t)8192 * 512 * 2);     // 8MB
  ushort_t* B2          = (ushort_t*)alloc((size_t)GDIM * LDA1 * 2);    // 5MB [WhhL | SW]
  ushort_t* whhRP       = (ushort_t*)alloc((size_t)GDIM * 512 * 2);     // 4MB
  ushort_t* B_cat       = (ushort_t*)alloc((size_t)FEWN * 1536 * 2);
  float*    logits3     = (float*)   alloc((size_t)3 * BATCH * FEWN * 4); // 6MB

  const size_t LOFS = (size_t)BATCH * FEWN;
  const dim3 blk(256);

  // ---- setup ----
  build_wcomb<<<8192 * 512 / 256, blk, 0, stream>>>(W_ih, W_hh, wcomb);
  build_B2left<<<GDIM * 512 / 256, blk, 0, stream>>>(W_hh, B2);
  build_whhRP<<<GDIM * 512 / 256, blk, 0, stream>>>(W_hh, whhRP);
  build_qcat<<<BATCH * 512 / 256, blk, 0, stream>>>(query, Q_cat);
  build_bcat<<<FEWN * 512 / 256, blk, 0, stream>>>(support, B_cat);

  // logits3[0..2] = Q_cat @ B_cat^T (split-precision q@s^T, triple-write)
  gemm_bt<4><<<dim3(1, 32), blk, 0, stream>>>(Q_cat, B_cat, logits3, nullptr,
                                              1536, 1536, 1536, FEWN);
  // SW = W_hhR_P @ support^T -> bf16 into B2[:, 512:640]  (low-rank factorization)
  gemm_bt<2><<<dim3(1, 32), blk, 0, stream>>>(whhRP, B_cat, nullptr, B2 + 512,
                                              512, 512, 1536, LDA1);

  // wide GEMM (K=512): left = step-0 gates + cell0; right = gates_base (interleaved)
  gemm_wide<<<dim3(64, 32), blk, 0, stream>>>(
      Q_cat, wcomb, gates_baseP, cbuf, A1a, A2a, b_ih, b_hh, 512, 1536, 512);

  auto attn_phase = [&](int s, ushort_t* A1, ushort_t* A2) {
    float* lg = logits3 + (size_t)s * LOFS;
    gemm_logits_splitk<<<dim3(3, 32), blk, 0, stream>>>(A1, A2, B_cat, lg);
    softmax_kernel<<<BATCH / 4, blk, 0, stream>>>(lg, A1);  // attn -> A1[:,512:640]
  };

  attn_phase(0, A1a, A2a);

  // step 1: A = [hr_0 | attn_0] (A1a), K=640 -> A1b/A2b
  gemm_fused<1><<<dim3(32, 32), blk, 0, stream>>>(
      A1a, B2, gates_baseP, cbuf, A1b, A2b, nullptr, nullptr, 640, LDA1, LDA1);
  attn_phase(1, A1b, A2b);

  // step 2: A1b -> A1a/A2a
  gemm_fused<1><<<dim3(32, 32), blk, 0, stream>>>(
      A1b, B2, gates_baseP, cbuf, A1a, A2a, nullptr, nullptr, 640, LDA1, LDA1);
  attn_phase(2, A1a, A2a);

  // step 3 (last): only j<512 -> half grid; out = query + hr
  gemm_fused<2><<<dim3(16, 32), blk, 0, stream>>>(
      A1a, B2, gates_baseP, cbuf, nullptr, nullptr, query, out, 640, LDA1, LDA1);
}

// Round 14
// 285.137 us; speedup vs baseline: 2.0350x; 1.0715x over previous
//
#include <hip/hip_runtime.h>

#define BATCH 4096
#define DDIM  512
#define HDIM  1024
#define GDIM  4096
#define FEWN  128
#define LDA1  640     // A1 = [hr'(512) | attn(128)]

typedef unsigned short ushort_t;
typedef __attribute__((ext_vector_type(8))) short bf16x8;
typedef __attribute__((ext_vector_type(4))) float f32x4;

__device__ inline ushort_t f2bf(float f) {
  unsigned u = __float_as_uint(f);
  unsigned r = (u + 0x7FFFu + ((u >> 16) & 1u)) >> 16;
  return (ushort_t)r;
}
__device__ inline float bf2f(ushort_t h) { return __uint_as_float((unsigned)h << 16); }
__device__ inline float bf2f_u(unsigned h16) { return __uint_as_float(h16 << 16); }

__device__ inline float sigmoidf(float x) { return 1.f / (1.f + __expf(-x)); }
__device__ inline float tanh_fast(float x) {
  float ax = fabsf(x);
  float t = __expf(-2.f * ax);
  float r = (1.f - t) / (1.f + t);
  return copysignf(r, x);
}

// permuted gate layout: col' -> original W row; gate g of j at col' with ((col'>>4)&3)=g
__device__ inline int orig_row(int colp) {
  return ((colp >> 4) & 3) * 1024 + ((colp >> 6) << 4) + (colp & 15);
}

__device__ inline void async_copy16(ushort_t* lds, const ushort_t* g) {
  __builtin_amdgcn_global_load_lds(
      (const __attribute__((address_space(1))) unsigned int*)g,
      (__attribute__((address_space(3))) unsigned int*)lds, 16, 0, 0);
}

// XCD-aware swizzle. gx%8==0: column-slice; else bijective 1D (m204).
#define XCD_SWZ()                                                            \
  int bx = blockIdx.x, by = blockIdx.y;                                      \
  {                                                                          \
    const int gx = gridDim.x;                                                \
    const int id = by * gx + bx;                                             \
    if ((gx & 7) == 0) {                                                     \
      const int cpx = gx >> 3;                                               \
      const int x = id & 7, s = id >> 3;                                     \
      bx = x * cpx + (s % cpx);                                              \
      by = s / cpx;                                                          \
    } else {                                                                 \
      const int nwg = gx * gridDim.y;                                        \
      const int qq = nwg >> 3, rr = nwg & 7;                                 \
      const int x = id & 7, s = id >> 3;                                     \
      const int nid = (x < rr ? x * (qq + 1) : rr * (qq + 1) + (x - rr) * qq) + s; \
      bx = nid % gx; by = nid / gx;                                          \
    }                                                                        \
  }

// ---- K-loop: BK=64 (two [128][32] halves), DOUBLE-BUFFERED with one barrier per
// tile. stage(t+1) issued BEFORE compute(t) -> its latency hides under the MFMAs;
// compiler's vmcnt(0)+lgkmcnt(0) at the barrier provides all ordering.
// Race-free: stage(t+1) writes buf[(t+1)&1], compute(t) reads buf[t&1] (disjoint);
// buf[t&1] is rewritten only at t+2's stage, after barrier(t+1) drained t's ds_reads.
#define STAGE8(dA, dB, kk)                                                   \
    async_copy16(dA,              gA0 + (kk));                               \
    async_copy16(dA + 512,        gA0 + (size_t)16 * lda + (kk));            \
    async_copy16(dA + 4096,       gA0 + (kk) + 32);                          \
    async_copy16(dA + 4096 + 512, gA0 + (size_t)16 * lda + (kk) + 32);       \
    async_copy16(dB,              gB0 + (kk));                               \
    async_copy16(dB + 512,        gB0 + (size_t)16 * ldb + (kk));            \
    async_copy16(dB + 4096,       gB0 + (kk) + 32);                          \
    async_copy16(dB + 4096 + 512, gB0 + (size_t)16 * ldb + (kk) + 32);

#define GEMM_PROLOG()                                                        \
  __shared__ __align__(16) ushort_t lA[2 * 8192];                            \
  __shared__ __align__(16) ushort_t lB[2 * 8192];                            \
  const int tid = threadIdx.x;                                               \
  const int wid = tid >> 6, lane = tid & 63;                                 \
  const int wr = wid >> 1, wc = wid & 1;                                     \
  XCD_SWZ()                                                                  \
  const int m0 = by * 128, n0 = bx * 128;                                    \
  const int lr = lane & 15, kg = lane >> 4;                                  \
  f32x4 acc[4][4] = {};                                                      \
  const int srow = lane >> 2;                                                \
  const int scol = (lane & 3) * 8;                                           \
  const ushort_t* gA0 = A + (size_t)(m0 + wid * 32 + srow) * lda + scol;     \
  const ushort_t* gB0 = B + (size_t)(n0 + wid * 32 + srow) * ldb + scol;     \
  ushort_t* sA = &lA[wid * 1024];                                            \
  ushort_t* sB = &lB[wid * 1024];                                            \
  const int nIter = K >> 6;                                                  \
  { STAGE8(sA, sB, 0) }                                                      \
  for (int kt = 0; kt < nIter; ++kt) {                                       \
    __syncthreads();                                                         \
    const int cur = (kt & 1) * 8192;                                         \
    if (kt + 1 < nIter) {                                                    \
      const int nxt = ((kt + 1) & 1) * 8192;                                 \
      const int k1 = (kt + 1) << 6;                                          \
      STAGE8(sA + nxt, sB + nxt, k1)                                         \
    }                                                                        \
    _Pragma("unroll")                                                        \
    for (int h = 0; h < 2; ++h) {                                            \
      bf16x8 af[4], bfr[4];                                                  \
      _Pragma("unroll")                                                      \
      for (int mi = 0; mi < 4; ++mi)                                         \
        af[mi] = *(const bf16x8*)&lA[cur + h * 4096 + (wr * 64 + mi * 16 + lr) * 32 + kg * 8]; \
      _Pragma("unroll")                                                      \
      for (int ni = 0; ni < 4; ++ni)                                         \
        bfr[ni] = *(const bf16x8*)&lB[cur + h * 4096 + (wc * 64 + ni * 16 + lr) * 32 + kg * 8]; \
      _Pragma("unroll")                                                      \
      for (int mi = 0; mi < 4; ++mi)                                         \
        _Pragma("unroll")                                                    \
        for (int ni = 0; ni < 4; ++ni)                                       \
          acc[mi][ni] = __builtin_amdgcn_mfma_f32_16x16x32_bf16(af[mi], bfr[ni], acc[mi][ni], 0, 0, 0); \
    }                                                                        \
  }

// Wide GEMM: C = q_hi @ [wihP | wsumP]^T, N=8192, K=512.
// Left (n0<4096): step-0 gates -> cell0 (c f32, A1.hi lda640, A2.lo).
// Right: gates_base 4-gate-INTERLEAVED: gbase[row*4096 + jj*4 + g] (one 8B store).
__launch_bounds__(256)
__global__ void gemm_wide(const ushort_t* __restrict__ A, const ushort_t* __restrict__ B,
                          ushort_t* __restrict__ gbase, float* __restrict__ c,
                          ushort_t* __restrict__ A1out, ushort_t* __restrict__ A2out,
                          const float* __restrict__ b1, const float* __restrict__ b2,
                          int K, int lda, int ldb) {
  GEMM_PROLOG()
  if (n0 < 4096) {
    const int jj = ((n0 + wc * 64) >> 6) * 16 + lr;   // 0..1023
    const bool do_h = (n0 + wc * 64) < 2048;          // j < 512
    const float bi0 = b1[jj]        + b2[jj];
    const float bi2 = b1[2048 + jj] + b2[2048 + jj];
    const float bi3 = b1[3072 + jj] + b2[3072 + jj];
#pragma unroll
    for (int mi = 0; mi < 4; ++mi) {
#pragma unroll
      for (int r = 0; r < 4; ++r) {
        const int row = m0 + wr * 64 + mi * 16 + kg * 4 + r;
        const float si = sigmoidf(acc[mi][0][r] + bi0);
        const float tg = tanh_fast(acc[mi][2][r] + bi2);
        const float so = sigmoidf(acc[mi][3][r] + bi3);
        const float cn = si * tg;                      // c_prev = 0
        c[(size_t)row * HDIM + jj] = cn;
        if (do_h) {
          const float hr = so * tanh_fast(cn);
          const ushort_t hi = f2bf(hr);
          const ushort_t lo = f2bf(hr - bf2f(hi));
          A1out[(size_t)row * LDA1 + jj] = hi;
          A2out[(size_t)row * DDIM + jj] = lo;
        }
      }
    }
  } else {
    const int jj = ((n0 - 4096 + wc * 64) >> 6) * 16 + lr;  // 0..1023
    const float bi0 = b1[jj]        + b2[jj];
    const float bi1 = b1[1024 + jj] + b2[1024 + jj];
    const float bi2 = b1[2048 + jj] + b2[2048 + jj];
    const float bi3 = b1[3072 + jj] + b2[3072 + jj];
#pragma unroll
    for (int mi = 0; mi < 4; ++mi)
#pragma unroll
      for (int r = 0; r < 4; ++r) {
        const int row = m0 + wr * 64 + mi * 16 + kg * 4 + r;
        uint2 p;
        p.x = (unsigned)f2bf(acc[mi][0][r] + bi0) | ((unsigned)f2bf(acc[mi][1][r] + bi1) << 16);
        p.y = (unsigned)f2bf(acc[mi][2][r] + bi2) | ((unsigned)f2bf(acc[mi][3][r] + bi3) << 16);
        *(uint2*)&gbase[(size_t)row * GDIM + jj * 4] = p;
      }
  }
}

// Fused recurrent GEMM + LSTM cell. K=640: A=[hr'|attn], B=[WhhL|SW]. base interleaved.
// MODE 1: cell -> c, A1.hi, A2.lo.  MODE 2: out = query + hr (grid.x = 16).
template<int MODE>
__launch_bounds__(256)
__global__ void gemm_fused(const ushort_t* __restrict__ A, const ushort_t* __restrict__ B,
                           const ushort_t* __restrict__ base, float* __restrict__ c,
                           ushort_t* __restrict__ A1out, ushort_t* __restrict__ A2out,
                           const float* __restrict__ query, float* __restrict__ out,
                           int K, int lda, int ldb) {
  GEMM_PROLOG()
  const int jj = ((n0 + wc * 64) >> 6) * 16 + lr;
  const bool do_h = (MODE == 2) || ((n0 + wc * 64) < 2048);
#pragma unroll
  for (int mi = 0; mi < 4; ++mi) {
#pragma unroll
    for (int r = 0; r < 4; ++r) {
      const int row = m0 + wr * 64 + mi * 16 + kg * 4 + r;
      const uint2 p = *(const uint2*)&base[(size_t)row * GDIM + jj * 4];
      const float g0 = bf2f_u(p.x & 0xFFFFu) + acc[mi][0][r];
      const float g1 = bf2f_u(p.x >> 16)     + acc[mi][1][r];
      const float g2 = bf2f_u(p.y & 0xFFFFu) + acc[mi][2][r];
      const float g3 = bf2f_u(p.y >> 16)     + acc[mi][3][r];
      const float si = sigmoidf(g0);
      const float sf = sigmoidf(g1);
      const float tg = tanh_fast(g2);
      const float so = sigmoidf(g3);
      const size_t ci = (size_t)row * HDIM + jj;
      const float cn = sf * c[ci] + si * tg;
      if (MODE != 2) c[ci] = cn;
      if (do_h) {
        const float hr = so * tanh_fast(cn);
        if (MODE == 2) {
          out[(size_t)row * DDIM + jj] = query[(size_t)row * DDIM + jj] + hr;
        } else {
          const ushort_t hi = f2bf(hr);
          const ushort_t lo = f2bf(hr - bf2f(hi));
          A1out[(size_t)row * LDA1 + jj] = hi;
          A2out[(size_t)row * DDIM + jj] = lo;
        }
      }
    }
  }
}

// Split-K logits: grid (3, 32), dedicated body (same dbuf prefetch structure).
// chunk k: A-seg {A1.hi, A2.lo, A1.hi} x B-seg {s_hi, s_hi, s_lo};
// atomicAdd into prefilled logits. B rows 0..127 only.
__launch_bounds__(256)
__global__ void gemm_logits_splitk(const ushort_t* __restrict__ A1, const ushort_t* __restrict__ A2,
                                   const ushort_t* __restrict__ Bc, float* __restrict__ Cf) {
  __shared__ __align__(16) ushort_t lA[2 * 8192];
  __shared__ __align__(16) ushort_t lB[2 * 8192];
  const int tid = threadIdx.x;
  const int wid = tid >> 6, lane = tid & 63;
  const int wr = wid >> 1, wc = wid & 1;
  const int chunk = blockIdx.x;          // 0..2
  const int m0 = blockIdx.y * 128;
  const int lr = lane & 15, kg = lane >> 4;
  f32x4 acc[4][4] = {};
  const int srow = lane >> 2;
  const int scol = (lane & 3) * 8;
  const ushort_t* A = (chunk == 1) ? A2 : A1;
  const int lda = (chunk == 1) ? DDIM : LDA1;
  const int ldb = 1536;
  const ushort_t* gA0 = A + (size_t)(m0 + wid * 32 + srow) * lda + scol;
  const ushort_t* gB0 = Bc + (size_t)(wid * 32 + srow) * 1536 + chunk * 512 + scol;
  ushort_t* sA = &lA[wid * 1024];
  ushort_t* sB = &lB[wid * 1024];
  const int nIter = 8;                   // K=512, BK=64
  { STAGE8(sA, sB, 0) }
  for (int kt = 0; kt < nIter; ++kt) {
    __syncthreads();
    const int cur = (kt & 1) * 8192;
    if (kt + 1 < nIter) {
      const int nxt = ((kt + 1) & 1) * 8192;
      const int k1 = (kt + 1) << 6;
      STAGE8(sA + nxt, sB + nxt, k1)
    }
#pragma unroll
    for (int h = 0; h < 2; ++h) {
      bf16x8 af[4], bfr[4];
#pragma unroll
      for (int mi = 0; mi < 4; ++mi)
        af[mi] = *(const bf16x8*)&lA[cur + h * 4096 + (wr * 64 + mi * 16 + lr) * 32 + kg * 8];
#pragma unroll
      for (int ni = 0; ni < 4; ++ni)
        bfr[ni] = *(const bf16x8*)&lB[cur + h * 4096 + (wc * 64 + ni * 16 + lr) * 32 + kg * 8];
#pragma unroll
      for (int mi = 0; mi < 4; ++mi)
#pragma unroll
        for (int ni = 0; ni < 4; ++ni)
          acc[mi][ni] = __builtin_amdgcn_mfma_f32_16x16x32_bf16(af[mi], bfr[ni], acc[mi][ni], 0, 0, 0);
    }
    __syncthreads();
  }
#pragma unroll
  for (int mi = 0; mi < 4; ++mi)
#pragma unroll
    for (int ni = 0; ni < 4; ++ni)
#pragma unroll
      for (int r = 0; r < 4; ++r) {
        const int row = m0 + wr * 64 + mi * 16 + kg * 4 + r;
        const int col = wc * 64 + ni * 16 + lr;
        atomicAdd(&Cf[(size_t)row * FEWN + col], acc[mi][ni][r]);
      }
}

// generic: EPI 2 = bf16(acc) -> Cb ; EPI 4 = acc -> Cf, Cf+OFS, Cf+2*OFS (triple prefill)
template<int EPI>
__launch_bounds__(256)
__global__ void gemm_bt(const ushort_t* __restrict__ A, const ushort_t* __restrict__ B,
                        float* __restrict__ Cf, ushort_t* __restrict__ Cb,
                        int K, int lda, int ldb, int ldc) {
  GEMM_PROLOG()
  const size_t OFS = (size_t)BATCH * FEWN;
#pragma unroll
  for (int mi = 0; mi < 4; ++mi)
#pragma unroll
    for (int ni = 0; ni < 4; ++ni)
#pragma unroll
      for (int r = 0; r < 4; ++r) {
        const int row = m0 + wr * 64 + mi * 16 + kg * 4 + r;
        const int col = n0 + wc * 64 + ni * 16 + lr;
        const float v = acc[mi][ni][r];
        const size_t o = (size_t)row * ldc + col;
        if (EPI == 2) {
          Cb[o] = f2bf(v);
        } else {
          Cf[o] = v; Cf[o + OFS] = v; Cf[o + 2 * OFS] = v;
        }
      }
}

// softmax: reads logits row, writes attn bf16 directly into A1[:, 512:640]
__global__ void softmax_kernel(const float* __restrict__ logits, ushort_t* __restrict__ A1) {
  const int row = blockIdx.x * 4 + (threadIdx.x >> 6);
  const int lane = threadIdx.x & 63;
  const float* L = logits + (size_t)row * FEWN;
  const float x0 = L[lane], x1 = L[lane + 64];
  float m = fmaxf(x0, x1);
#pragma unroll
  for (int s = 32; s > 0; s >>= 1) m = fmaxf(m, __shfl_xor(m, s));
  const float e0 = __expf(x0 - m), e1 = __expf(x1 - m);
  float sum = e0 + e1;
#pragma unroll
  for (int s = 32; s > 0; s >>= 1) sum += __shfl_xor(sum, s);
  const float inv = 1.f / sum;
  A1[(size_t)row * LDA1 + 512 + lane]      = f2bf(e0 * inv);
  A1[(size_t)row * LDA1 + 512 + 64 + lane] = f2bf(e1 * inv);
}

// wcomb [8192][512]: rows 0-4095 = bf16(W_ih[og]); 4096-8191 = bf16(W_ih[og]+W_hhL[og])
__global__ void build_wcomb(const float* __restrict__ Wih, const float* __restrict__ Whh,
                            ushort_t* __restrict__ out) {
  const int idx = blockIdx.x * 256 + threadIdx.x;  // 8192*512
  const int r = idx >> 9, cc = idx & 511;
  ushort_t v;
  if (r < 4096) {
    v = f2bf(Wih[(size_t)orig_row(r) * 512 + cc]);
  } else {
    const int og = orig_row(r - 4096);
    v = f2bf(Wih[(size_t)og * 512 + cc] + Whh[(size_t)og * 1024 + cc]);
  }
  out[idx] = v;
}

// B2 left: B2[r*640 + k] = bf16(W_hh[orig(r)][k]), k<512
__global__ void build_B2left(const float* __restrict__ W, ushort_t* __restrict__ B2) {
  const int idx = blockIdx.x * 256 + threadIdx.x;  // 4096*512
  const int r = idx >> 9, k = idx & 511;
  B2[(size_t)r * LDA1 + k] = f2bf(W[(size_t)orig_row(r) * 1024 + k]);
}

// whhRP[r*512 + d] = bf16(W_hh[orig(r)][512+d])
__global__ void build_whhRP(const float* __restrict__ W, ushort_t* __restrict__ out) {
  const int idx = blockIdx.x * 256 + threadIdx.x;  // 4096*512
  const int r = idx >> 9, d = idx & 511;
  out[idx] = f2bf(W[(size_t)orig_row(r) * 1024 + 512 + d]);
}

// Q_cat [4096][1536] = [q_hi, q_lo, q_hi]
__global__ void build_qcat(const float* __restrict__ q, ushort_t* __restrict__ out) {
  const int idx = blockIdx.x * 256 + threadIdx.x;  // 4096*512
  const int b = idx >> 9, cc = idx & 511;
  const float v = q[idx];
  const ushort_t hi = f2bf(v);
  const ushort_t lo = f2bf(v - bf2f(hi));
  const size_t ro = (size_t)b * 1536;
  out[ro + cc] = hi;
  out[ro + 512 + cc] = lo;
  out[ro + 1024 + cc] = hi;
}

// B_cat [128][1536] = [s_hi, s_hi, s_lo]
__global__ void build_bcat(const float* __restrict__ s, ushort_t* __restrict__ out) {
  const int idx = blockIdx.x * 256 + threadIdx.x;  // 128*512
  const int n = idx >> 9, cc = idx & 511;
  const float v = s[idx];
  const ushort_t hi = f2bf(v);
  const ushort_t lo = f2bf(v - bf2f(hi));
  const size_t ro = (size_t)n * 1536;
  out[ro + cc] = hi;
  out[ro + 512 + cc] = hi;
  out[ro + 1024 + cc] = lo;
}

extern "C" void kernel_launch(void* const* d_in, const int* in_sizes, int n_in,
                              void* d_out, int out_size, void* d_ws, size_t ws_size,
                              hipStream_t stream) {
  const float* support = (const float*)d_in[0];
  const float* query   = (const float*)d_in[1];
  const float* W_ih    = (const float*)d_in[2];
  const float* W_hh    = (const float*)d_in[3];
  const float* b_ih    = (const float*)d_in[4];
  const float* b_hh    = (const float*)d_in[5];
  float* out = (float*)d_out;

  char* ws = (char*)d_ws;
  size_t off = 0;
  auto alloc = [&](size_t bytes) { char* p = ws + off; off += (bytes + 255) & ~255ull; return p; };
  ushort_t* gates_baseP = (ushort_t*)alloc((size_t)BATCH * GDIM * 2);   // 32MB (interleaved)
  float*    cbuf        = (float*)   alloc((size_t)BATCH * HDIM * 4);   // 16MB f32
  ushort_t* A1a         = (ushort_t*)alloc((size_t)BATCH * LDA1 * 2);   // 5MB [hr | attn]
  ushort_t* A1b         = (ushort_t*)alloc((size_t)BATCH * LDA1 * 2);   // 5MB
  ushort_t* A2a         = (ushort_t*)alloc((size_t)BATCH * DDIM * 2);   // 4MB lo
  ushort_t* A2b         = (ushort_t*)alloc((size_t)BATCH * DDIM * 2);   // 4MB
  ushort_t* Q_cat       = (ushort_t*)alloc((size_t)BATCH * 1536 * 2);   // 12MB
  ushort_t* wcomb       = (ushort_t*)alloc((size_t)8192 * 512 * 2);     // 8MB
  ushort_t* B2          = (ushort_t*)alloc((size_t)GDIM * LDA1 * 2);    // 5MB [WhhL | SW]
  ushort_t* whhRP       = (ushort_t*)alloc((size_t)GDIM * 512 * 2);     // 4MB
  ushort_t* B_cat       = (ushort_t*)alloc((size_t)FEWN * 1536 * 2);
  float*    logits3     = (float*)   alloc((size_t)3 * BATCH * FEWN * 4); // 6MB

  const size_t LOFS = (size_t)BATCH * FEWN;
  const dim3 blk(256);

  // ---- setup ----
  build_wcomb<<<8192 * 512 / 256, blk, 0, stream>>>(W_ih, W_hh, wcomb);
  build_B2left<<<GDIM * 512 / 256, blk, 0, stream>>>(W_hh, B2);
  build_whhRP<<<GDIM * 512 / 256, blk, 0, stream>>>(W_hh, whhRP);
  build_qcat<<<BATCH * 512 / 256, blk, 0, stream>>>(query, Q_cat);
  build_bcat<<<FEWN * 512 / 256, blk, 0, stream>>>(support, B_cat);

  // logits3[0..2] = Q_cat @ B_cat^T (split-precision q@s^T, triple-write)
  gemm_bt<4><<<dim3(1, 32), blk, 0, stream>>>(Q_cat, B_cat, logits3, nullptr,
                                              1536, 1536, 1536, FEWN);
  // SW = W_hhR_P @ support^T -> bf16 into B2[:, 512:640]  (low-rank factorization)
  gemm_bt<2><<<dim3(1, 32), blk, 0, stream>>>(whhRP, B_cat, nullptr, B2 + 512,
                                              512, 512, 1536, LDA1);

  // wide GEMM (K=512): left = step-0 gates + cell0; right = gates_base (interleaved)
  gemm_wide<<<dim3(64, 32), blk, 0, stream>>>(
      Q_cat, wcomb, gates_baseP, cbuf, A1a, A2a, b_ih, b_hh, 512, 1536, 512);

  auto attn_phase = [&](int s, ushort_t* A1, ushort_t* A2) {
    float* lg = logits3 + (size_t)s * LOFS;
    gemm_logits_splitk<<<dim3(3, 32), blk, 0, stream>>>(A1, A2, B_cat, lg);
    softmax_kernel<<<BATCH / 4, blk, 0, stream>>>(lg, A1);  // attn -> A1[:,512:640]
  };

  attn_phase(0, A1a, A2a);

  // step 1: A = [hr_0 | attn_0] (A1a), K=640 -> A1b/A2b
  gemm_fused<1><<<dim3(32, 32), blk, 0, stream>>>(
      A1a, B2, gates_baseP, cbuf, A1b, A2b, nullptr, nullptr, 640, LDA1, LDA1);
  attn_phase(1, A1b, A2b);

  // step 2: A1b -> A1a/A2a
  gemm_fused<1><<<dim3(32, 32), blk, 0, stream>>>(
      A1b, B2, gates_baseP, cbuf, A1a, A2a, nullptr, nullptr, 640, LDA1, LDA1);
  attn_phase(2, A1a, A2a);

  // step 3 (last): only j<512 -> half grid; out = query + hr
  gemm_fused<2><<<dim3(16, 32), blk, 0, stream>>>(
      A1a, B2, gates_baseP, cbuf, nullptr, nullptr, query, out, 640, LDA1, LDA1);
}

// Round 15
// 282.662 us; speedup vs baseline: 2.0528x; 1.0088x over previous
//
#include <hip/hip_runtime.h>

#define BATCH 4096
#define DDIM  512
#define HDIM  1024
#define GDIM  4096
#define FEWN  128
#define LDA1  640     // A1 = [hr'(512) | attn(128)]

typedef unsigned short ushort_t;
typedef __attribute__((ext_vector_type(8))) short bf16x8;
typedef __attribute__((ext_vector_type(4))) float f32x4;

__device__ inline ushort_t f2bf(float f) {
  unsigned u = __float_as_uint(f);
  unsigned r = (u + 0x7FFFu + ((u >> 16) & 1u)) >> 16;
  return (ushort_t)r;
}
__device__ inline float bf2f(ushort_t h) { return __uint_as_float((unsigned)h << 16); }
__device__ inline float bf2f_u(unsigned h16) { return __uint_as_float(h16 << 16); }

__device__ inline float sigmoidf(float x) { return 1.f / (1.f + __expf(-x)); }
__device__ inline float tanh_fast(float x) {
  float ax = fabsf(x);
  float t = __expf(-2.f * ax);
  float r = (1.f - t) / (1.f + t);
  return copysignf(r, x);
}

// permuted gate layout: col' -> original W row; gate g of j at col' with ((col'>>4)&3)=g
__device__ inline int orig_row(int colp) {
  return ((colp >> 4) & 3) * 1024 + ((colp >> 6) << 4) + (colp & 15);
}

__device__ inline void async_copy16(ushort_t* lds, const ushort_t* g) {
  __builtin_amdgcn_global_load_lds(
      (const __attribute__((address_space(1))) unsigned int*)g,
      (__attribute__((address_space(3))) unsigned int*)lds, 16, 0, 0);
}

// XCD-aware swizzle. gx%8==0: column-slice; else bijective 1D (m204).
#define XCD_SWZ()                                                            \
  int bx = blockIdx.x, by = blockIdx.y;                                      \
  {                                                                          \
    const int gx = gridDim.x;                                                \
    const int id = by * gx + bx;                                             \
    if ((gx & 7) == 0) {                                                     \
      const int cpx = gx >> 3;                                               \
      const int x = id & 7, s = id >> 3;                                     \
      bx = x * cpx + (s % cpx);                                              \
      by = s / cpx;                                                          \
    } else {                                                                 \
      const int nwg = gx * gridDim.y;                                        \
      const int qq = nwg >> 3, rr = nwg & 7;                                 \
      const int x = id & 7, s = id >> 3;                                     \
      const int nid = (x < rr ? x * (qq + 1) : rr * (qq + 1) + (x - rr) * qq) + s; \
      bx = nid % gx; by = nid / gx;                                          \
    }                                                                        \
  }

// ---- K-loop: BK=64 (two [128][32] halves), double-buffered, one barrier per tile.
#define STAGE8(dA, dB, kk)                                                   \
    async_copy16(dA,              gA0 + (kk));                               \
    async_copy16(dA + 512,        gA0 + (size_t)16 * lda + (kk));            \
    async_copy16(dA + 4096,       gA0 + (kk) + 32);                          \
    async_copy16(dA + 4096 + 512, gA0 + (size_t)16 * lda + (kk) + 32);       \
    async_copy16(dB,              gB0 + (kk));                               \
    async_copy16(dB + 512,        gB0 + (size_t)16 * ldb + (kk));            \
    async_copy16(dB + 4096,       gB0 + (kk) + 32);                          \
    async_copy16(dB + 4096 + 512, gB0 + (size_t)16 * ldb + (kk) + 32);

#define KLOOP_DBUF()                                                         \
  const int nIter = K >> 6;                                                  \
  { STAGE8(sA, sB, 0) }                                                      \
  for (int kt = 0; kt < nIter; ++kt) {                                       \
    __syncthreads();                                                         \
    const int cur = (kt & 1) * 8192;                                         \
    if (kt + 1 < nIter) {                                                    \
      const int nxt = ((kt + 1) & 1) * 8192;                                 \
      const int k1 = (kt + 1) << 6;                                          \
      STAGE8(sA + nxt, sB + nxt, k1)                                         \
    }                                                                        \
    _Pragma("unroll")                                                        \
    for (int h = 0; h < 2; ++h) {                                            \
      bf16x8 af[4], bfr[4];                                                  \
      _Pragma("unroll")                                                      \
      for (int mi = 0; mi < 4; ++mi)                                         \
        af[mi] = *(const bf16x8*)&lA[cur + h * 4096 + (wr * 64 + mi * 16 + lr) * 32 + kg * 8]; \
      _Pragma("unroll")                                                      \
      for (int ni = 0; ni < 4; ++ni)                                         \
        bfr[ni] = *(const bf16x8*)&lB[cur + h * 4096 + (wc * 64 + ni * 16 + lr) * 32 + kg * 8]; \
      _Pragma("unroll")                                                      \
      for (int mi = 0; mi < 4; ++mi)                                         \
        _Pragma("unroll")                                                    \
        for (int ni = 0; ni < 4; ++ni)                                       \
          acc[mi][ni] = __builtin_amdgcn_mfma_f32_16x16x32_bf16(af[mi], bfr[ni], acc[mi][ni], 0, 0, 0); \
    }                                                                        \
  }

#define GEMM_PROLOG()                                                        \
  __shared__ __align__(16) ushort_t lA[2 * 8192];                            \
  __shared__ __align__(16) ushort_t lB[2 * 8192];                            \
  const int tid = threadIdx.x;                                               \
  const int wid = tid >> 6, lane = tid & 63;                                 \
  const int wr = wid >> 1, wc = wid & 1;                                     \
  XCD_SWZ()                                                                  \
  const int m0 = by * 128, n0 = bx * 128;                                    \
  const int lr = lane & 15, kg = lane >> 4;                                  \
  f32x4 acc[4][4] = {};                                                      \
  const int srow = lane >> 2;                                                \
  const int scol = (lane & 3) * 8;                                           \
  const ushort_t* gA0 = A + (size_t)(m0 + wid * 32 + srow) * lda + scol;     \
  const ushort_t* gB0 = B + (size_t)(n0 + wid * 32 + srow) * ldb + scol;     \
  ushort_t* sA = &lA[wid * 1024];                                            \
  ushort_t* sB = &lB[wid * 1024];                                            \
  KLOOP_DBUF()

// Wide GEMM: C = q_hi @ [wihP | wsumP]^T, N=8192, K=512.
// Left (n0<4096): step-0 gates -> cell0 (c f32, A1.hi lda640, A2.lo).
// Right: gates_base 4-gate-INTERLEAVED: gbase[row*4096 + jj*4 + g] (one 8B store).
__launch_bounds__(256)
__global__ void gemm_wide(const ushort_t* __restrict__ A, const ushort_t* __restrict__ B,
                          ushort_t* __restrict__ gbase, float* __restrict__ c,
                          ushort_t* __restrict__ A1out, ushort_t* __restrict__ A2out,
                          const float* __restrict__ b1, const float* __restrict__ b2,
                          int K, int lda, int ldb) {
  GEMM_PROLOG()
  if (n0 < 4096) {
    const int jj = ((n0 + wc * 64) >> 6) * 16 + lr;   // 0..1023
    const bool do_h = (n0 + wc * 64) < 2048;          // j < 512
    const float bi0 = b1[jj]        + b2[jj];
    const float bi2 = b1[2048 + jj] + b2[2048 + jj];
    const float bi3 = b1[3072 + jj] + b2[3072 + jj];
#pragma unroll
    for (int mi = 0; mi < 4; ++mi) {
#pragma unroll
      for (int r = 0; r < 4; ++r) {
        const int row = m0 + wr * 64 + mi * 16 + kg * 4 + r;
        const float si = sigmoidf(acc[mi][0][r] + bi0);
        const float tg = tanh_fast(acc[mi][2][r] + bi2);
        const float so = sigmoidf(acc[mi][3][r] + bi3);
        const float cn = si * tg;                      // c_prev = 0
        c[(size_t)row * HDIM + jj] = cn;
        if (do_h) {
          const float hr = so * tanh_fast(cn);
          const ushort_t hi = f2bf(hr);
          const ushort_t lo = f2bf(hr - bf2f(hi));
          A1out[(size_t)row * LDA1 + jj] = hi;
          A2out[(size_t)row * DDIM + jj] = lo;
        }
      }
    }
  } else {
    const int jj = ((n0 - 4096 + wc * 64) >> 6) * 16 + lr;  // 0..1023
    const float bi0 = b1[jj]        + b2[jj];
    const float bi1 = b1[1024 + jj] + b2[1024 + jj];
    const float bi2 = b1[2048 + jj] + b2[2048 + jj];
    const float bi3 = b1[3072 + jj] + b2[3072 + jj];
#pragma unroll
    for (int mi = 0; mi < 4; ++mi)
#pragma unroll
      for (int r = 0; r < 4; ++r) {
        const int row = m0 + wr * 64 + mi * 16 + kg * 4 + r;
        uint2 p;
        p.x = (unsigned)f2bf(acc[mi][0][r] + bi0) | ((unsigned)f2bf(acc[mi][1][r] + bi1) << 16);
        p.y = (unsigned)f2bf(acc[mi][2][r] + bi2) | ((unsigned)f2bf(acc[mi][3][r] + bi3) << 16);
        *(uint2*)&gbase[(size_t)row * GDIM + jj * 4] = p;
      }
  }
}

// Fused recurrent GEMM + LSTM cell. K=640: A=[hr'|attn], B=[WhhL|SW]. base interleaved.
// MODE 1: cell -> c, A1.hi, A2.lo.  MODE 2: out = query + hr (grid.x = 16).
template<int MODE>
__launch_bounds__(256)
__global__ void gemm_fused(const ushort_t* __restrict__ A, const ushort_t* __restrict__ B,
                           const ushort_t* __restrict__ base, float* __restrict__ c,
                           ushort_t* __restrict__ A1out, ushort_t* __restrict__ A2out,
                           const float* __restrict__ query, float* __restrict__ out,
                           int K, int lda, int ldb) {
  GEMM_PROLOG()
  const int jj = ((n0 + wc * 64) >> 6) * 16 + lr;
  const bool do_h = (MODE == 2) || ((n0 + wc * 64) < 2048);
#pragma unroll
  for (int mi = 0; mi < 4; ++mi) {
#pragma unroll
    for (int r = 0; r < 4; ++r) {
      const int row = m0 + wr * 64 + mi * 16 + kg * 4 + r;
      const uint2 p = *(const uint2*)&base[(size_t)row * GDIM + jj * 4];
      const float g0 = bf2f_u(p.x & 0xFFFFu) + acc[mi][0][r];
      const float g1 = bf2f_u(p.x >> 16)     + acc[mi][1][r];
      const float g2 = bf2f_u(p.y & 0xFFFFu) + acc[mi][2][r];
      const float g3 = bf2f_u(p.y >> 16)     + acc[mi][3][r];
      const float si = sigmoidf(g0);
      const float sf = sigmoidf(g1);
      const float tg = tanh_fast(g2);
      const float so = sigmoidf(g3);
      const size_t ci = (size_t)row * HDIM + jj;
      const float cn = sf * c[ci] + si * tg;
      if (MODE != 2) c[ci] = cn;
      if (do_h) {
        const float hr = so * tanh_fast(cn);
        if (MODE == 2) {
          out[(size_t)row * DDIM + jj] = query[(size_t)row * DDIM + jj] + hr;
        } else {
          const ushort_t hi = f2bf(hr);
          const ushort_t lo = f2bf(hr - bf2f(hi));
          A1out[(size_t)row * LDA1 + jj] = hi;
          A2out[(size_t)row * DDIM + jj] = lo;
        }
      }
    }
  }
}

// Unified 6-chunk split-K logits: grid (6, 32). chunk c: seg=c>>1 (A/B segment),
// half=c&1 (K-half of 256). seg0: A1 x B[0:512); seg1: A2 x B[512:1024);
// seg2: A1 x B[1024:1536). atomicAdd into Cf (prefilled). B rows 0..127 only.
// Works for per-step logits (A1buf lda 640 / A2buf lda 512) AND logits_base
// (A1 = Q_cat lda 1536 / A2 = Q_cat+512 lda 1536).
__launch_bounds__(256)
__global__ void gemm_splitk6(const ushort_t* __restrict__ A1, const ushort_t* __restrict__ A2,
                             int lda1, int lda2,
                             const ushort_t* __restrict__ Bc, float* __restrict__ Cf) {
  __shared__ __align__(16) ushort_t lA[2 * 8192];
  __shared__ __align__(16) ushort_t lB[2 * 8192];
  const int tid = threadIdx.x;
  const int wid = tid >> 6, lane = tid & 63;
  const int wr = wid >> 1, wc = wid & 1;
  const int seg = blockIdx.x >> 1;       // 0..2
  const int koff = (blockIdx.x & 1) * 256;
  const int m0 = blockIdx.y * 128;
  const int lr = lane & 15, kg = lane >> 4;
  f32x4 acc[4][4] = {};
  const int srow = lane >> 2;
  const int scol = (lane & 3) * 8;
  const ushort_t* A = (seg == 1) ? A2 : A1;
  const int lda = (seg == 1) ? lda2 : lda1;
  const int ldb = 1536;
  const ushort_t* gA0 = A + (size_t)(m0 + wid * 32 + srow) * lda + koff + scol;
  const ushort_t* gB0 = Bc + (size_t)(wid * 32 + srow) * 1536 + seg * 512 + koff + scol;
  ushort_t* sA = &lA[wid * 1024];
  ushort_t* sB = &lB[wid * 1024];
  const int K = 256;
  KLOOP_DBUF()
#pragma unroll
  for (int mi = 0; mi < 4; ++mi)
#pragma unroll
    for (int ni = 0; ni < 4; ++ni)
#pragma unroll
      for (int r = 0; r < 4; ++r) {
        const int row = m0 + wr * 64 + mi * 16 + kg * 4 + r;
        const int col = wc * 64 + ni * 16 + lr;
        atomicAdd(&Cf[(size_t)row * FEWN + col], acc[mi][ni][r]);
      }
}

// generic: EPI 2 = bf16(acc) -> Cb
template<int EPI>
__launch_bounds__(256)
__global__ void gemm_bt(const ushort_t* __restrict__ A, const ushort_t* __restrict__ B,
                        float* __restrict__ Cf, ushort_t* __restrict__ Cb,
                        int K, int lda, int ldb, int ldc) {
  GEMM_PROLOG()
#pragma unroll
  for (int mi = 0; mi < 4; ++mi)
#pragma unroll
    for (int ni = 0; ni < 4; ++ni)
#pragma unroll
      for (int r = 0; r < 4; ++r) {
        const int row = m0 + wr * 64 + mi * 16 + kg * 4 + r;
        const int col = n0 + wc * 64 + ni * 16 + lr;
        const float v = acc[mi][ni][r];
        const size_t o = (size_t)row * ldc + col;
        if (EPI == 2) Cb[o] = f2bf(v);
        else          Cf[o] = v;
      }
}

// broadcast base logits: lg[LOFS + i] = lg[2*LOFS + i] = lg[i]
__global__ void broadcast3(float* __restrict__ lg) {
  const size_t LOFS = (size_t)BATCH * FEWN;
  const int i = blockIdx.x * 256 + threadIdx.x;   // over LOFS/4 float4s
  const float4 v = ((const float4*)lg)[i];
  ((float4*)(lg + LOFS))[i] = v;
  ((float4*)(lg + 2 * LOFS))[i] = v;
}

// softmax: reads logits row, writes attn bf16 directly into A1[:, 512:640]
__global__ void softmax_kernel(const float* __restrict__ logits, ushort_t* __restrict__ A1) {
  const int row = blockIdx.x * 4 + (threadIdx.x >> 6);
  const int lane = threadIdx.x & 63;
  const float* L = logits + (size_t)row * FEWN;
  const float x0 = L[lane], x1 = L[lane + 64];
  float m = fmaxf(x0, x1);
#pragma unroll
  for (int s = 32; s > 0; s >>= 1) m = fmaxf(m, __shfl_xor(m, s));
  const float e0 = __expf(x0 - m), e1 = __expf(x1 - m);
  float sum = e0 + e1;
#pragma unroll
  for (int s = 32; s > 0; s >>= 1) sum += __shfl_xor(sum, s);
  const float inv = 1.f / sum;
  A1[(size_t)row * LDA1 + 512 + lane]      = f2bf(e0 * inv);
  A1[(size_t)row * LDA1 + 512 + 64 + lane] = f2bf(e1 * inv);
}

// wcomb [8192][512]: rows 0-4095 = bf16(W_ih[og]); 4096-8191 = bf16(W_ih[og]+W_hhL[og])
__global__ void build_wcomb(const float* __restrict__ Wih, const float* __restrict__ Whh,
                            ushort_t* __restrict__ out) {
  const int idx = blockIdx.x * 256 + threadIdx.x;  // 8192*512
  const int r = idx >> 9, cc = idx & 511;
  ushort_t v;
  if (r < 4096) {
    v = f2bf(Wih[(size_t)orig_row(r) * 512 + cc]);
  } else {
    const int og = orig_row(r - 4096);
    v = f2bf(Wih[(size_t)og * 512 + cc] + Whh[(size_t)og * 1024 + cc]);
  }
  out[idx] = v;
}

// B2 left: B2[r*640 + k] = bf16(W_hh[orig(r)][k]), k<512
__global__ void build_B2left(const float* __restrict__ W, ushort_t* __restrict__ B2) {
  const int idx = blockIdx.x * 256 + threadIdx.x;  // 4096*512
  const int r = idx >> 9, k = idx & 511;
  B2[(size_t)r * LDA1 + k] = f2bf(W[(size_t)orig_row(r) * 1024 + k]);
}

// whhRP[r*512 + d] = bf16(W_hh[orig(r)][512+d])
__global__ void build_whhRP(const float* __restrict__ W, ushort_t* __restrict__ out) {
  const int idx = blockIdx.x * 256 + threadIdx.x;  // 4096*512
  const int r = idx >> 9, d = idx & 511;
  out[idx] = f2bf(W[(size_t)orig_row(r) * 1024 + 512 + d]);
}

// Q_cat [4096][1536] = [q_hi, q_lo, q_hi]
__global__ void build_qcat(const float* __restrict__ q, ushort_t* __restrict__ out) {
  const int idx = blockIdx.x * 256 + threadIdx.x;  // 4096*512
  const int b = idx >> 9, cc = idx & 511;
  const float v = q[idx];
  const ushort_t hi = f2bf(v);
  const ushort_t lo = f2bf(v - bf2f(hi));
  const size_t ro = (size_t)b * 1536;
  out[ro + cc] = hi;
  out[ro + 512 + cc] = lo;
  out[ro + 1024 + cc] = hi;
}

// B_cat [128][1536] = [s_hi, s_hi, s_lo]
__global__ void build_bcat(const float* __restrict__ s, ushort_t* __restrict__ out) {
  const int idx = blockIdx.x * 256 + threadIdx.x;  // 128*512
  const int n = idx >> 9, cc = idx & 511;
  const float v = s[idx];
  const ushort_t hi = f2bf(v);
  const ushort_t lo = f2bf(v - bf2f(hi));
  const size_t ro = (size_t)n * 1536;
  out[ro + cc] = hi;
  out[ro + 512 + cc] = hi;
  out[ro + 1024 + cc] = lo;
}

extern "C" void kernel_launch(void* const* d_in, const int* in_sizes, int n_in,
                              void* d_out, int out_size, void* d_ws, size_t ws_size,
                              hipStream_t stream) {
  const float* support = (const float*)d_in[0];
  const float* query   = (const float*)d_in[1];
  const float* W_ih    = (const float*)d_in[2];
  const float* W_hh    = (const float*)d_in[3];
  const float* b_ih    = (const float*)d_in[4];
  const float* b_hh    = (const float*)d_in[5];
  float* out = (float*)d_out;

  char* ws = (char*)d_ws;
  size_t off = 0;
  auto alloc = [&](size_t bytes) { char* p = ws + off; off += (bytes + 255) & ~255ull; return p; };
  ushort_t* gates_baseP = (ushort_t*)alloc((size_t)BATCH * GDIM * 2);   // 32MB (interleaved)
  float*    cbuf        = (float*)   alloc((size_t)BATCH * HDIM * 4);   // 16MB f32
  ushort_t* A1a         = (ushort_t*)alloc((size_t)BATCH * LDA1 * 2);   // 5MB [hr | attn]
  ushort_t* A1b         = (ushort_t*)alloc((size_t)BATCH * LDA1 * 2);   // 5MB
  ushort_t* A2a         = (ushort_t*)alloc((size_t)BATCH * DDIM * 2);   // 4MB lo
  ushort_t* A2b         = (ushort_t*)alloc((size_t)BATCH * DDIM * 2);   // 4MB
  ushort_t* Q_cat       = (ushort_t*)alloc((size_t)BATCH * 1536 * 2);   // 12MB
  ushort_t* wcomb       = (ushort_t*)alloc((size_t)8192 * 512 * 2);     // 8MB
  ushort_t* B2          = (ushort_t*)alloc((size_t)GDIM * LDA1 * 2);    // 5MB [WhhL | SW]
  ushort_t* whhRP       = (ushort_t*)alloc((size_t)GDIM * 512 * 2);     // 4MB
  ushort_t* B_cat       = (ushort_t*)alloc((size_t)FEWN * 1536 * 2);
  float*    logits3     = (float*)   alloc((size_t)3 * BATCH * FEWN * 4); // 6MB

  const size_t LOFS = (size_t)BATCH * FEWN;
  const dim3 blk(256);

  // ---- setup ----
  build_wcomb<<<8192 * 512 / 256, blk, 0, stream>>>(W_ih, W_hh, wcomb);
  build_B2left<<<GDIM * 512 / 256, blk, 0, stream>>>(W_hh, B2);
  build_whhRP<<<GDIM * 512 / 256, blk, 0, stream>>>(W_hh, whhRP);
  build_qcat<<<BATCH * 512 / 256, blk, 0, stream>>>(query, Q_cat);
  build_bcat<<<FEWN * 512 / 256, blk, 0, stream>>>(support, B_cat);

  // logits_base = Q_cat @ B_cat^T via 6-chunk split-K (192 blocks), then broadcast x3
  hipMemsetAsync(logits3, 0, LOFS * 4, stream);
  gemm_splitk6<<<dim3(6, 32), blk, 0, stream>>>(Q_cat, Q_cat + 512, 1536, 1536,
                                                B_cat, logits3);
  broadcast3<<<(int)(LOFS / 4 / 256), blk, 0, stream>>>(logits3);

  // SW = W_hhR_P @ support^T -> bf16 into B2[:, 512:640]  (low-rank factorization)
  gemm_bt<2><<<dim3(1, 32), blk, 0, stream>>>(whhRP, B_cat, nullptr, B2 + 512,
                                              512, 512, 1536, LDA1);

  // wide GEMM (K=512): left = step-0 gates + cell0; right = gates_base (interleaved)
  gemm_wide<<<dim3(64, 32), blk, 0, stream>>>(
      Q_cat, wcomb, gates_baseP, cbuf, A1a, A2a, b_ih, b_hh, 512, 1536, 512);

  auto attn_phase = [&](int s, ushort_t* A1, ushort_t* A2) {
    float* lg = logits3 + (size_t)s * LOFS;
    gemm_splitk6<<<dim3(6, 32), blk, 0, stream>>>(A1, A2, LDA1, DDIM, B_cat, lg);
    softmax_kernel<<<BATCH / 4, blk, 0, stream>>>(lg, A1);  // attn -> A1[:,512:640]
  };

  attn_phase(0, A1a, A2a);

  // step 1: A = [hr_0 | attn_0] (A1a), K=640 -> A1b/A2b
  gemm_fused<1><<<dim3(32, 32), blk, 0, stream>>>(
      A1a, B2, gates_baseP, cbuf, A1b, A2b, nullptr, nullptr, 640, LDA1, LDA1);
  attn_phase(1, A1b, A2b);

  // step 2: A1b -> A1a/A2a
  gemm_fused<1><<<dim3(32, 32), blk, 0, stream>>>(
      A1b, B2, gates_baseP, cbuf, A1a, A2a, nullptr, nullptr, 640, LDA1, LDA1);
  attn_phase(2, A1a, A2a);

  // step 3 (last): only j<512 -> half grid; out = query + hr
  gemm_fused<2><<<dim3(16, 32), blk, 0, stream>>>(
      A1a, B2, gates_baseP, cbuf, nullptr, nullptr, query, out, 640, LDA1, LDA1);
}

// Round 16
// 274.303 us; speedup vs baseline: 2.1154x; 1.0305x over previous
//
#include <hip/hip_runtime.h>

#define BATCH 4096
#define DDIM  512
#define HDIM  1024
#define GDIM  4096
#define FEWN  128
#define LDA1  640     // A1 = [hr'(512) | attn(128)]

typedef unsigned short ushort_t;
typedef __attribute__((ext_vector_type(8))) short bf16x8;
typedef __attribute__((ext_vector_type(4))) float f32x4;

__device__ inline ushort_t f2bf(float f) {
  unsigned u = __float_as_uint(f);
  unsigned r = (u + 0x7FFFu + ((u >> 16) & 1u)) >> 16;
  return (ushort_t)r;
}
__device__ inline float bf2f(ushort_t h) { return __uint_as_float((unsigned)h << 16); }
__device__ inline float bf2f_u(unsigned h16) { return __uint_as_float(h16 << 16); }

__device__ inline float sigmoidf(float x) { return 1.f / (1.f + __expf(-x)); }
__device__ inline float tanh_fast(float x) {
  float ax = fabsf(x);
  float t = __expf(-2.f * ax);
  float r = (1.f - t) / (1.f + t);
  return copysignf(r, x);
}

// permuted gate layout: col' -> original W row; gate g of j at col' with ((col'>>4)&3)=g
__device__ inline int orig_row(int colp) {
  return ((colp >> 4) & 3) * 1024 + ((colp >> 6) << 4) + (colp & 15);
}

__device__ inline void async_copy16(ushort_t* lds, const ushort_t* g) {
  __builtin_amdgcn_global_load_lds(
      (const __attribute__((address_space(1))) unsigned int*)g,
      (__attribute__((address_space(3))) unsigned int*)lds, 16, 0, 0);
}

// XCD-aware swizzle. gx%8==0: column-slice; else bijective 1D (m204).
#define XCD_SWZ()                                                            \
  int bx = blockIdx.x, by = blockIdx.y;                                      \
  {                                                                          \
    const int gx = gridDim.x;                                                \
    const int id = by * gx + bx;                                             \
    if ((gx & 7) == 0) {                                                     \
      const int cpx = gx >> 3;                                               \
      const int x = id & 7, s = id >> 3;                                     \
      bx = x * cpx + (s % cpx);                                              \
      by = s / cpx;                                                          \
    } else {                                                                 \
      const int nwg = gx * gridDim.y;                                        \
      const int qq = nwg >> 3, rr = nwg & 7;                                 \
      const int x = id & 7, s = id >> 3;                                     \
      const int nid = (x < rr ? x * (qq + 1) : rr * (qq + 1) + (x - rr) * qq) + s; \
      bx = nid % gx; by = nid / gx;                                          \
    }                                                                        \
  }

// ---- K-loop: BK=64, double-buffered, COUNTED vmcnt (T4): no vmcnt(0) mid-loop.
// prologue stages tiles 0,1. iter t: vmcnt(8) [oldest stage landed; next-tile
// stage stays in flight across the barrier] -> raw s_barrier -> compute(buf t&1)
// -> raw s_barrier [all waves' ds_reads done] -> restage tile t+2 into buf t&1.
#define STAGE8(dA, dB, kk)                                                   \
    async_copy16(dA,              gA0 + (kk));                               \
    async_copy16(dA + 512,        gA0 + (size_t)16 * lda + (kk));            \
    async_copy16(dA + 4096,       gA0 + (kk) + 32);                          \
    async_copy16(dA + 4096 + 512, gA0 + (size_t)16 * lda + (kk) + 32);       \
    async_copy16(dB,              gB0 + (kk));                               \
    async_copy16(dB + 512,        gB0 + (size_t)16 * ldb + (kk));            \
    async_copy16(dB + 4096,       gB0 + (kk) + 32);                          \
    async_copy16(dB + 4096 + 512, gB0 + (size_t)16 * ldb + (kk) + 32);

#define KLOOP_DBUF()                                                         \
  const int nIter = K >> 6;                                                  \
  { STAGE8(sA, sB, 0) }                                                      \
  if (nIter > 1) { STAGE8(sA + 8192, sB + 8192, 64) }                        \
  for (int kt = 0; kt < nIter; ++kt) {                                       \
    if (kt + 1 < nIter) asm volatile("s_waitcnt vmcnt(8)" ::: "memory");     \
    else                asm volatile("s_waitcnt vmcnt(0)" ::: "memory");     \
    __builtin_amdgcn_s_barrier();                                            \
    const int cur = (kt & 1) * 8192;                                         \
    _Pragma("unroll")                                                        \
    for (int h = 0; h < 2; ++h) {                                            \
      bf16x8 af[4], bfr[4];                                                  \
      _Pragma("unroll")                                                      \
      for (int mi = 0; mi < 4; ++mi)                                         \
        af[mi] = *(const bf16x8*)&lA[cur + h * 4096 + (wr * 64 + mi * 16 + lr) * 32 + kg * 8]; \
      _Pragma("unroll")                                                      \
      for (int ni = 0; ni < 4; ++ni)                                         \
        bfr[ni] = *(const bf16x8*)&lB[cur + h * 4096 + (wc * 64 + ni * 16 + lr) * 32 + kg * 8]; \
      _Pragma("unroll")                                                      \
      for (int mi = 0; mi < 4; ++mi)                                         \
        _Pragma("unroll")                                                    \
        for (int ni = 0; ni < 4; ++ni)                                       \
          acc[mi][ni] = __builtin_amdgcn_mfma_f32_16x16x32_bf16(af[mi], bfr[ni], acc[mi][ni], 0, 0, 0); \
    }                                                                        \
    __builtin_amdgcn_s_barrier();                                            \
    if (kt + 2 < nIter) {                                                    \
      const int k2 = (kt + 2) << 6;                                          \
      STAGE8(sA + cur, sB + cur, k2)                                         \
    }                                                                        \
  }

#define GEMM_PROLOG()                                                        \
  __shared__ __align__(16) ushort_t lA[2 * 8192];                            \
  __shared__ __align__(16) ushort_t lB[2 * 8192];                            \
  const int tid = threadIdx.x;                                               \
  const int wid = tid >> 6, lane = tid & 63;                                 \
  const int wr = wid >> 1, wc = wid & 1;                                     \
  XCD_SWZ()                                                                  \
  const int m0 = by * 128, n0 = bx * 128;                                    \
  const int lr = lane & 15, kg = lane >> 4;                                  \
  f32x4 acc[4][4] = {};                                                      \
  const int srow = lane >> 2;                                                \
  const int scol = (lane & 3) * 8;                                           \
  const ushort_t* gA0 = A + (size_t)(m0 + wid * 32 + srow) * lda + scol;     \
  const ushort_t* gB0 = B + (size_t)(n0 + wid * 32 + srow) * ldb + scol;     \
  ushort_t* sA = &lA[wid * 1024];                                            \
  ushort_t* sB = &lB[wid * 1024];                                            \
  KLOOP_DBUF()

// Wide GEMM: C = q_hi @ [wihP | wsumP]^T, N=8192, K=512.
// Left (n0<4096): step-0 gates -> cell0 (c bf16, A1.hi lda640, A2.lo).
// Right: gates_base 4-gate-INTERLEAVED: gbase[row*4096 + jj*4 + g] (one 8B store).
__launch_bounds__(256)
__global__ void gemm_wide(const ushort_t* __restrict__ A, const ushort_t* __restrict__ B,
                          ushort_t* __restrict__ gbase, ushort_t* __restrict__ c,
                          ushort_t* __restrict__ A1out, ushort_t* __restrict__ A2out,
                          const float* __restrict__ b1, const float* __restrict__ b2,
                          int K, int lda, int ldb) {
  GEMM_PROLOG()
  if (n0 < 4096) {
    const int jj = ((n0 + wc * 64) >> 6) * 16 + lr;   // 0..1023
    const bool do_h = (n0 + wc * 64) < 2048;          // j < 512
    const float bi0 = b1[jj]        + b2[jj];
    const float bi2 = b1[2048 + jj] + b2[2048 + jj];
    const float bi3 = b1[3072 + jj] + b2[3072 + jj];
#pragma unroll
    for (int mi = 0; mi < 4; ++mi) {
#pragma unroll
      for (int r = 0; r < 4; ++r) {
        const int row = m0 + wr * 64 + mi * 16 + kg * 4 + r;
        const float si = sigmoidf(acc[mi][0][r] + bi0);
        const float tg = tanh_fast(acc[mi][2][r] + bi2);
        const float so = sigmoidf(acc[mi][3][r] + bi3);
        const float cn = si * tg;                      // c_prev = 0
        c[(size_t)row * HDIM + jj] = f2bf(cn);
        if (do_h) {
          const float hr = so * tanh_fast(cn);
          const ushort_t hi = f2bf(hr);
          const ushort_t lo = f2bf(hr - bf2f(hi));
          A1out[(size_t)row * LDA1 + jj] = hi;
          A2out[(size_t)row * DDIM + jj] = lo;
        }
      }
    }
  } else {
    const int jj = ((n0 - 4096 + wc * 64) >> 6) * 16 + lr;  // 0..1023
    const float bi0 = b1[jj]        + b2[jj];
    const float bi1 = b1[1024 + jj] + b2[1024 + jj];
    const float bi2 = b1[2048 + jj] + b2[2048 + jj];
    const float bi3 = b1[3072 + jj] + b2[3072 + jj];
#pragma unroll
    for (int mi = 0; mi < 4; ++mi)
#pragma unroll
      for (int r = 0; r < 4; ++r) {
        const int row = m0 + wr * 64 + mi * 16 + kg * 4 + r;
        uint2 p;
        p.x = (unsigned)f2bf(acc[mi][0][r] + bi0) | ((unsigned)f2bf(acc[mi][1][r] + bi1) << 16);
        p.y = (unsigned)f2bf(acc[mi][2][r] + bi2) | ((unsigned)f2bf(acc[mi][3][r] + bi3) << 16);
        *(uint2*)&gbase[(size_t)row * GDIM + jj * 4] = p;
      }
  }
}

// Fused recurrent GEMM + LSTM cell. K=640: A=[hr'|attn], B=[WhhL|SW]. base interleaved, c bf16.
// MODE 1: cell -> c, A1.hi, A2.lo.  MODE 2: out = query + hr (grid.x = 16).
template<int MODE>
__launch_bounds__(256)
__global__ void gemm_fused(const ushort_t* __restrict__ A, const ushort_t* __restrict__ B,
                           const ushort_t* __restrict__ base, ushort_t* __restrict__ c,
                           ushort_t* __restrict__ A1out, ushort_t* __restrict__ A2out,
                           const float* __restrict__ query, float* __restrict__ out,
                           int K, int lda, int ldb) {
  GEMM_PROLOG()
  const int jj = ((n0 + wc * 64) >> 6) * 16 + lr;
  const bool do_h = (MODE == 2) || ((n0 + wc * 64) < 2048);
#pragma unroll
  for (int mi = 0; mi < 4; ++mi) {
#pragma unroll
    for (int r = 0; r < 4; ++r) {
      const int row = m0 + wr * 64 + mi * 16 + kg * 4 + r;
      const uint2 p = *(const uint2*)&base[(size_t)row * GDIM + jj * 4];
      const float g0 = bf2f_u(p.x & 0xFFFFu) + acc[mi][0][r];
      const float g1 = bf2f_u(p.x >> 16)     + acc[mi][1][r];
      const float g2 = bf2f_u(p.y & 0xFFFFu) + acc[mi][2][r];
      const float g3 = bf2f_u(p.y >> 16)     + acc[mi][3][r];
      const float si = sigmoidf(g0);
      const float sf = sigmoidf(g1);
      const float tg = tanh_fast(g2);
      const float so = sigmoidf(g3);
      const size_t ci = (size_t)row * HDIM + jj;
      const float cn = sf * bf2f(c[ci]) + si * tg;
      if (MODE != 2) c[ci] = f2bf(cn);
      if (do_h) {
        const float hr = so * tanh_fast(cn);
        if (MODE == 2) {
          out[(size_t)row * DDIM + jj] = query[(size_t)row * DDIM + jj] + hr;
        } else {
          const ushort_t hi = f2bf(hr);
          const ushort_t lo = f2bf(hr - bf2f(hi));
          A1out[(size_t)row * LDA1 + jj] = hi;
          A2out[(size_t)row * DDIM + jj] = lo;
        }
      }
    }
  }
}

// Unified 6-chunk split-K logits: grid (6, 32). seg=c>>1, half=c&1 (K 256 each).
// atomicAdd into prefilled Cf. B rows 0..127 only.
__launch_bounds__(256)
__global__ void gemm_splitk6(const ushort_t* __restrict__ A1, const ushort_t* __restrict__ A2,
                             int lda1, int lda2,
                             const ushort_t* __restrict__ Bc, float* __restrict__ Cf) {
  __shared__ __align__(16) ushort_t lA[2 * 8192];
  __shared__ __align__(16) ushort_t lB[2 * 8192];
  const int tid = threadIdx.x;
  const int wid = tid >> 6, lane = tid & 63;
  const int wr = wid >> 1, wc = wid & 1;
  const int seg = blockIdx.x >> 1;       // 0..2
  const int koff = (blockIdx.x & 1) * 256;
  const int m0 = blockIdx.y * 128;
  const int lr = lane & 15, kg = lane >> 4;
  f32x4 acc[4][4] = {};
  const int srow = lane >> 2;
  const int scol = (lane & 3) * 8;
  const ushort_t* A = (seg == 1) ? A2 : A1;
  const int lda = (seg == 1) ? lda2 : lda1;
  const int ldb = 1536;
  const ushort_t* gA0 = A + (size_t)(m0 + wid * 32 + srow) * lda + koff + scol;
  const ushort_t* gB0 = Bc + (size_t)(wid * 32 + srow) * 1536 + seg * 512 + koff + scol;
  ushort_t* sA = &lA[wid * 1024];
  ushort_t* sB = &lB[wid * 1024];
  const int K = 256;
  KLOOP_DBUF()
#pragma unroll
  for (int mi = 0; mi < 4; ++mi)
#pragma unroll
    for (int ni = 0; ni < 4; ++ni)
#pragma unroll
      for (int r = 0; r < 4; ++r) {
        const int row = m0 + wr * 64 + mi * 16 + kg * 4 + r;
        const int col = wc * 64 + ni * 16 + lr;
        atomicAdd(&Cf[(size_t)row * FEWN + col], acc[mi][ni][r]);
      }
}

// generic: EPI 2 = bf16(acc) -> Cb
template<int EPI>
__launch_bounds__(256)
__global__ void gemm_bt(const ushort_t* __restrict__ A, const ushort_t* __restrict__ B,
                        float* __restrict__ Cf, ushort_t* __restrict__ Cb,
                        int K, int lda, int ldb, int ldc) {
  GEMM_PROLOG()
#pragma unroll
  for (int mi = 0; mi < 4; ++mi)
#pragma unroll
    for (int ni = 0; ni < 4; ++ni)
#pragma unroll
      for (int r = 0; r < 4; ++r) {
        const int row = m0 + wr * 64 + mi * 16 + kg * 4 + r;
        const int col = n0 + wc * 64 + ni * 16 + lr;
        const float v = acc[mi][ni][r];
        const size_t o = (size_t)row * ldc + col;
        if (EPI == 2) Cb[o] = f2bf(v);
        else          Cf[o] = v;
      }
}

// broadcast base logits: lg[LOFS + i] = lg[2*LOFS + i] = lg[i]
__global__ void broadcast3(float* __restrict__ lg) {
  const size_t LOFS = (size_t)BATCH * FEWN;
  const int i = blockIdx.x * 256 + threadIdx.x;   // over LOFS/4 float4s
  const float4 v = ((const float4*)lg)[i];
  ((float4*)(lg + LOFS))[i] = v;
  ((float4*)(lg + 2 * LOFS))[i] = v;
}

// softmax: reads logits row, writes attn bf16 directly into A1[:, 512:640]
__global__ void softmax_kernel(const float* __restrict__ logits, ushort_t* __restrict__ A1) {
  const int row = blockIdx.x * 4 + (threadIdx.x >> 6);
  const int lane = threadIdx.x & 63;
  const float* L = logits + (size_t)row * FEWN;
  const float x0 = L[lane], x1 = L[lane + 64];
  float m = fmaxf(x0, x1);
#pragma unroll
  for (int s = 32; s > 0; s >>= 1) m = fmaxf(m, __shfl_xor(m, s));
  const float e0 = __expf(x0 - m), e1 = __expf(x1 - m);
  float sum = e0 + e1;
#pragma unroll
  for (int s = 32; s > 0; s >>= 1) sum += __shfl_xor(sum, s);
  const float inv = 1.f / sum;
  A1[(size_t)row * LDA1 + 512 + lane]      = f2bf(e0 * inv);
  A1[(size_t)row * LDA1 + 512 + 64 + lane] = f2bf(e1 * inv);
}

// wcomb [8192][512]: rows 0-4095 = bf16(W_ih[og]); 4096-8191 = bf16(W_ih[og]+W_hhL[og])
__global__ void build_wcomb(const float* __restrict__ Wih, const float* __restrict__ Whh,
                            ushort_t* __restrict__ out) {
  const int idx = blockIdx.x * 256 + threadIdx.x;  // 8192*512
  const int r = idx >> 9, cc = idx & 511;
  ushort_t v;
  if (r < 4096) {
    v = f2bf(Wih[(size_t)orig_row(r) * 512 + cc]);
  } else {
    const int og = orig_row(r - 4096);
    v = f2bf(Wih[(size_t)og * 512 + cc] + Whh[(size_t)og * 1024 + cc]);
  }
  out[idx] = v;
}

// one pass over W_hh: cols 0-511 -> B2[r*640+k]; cols 512-1023 -> whhRP[r*512+(k-512)]
__global__ void build_whh_both(const float* __restrict__ W, ushort_t* __restrict__ B2,
                               ushort_t* __restrict__ whhRP) {
  const int idx = blockIdx.x * 256 + threadIdx.x;  // 4096*1024
  const int r = idx >> 10, k = idx & 1023;
  const ushort_t v = f2bf(W[(size_t)orig_row(r) * 1024 + k]);
  if (k < 512) B2[(size_t)r * LDA1 + k] = v;
  else         whhRP[(size_t)r * 512 + (k - 512)] = v;
}

// Q_cat [4096][1536] = [q_hi, q_lo, q_hi]
__global__ void build_qcat(const float* __restrict__ q, ushort_t* __restrict__ out) {
  const int idx = blockIdx.x * 256 + threadIdx.x;  // 4096*512
  const int b = idx >> 9, cc = idx & 511;
  const float v = q[idx];
  const ushort_t hi = f2bf(v);
  const ushort_t lo = f2bf(v - bf2f(hi));
  const size_t ro = (size_t)b * 1536;
  out[ro + cc] = hi;
  out[ro + 512 + cc] = lo;
  out[ro + 1024 + cc] = hi;
}

// B_cat [128][1536] = [s_hi, s_hi, s_lo]
__global__ void build_bcat(const float* __restrict__ s, ushort_t* __restrict__ out) {
  const int idx = blockIdx.x * 256 + threadIdx.x;  // 128*512
  const int n = idx >> 9, cc = idx & 511;
  const float v = s[idx];
  const ushort_t hi = f2bf(v);
  const ushort_t lo = f2bf(v - bf2f(hi));
  const size_t ro = (size_t)n * 1536;
  out[ro + cc] = hi;
  out[ro + 512 + cc] = hi;
  out[ro + 1024 + cc] = lo;
}

extern "C" void kernel_launch(void* const* d_in, const int* in_sizes, int n_in,
                              void* d_out, int out_size, void* d_ws, size_t ws_size,
                              hipStream_t stream) {
  const float* support = (const float*)d_in[0];
  const float* query   = (const float*)d_in[1];
  const float* W_ih    = (const float*)d_in[2];
  const float* W_hh    = (const float*)d_in[3];
  const float* b_ih    = (const float*)d_in[4];
  const float* b_hh    = (const float*)d_in[5];
  float* out = (float*)d_out;

  char* ws = (char*)d_ws;
  size_t off = 0;
  auto alloc = [&](size_t bytes) { char* p = ws + off; off += (bytes + 255) & ~255ull; return p; };
  ushort_t* gates_baseP = (ushort_t*)alloc((size_t)BATCH * GDIM * 2);   // 32MB (interleaved)
  ushort_t* cbuf        = (ushort_t*)alloc((size_t)BATCH * HDIM * 2);   // 8MB bf16
  ushort_t* A1a         = (ushort_t*)alloc((size_t)BATCH * LDA1 * 2);   // 5MB [hr | attn]
  ushort_t* A1b         = (ushort_t*)alloc((size_t)BATCH * LDA1 * 2);   // 5MB
  ushort_t* A2a         = (ushort_t*)alloc((size_t)BATCH * DDIM * 2);   // 4MB lo
  ushort_t* A2b         = (ushort_t*)alloc((size_t)BATCH * DDIM * 2);   // 4MB
  ushort_t* Q_cat       = (ushort_t*)alloc((size_t)BATCH * 1536 * 2);   // 12MB
  ushort_t* wcomb       = (ushort_t*)alloc((size_t)8192 * 512 * 2);     // 8MB
  ushort_t* B2          = (ushort_t*)alloc((size_t)GDIM * LDA1 * 2);    // 5MB [WhhL | SW]
  ushort_t* whhRP       = (ushort_t*)alloc((size_t)GDIM * 512 * 2);     // 4MB
  ushort_t* B_cat       = (ushort_t*)alloc((size_t)FEWN * 1536 * 2);
  float*    logits3     = (float*)   alloc((size_t)3 * BATCH * FEWN * 4); // 6MB

  const size_t LOFS = (size_t)BATCH * FEWN;
  const dim3 blk(256);

  // ---- setup ----
  build_wcomb<<<8192 * 512 / 256, blk, 0, stream>>>(W_ih, W_hh, wcomb);
  build_whh_both<<<GDIM * 1024 / 256, blk, 0, stream>>>(W_hh, B2, whhRP);
  build_qcat<<<BATCH * 512 / 256, blk, 0, stream>>>(query, Q_cat);
  build_bcat<<<FEWN * 512 / 256, blk, 0, stream>>>(support, B_cat);

  // logits_base = Q_cat @ B_cat^T via 6-chunk split-K (192 blocks), then broadcast x3
  hipMemsetAsync(logits3, 0, LOFS * 4, stream);
  gemm_splitk6<<<dim3(6, 32), blk, 0, stream>>>(Q_cat, Q_cat + 512, 1536, 1536,
                                                B_cat, logits3);
  broadcast3<<<(int)(LOFS / 4 / 256), blk, 0, stream>>>(logits3);

  // SW = W_hhR_P @ support^T -> bf16 into B2[:, 512:640]  (low-rank factorization)
  gemm_bt<2><<<dim3(1, 32), blk, 0, stream>>>(whhRP, B_cat, nullptr, B2 + 512,
                                              512, 512, 1536, LDA1);

  // wide GEMM (K=512): left = step-0 gates + cell0; right = gates_base (interleaved)
  gemm_wide<<<dim3(64, 32), blk, 0, stream>>>(
      Q_cat, wcomb, gates_baseP, cbuf, A1a, A2a, b_ih, b_hh, 512, 1536, 512);

  auto attn_phase = [&](int s, ushort_t* A1, ushort_t* A2) {
    float* lg = logits3 + (size_t)s * LOFS;
    gemm_splitk6<<<dim3(6, 32), blk, 0, stream>>>(A1, A2, LDA1, DDIM, B_cat, lg);
    softmax_kernel<<<BATCH / 4, blk, 0, stream>>>(lg, A1);  // attn -> A1[:,512:640]
  };

  attn_phase(0, A1a, A2a);

  // step 1: A = [hr_0 | attn_0] (A1a), K=640 -> A1b/A2b
  gemm_fused<1><<<dim3(32, 32), blk, 0, stream>>>(
      A1a, B2, gates_baseP, cbuf, A1b, A2b, nullptr, nullptr, 640, LDA1, LDA1);
  attn_phase(1, A1b, A2b);

  // step 2: A1b -> A1a/A2a
  gemm_fused<1><<<dim3(32, 32), blk, 0, stream>>>(
      A1b, B2, gates_baseP, cbuf, A1a, A2a, nullptr, nullptr, 640, LDA1, LDA1);
  attn_phase(2, A1a, A2a);

  // step 3 (last): only j<512 -> half grid; out = query + hr
  gemm_fused<2><<<dim3(16, 32), blk, 0, stream>>>(
      A1a, B2, gates_baseP, cbuf, nullptr, nullptr, query, out, 640, LDA1, LDA1);
}

// Round 18
// 197.151 us; speedup vs baseline: 2.9432x; 1.3913x over previous
//
#include <hip/hip_runtime.h>

#define BATCH 4096
#define DDIM  512
#define FEWN  128
#define LDA1  640     // A1 = [hr'(512) | attn(128)]
#define GATEN 2048    // live permuted gate cols (j<512 only: j>=512 half is DEAD CODE)
#define CDIM  512     // live c-state width

typedef unsigned short ushort_t;
typedef __attribute__((ext_vector_type(8))) short bf16x8;
typedef __attribute__((ext_vector_type(4))) float f32x4;

__device__ inline ushort_t f2bf(float f) {
  unsigned u = __float_as_uint(f);
  unsigned r = (u + 0x7FFFu + ((u >> 16) & 1u)) >> 16;
  return (ushort_t)r;
}
__device__ inline float bf2f(ushort_t h) { return __uint_as_float((unsigned)h << 16); }
__device__ inline float bf2f_u(unsigned h16) { return __uint_as_float(h16 << 16); }

__device__ inline float sigmoidf(float x) { return 1.f / (1.f + __expf(-x)); }
__device__ inline float tanh_fast(float x) {
  float ax = fabsf(x);
  float t = __expf(-2.f * ax);
  float r = (1.f - t) / (1.f + t);
  return copysignf(r, x);
}

// permuted layout over LIVE cols colp<2048: j = (colp>>6)*16 + (colp&15) in [0,512),
// gate g = (colp>>4)&3; original W row = g*1024 + j.
__device__ inline int orig_row(int colp) {
  return ((colp >> 4) & 3) * 1024 + ((colp >> 6) << 4) + (colp & 15);
}

__device__ inline void async_copy16(ushort_t* lds, const ushort_t* g) {
  __builtin_amdgcn_global_load_lds(
      (const __attribute__((address_space(1))) unsigned int*)g,
      (__attribute__((address_space(3))) unsigned int*)lds, 16, 0, 0);
}

// XCD-aware swizzle. gx%8==0: column-slice; else bijective 1D (m204).
#define XCD_SWZ()                                                            \
  int bx = blockIdx.x, by = blockIdx.y;                                      \
  {                                                                          \
    const int gx = gridDim.x;                                                \
    const int id = by * gx + bx;                                             \
    if ((gx & 7) == 0) {                                                     \
      const int cpx = gx >> 3;                                               \
      const int x = id & 7, s = id >> 3;                                     \
      bx = x * cpx + (s % cpx);                                              \
      by = s / cpx;                                                          \
    } else {                                                                 \
      const int nwg = gx * gridDim.y;                                        \
      const int qq = nwg >> 3, rr = nwg & 7;                                 \
      const int x = id & 7, s = id >> 3;                                     \
      const int nid = (x < rr ? x * (qq + 1) : rr * (qq + 1) + (x - rr) * qq) + s; \
      bx = nid % gx; by = nid / gx;                                          \
    }                                                                        \
  }

// ---- K-loop: BK=64, double-buffered, counted vmcnt (no vmcnt(0) mid-loop).
#define STAGE8(dA, dB, kk)                                                   \
    async_copy16(dA,              gA0 + (kk));                               \
    async_copy16(dA + 512,        gA0 + (size_t)16 * lda + (kk));            \
    async_copy16(dA + 4096,       gA0 + (kk) + 32);                          \
    async_copy16(dA + 4096 + 512, gA0 + (size_t)16 * lda + (kk) + 32);       \
    async_copy16(dB,              gB0 + (kk));                               \
    async_copy16(dB + 512,        gB0 + (size_t)16 * ldb + (kk));            \
    async_copy16(dB + 4096,       gB0 + (kk) + 32);                          \
    async_copy16(dB + 4096 + 512, gB0 + (size_t)16 * ldb + (kk) + 32);

#define KLOOP_DBUF()                                                         \
  const int nIter = K >> 6;                                                  \
  { STAGE8(sA, sB, 0) }                                                      \
  if (nIter > 1) { STAGE8(sA + 8192, sB + 8192, 64) }                        \
  for (int kt = 0; kt < nIter; ++kt) {                                       \
    if (kt + 1 < nIter) asm volatile("s_waitcnt vmcnt(8)" ::: "memory");     \
    else                asm volatile("s_waitcnt vmcnt(0)" ::: "memory");     \
    __builtin_amdgcn_s_barrier();                                            \
    const int cur = (kt & 1) * 8192;                                         \
    _Pragma("unroll")                                                        \
    for (int h = 0; h < 2; ++h) {                                            \
      bf16x8 af[4], bfr[4];                                                  \
      _Pragma("unroll")                                                      \
      for (int mi = 0; mi < 4; ++mi)                                         \
        af[mi] = *(const bf16x8*)&lA[cur + h * 4096 + (wr * 64 + mi * 16 + lr) * 32 + kg * 8]; \
      _Pragma("unroll")                                                      \
      for (int ni = 0; ni < 4; ++ni)                                         \
        bfr[ni] = *(const bf16x8*)&lB[cur + h * 4096 + (wc * 64 + ni * 16 + lr) * 32 + kg * 8]; \
      _Pragma("unroll")                                                      \
      for (int mi = 0; mi < 4; ++mi)                                         \
        _Pragma("unroll")                                                    \
        for (int ni = 0; ni < 4; ++ni)                                       \
          acc[mi][ni] = __builtin_amdgcn_mfma_f32_16x16x32_bf16(af[mi], bfr[ni], acc[mi][ni], 0, 0, 0); \
    }                                                                        \
    __builtin_amdgcn_s_barrier();                                            \
    if (kt + 2 < nIter) {                                                    \
      const int k2 = (kt + 2) << 6;                                          \
      STAGE8(sA + cur, sB + cur, k2)                                         \
    }                                                                        \
  }

#define GEMM_PROLOG()                                                        \
  __shared__ __align__(16) ushort_t lA[2 * 8192];                            \
  __shared__ __align__(16) ushort_t lB[2 * 8192];                            \
  const int tid = threadIdx.x;                                               \
  const int wid = tid >> 6, lane = tid & 63;                                 \
  const int wr = wid >> 1, wc = wid & 1;                                     \
  XCD_SWZ()                                                                  \
  const int m0 = by * 128, n0 = bx * 128;                                    \
  const int lr = lane & 15, kg = lane >> 4;                                  \
  f32x4 acc[4][4] = {};                                                      \
  const int srow = lane >> 2;                                                \
  const int scol = (lane & 3) * 8;                                           \
  const ushort_t* gA0 = A + (size_t)(m0 + wid * 32 + srow) * lda + scol;     \
  const ushort_t* gB0 = B + (size_t)(n0 + wid * 32 + srow) * ldb + scol;     \
  ushort_t* sA = &lA[wid * 1024];                                            \
  ushort_t* sB = &lB[wid * 1024];                                            \
  KLOOP_DBUF()

// Wide GEMM: C = q_hi @ [wihP | wsumP]^T, N=4096 (live cols only), K=512.
// Left (n0<2048): step-0 gates -> cell0 (c bf16 [4096][512], A1.hi, A2.lo).
// Right: gates_base 4-gate-interleaved: gbase[row*2048 + jj*4 + g] (one 8B store).
__launch_bounds__(256)
__global__ void gemm_wide(const ushort_t* __restrict__ A, const ushort_t* __restrict__ B,
                          ushort_t* __restrict__ gbase, ushort_t* __restrict__ c,
                          ushort_t* __restrict__ A1out, ushort_t* __restrict__ A2out,
                          const float* __restrict__ b1, const float* __restrict__ b2,
                          int K, int lda, int ldb) {
  GEMM_PROLOG()
  if (n0 < 2048) {
    const int jj = ((n0 + wc * 64) >> 6) * 16 + lr;   // 0..511
    const float bi0 = b1[jj]        + b2[jj];
    const float bi2 = b1[2048 + jj] + b2[2048 + jj];
    const float bi3 = b1[3072 + jj] + b2[3072 + jj];
#pragma unroll
    for (int mi = 0; mi < 4; ++mi) {
#pragma unroll
      for (int r = 0; r < 4; ++r) {
        const int row = m0 + wr * 64 + mi * 16 + kg * 4 + r;
        const float si = sigmoidf(acc[mi][0][r] + bi0);
        const float tg = tanh_fast(acc[mi][2][r] + bi2);
        const float so = sigmoidf(acc[mi][3][r] + bi3);
        const float cn = si * tg;                      // c_prev = 0
        c[(size_t)row * CDIM + jj] = f2bf(cn);
        const float hr = so * tanh_fast(cn);
        const ushort_t hi = f2bf(hr);
        const ushort_t lo = f2bf(hr - bf2f(hi));
        A1out[(size_t)row * LDA1 + jj] = hi;
        A2out[(size_t)row * DDIM + jj] = lo;
      }
    }
  } else {
    const int jj = ((n0 - 2048 + wc * 64) >> 6) * 16 + lr;  // 0..511
    const float bi0 = b1[jj]        + b2[jj];
    const float bi1 = b1[1024 + jj] + b2[1024 + jj];
    const float bi2 = b1[2048 + jj] + b2[2048 + jj];
    const float bi3 = b1[3072 + jj] + b2[3072 + jj];
#pragma unroll
    for (int mi = 0; mi < 4; ++mi)
#pragma unroll
      for (int r = 0; r < 4; ++r) {
        const int row = m0 + wr * 64 + mi * 16 + kg * 4 + r;
        uint2 p;
        p.x = (unsigned)f2bf(acc[mi][0][r] + bi0) | ((unsigned)f2bf(acc[mi][1][r] + bi1) << 16);
        p.y = (unsigned)f2bf(acc[mi][2][r] + bi2) | ((unsigned)f2bf(acc[mi][3][r] + bi3) << 16);
        *(uint2*)&gbase[(size_t)row * GATEN + jj * 4] = p;
      }
  }
}

// Fused recurrent GEMM + LSTM cell. N=2048 (live), K=640: A=[hr'|attn], B=[WhhL|SW].
// MODE 1: cell -> c, A1.hi, A2.lo.  MODE 2: out = query + hr. Grid (16,32) both.
template<int MODE>
__launch_bounds__(256)
__global__ void gemm_fused(const ushort_t* __restrict__ A, const ushort_t* __restrict__ B,
                           const ushort_t* __restrict__ base, ushort_t* __restrict__ c,
                           ushort_t* __restrict__ A1out, ushort_t* __restrict__ A2out,
                           const float* __restrict__ query, float* __restrict__ out,
                           int K, int lda, int ldb) {
  GEMM_PROLOG()
  const int jj = ((n0 + wc * 64) >> 6) * 16 + lr;   // 0..511
#pragma unroll
  for (int mi = 0; mi < 4; ++mi) {
#pragma unroll
    for (int r = 0; r < 4; ++r) {
      const int row = m0 + wr * 64 + mi * 16 + kg * 4 + r;
      const uint2 p = *(const uint2*)&base[(size_t)row * GATEN + jj * 4];
      const float g0 = bf2f_u(p.x & 0xFFFFu) + acc[mi][0][r];
      const float g1 = bf2f_u(p.x >> 16)     + acc[mi][1][r];
      const float g2 = bf2f_u(p.y & 0xFFFFu) + acc[mi][2][r];
      const float g3 = bf2f_u(p.y >> 16)     + acc[mi][3][r];
      const float si = sigmoidf(g0);
      const float sf = sigmoidf(g1);
      const float tg = tanh_fast(g2);
      const float so = sigmoidf(g3);
      const size_t ci = (size_t)row * CDIM + jj;
      const float cn = sf * bf2f(c[ci]) + si * tg;
      if (MODE != 2) c[ci] = f2bf(cn);
      const float hr = so * tanh_fast(cn);
      if (MODE == 2) {
        out[(size_t)row * DDIM + jj] = query[(size_t)row * DDIM + jj] + hr;
      } else {
        const ushort_t hi = f2bf(hr);
        const ushort_t lo = f2bf(hr - bf2f(hi));
        A1out[(size_t)row * LDA1 + jj] = hi;
        A2out[(size_t)row * DDIM + jj] = lo;
      }
    }
  }
}

// Unified 6-chunk split-K logits: grid (6, 32). seg=c>>1, half=c&1 (K 256 each).
// atomicAdd into prefilled Cf. B rows 0..127 only.
__launch_bounds__(256)
__global__ void gemm_splitk6(const ushort_t* __restrict__ A1, const ushort_t* __restrict__ A2,
                             int lda1, int lda2,
                             const ushort_t* __restrict__ Bc, float* __restrict__ Cf) {
  __shared__ __align__(16) ushort_t lA[2 * 8192];
  __shared__ __align__(16) ushort_t lB[2 * 8192];
  const int tid = threadIdx.x;
  const int wid = tid >> 6, lane = tid & 63;
  const int wr = wid >> 1, wc = wid & 1;
  const int seg = blockIdx.x >> 1;       // 0..2
  const int koff = (blockIdx.x & 1) * 256;
  const int m0 = blockIdx.y * 128;
  const int lr = lane & 15, kg = lane >> 4;
  f32x4 acc[4][4] = {};
  const int srow = lane >> 2;
  const int scol = (lane & 3) * 8;
  const ushort_t* A = (seg == 1) ? A2 : A1;
  const int lda = (seg == 1) ? lda2 : lda1;
  const int ldb = 1536;
  const ushort_t* gA0 = A + (size_t)(m0 + wid * 32 + srow) * lda + koff + scol;
  const ushort_t* gB0 = Bc + (size_t)(wid * 32 + srow) * 1536 + seg * 512 + koff + scol;
  ushort_t* sA = &lA[wid * 1024];
  ushort_t* sB = &lB[wid * 1024];
  const int K = 256;
  KLOOP_DBUF()
#pragma unroll
  for (int mi = 0; mi < 4; ++mi)
#pragma unroll
    for (int ni = 0; ni < 4; ++ni)
#pragma unroll
      for (int r = 0; r < 4; ++r) {
        const int row = m0 + wr * 64 + mi * 16 + kg * 4 + r;
        const int col = wc * 64 + ni * 16 + lr;
        atomicAdd(&Cf[(size_t)row * FEWN + col], acc[mi][ni][r]);
      }
}

// generic: EPI 2 = bf16(acc) -> Cb
template<int EPI>
__launch_bounds__(256)
__global__ void gemm_bt(const ushort_t* __restrict__ A, const ushort_t* __restrict__ B,
                        float* __restrict__ Cf, ushort_t* __restrict__ Cb,
                        int K, int lda, int ldb, int ldc) {
  GEMM_PROLOG()
#pragma unroll
  for (int mi = 0; mi < 4; ++mi)
#pragma unroll
    for (int ni = 0; ni < 4; ++ni)
#pragma unroll
      for (int r = 0; r < 4; ++r) {
        const int row = m0 + wr * 64 + mi * 16 + kg * 4 + r;
        const int col = n0 + wc * 64 + ni * 16 + lr;
        const float v = acc[mi][ni][r];
        const size_t o = (size_t)row * ldc + col;
        if (EPI == 2) Cb[o] = f2bf(v);
        else          Cf[o] = v;
      }
}

// broadcast base logits: lg[LOFS + i] = lg[2*LOFS + i] = lg[i]
__global__ void broadcast3(float* __restrict__ lg) {
  const size_t LOFS = (size_t)BATCH * FEWN;
  const int i = blockIdx.x * 256 + threadIdx.x;   // over LOFS/4 float4s
  const float4 v = ((const float4*)lg)[i];
  ((float4*)(lg + LOFS))[i] = v;
  ((float4*)(lg + 2 * LOFS))[i] = v;
}

// softmax: reads logits row, writes attn bf16 directly into A1[:, 512:640]
__global__ void softmax_kernel(const float* __restrict__ logits, ushort_t* __restrict__ A1) {
  const int row = blockIdx.x * 4 + (threadIdx.x >> 6);
  const int lane = threadIdx.x & 63;
  const float* L = logits + (size_t)row * FEWN;
  const float x0 = L[lane], x1 = L[lane + 64];
  float m = fmaxf(x0, x1);
#pragma unroll
  for (int s = 32; s > 0; s >>= 1) m = fmaxf(m, __shfl_xor(m, s));
  const float e0 = __expf(x0 - m), e1 = __expf(x1 - m);
  float sum = e0 + e1;
#pragma unroll
  for (int s = 32; s > 0; s >>= 1) sum += __shfl_xor(sum, s);
  const float inv = 1.f / sum;
  A1[(size_t)row * LDA1 + 512 + lane]      = f2bf(e0 * inv);
  A1[(size_t)row * LDA1 + 512 + 64 + lane] = f2bf(e1 * inv);
}

// wcomb [4096][512]: rows 0-2047 = bf16(W_ih[og]); 2048-4095 = bf16(W_ih[og]+W_hhL[og])
__global__ void build_wcomb(const float* __restrict__ Wih, const float* __restrict__ Whh,
                            ushort_t* __restrict__ out) {
  const int idx = blockIdx.x * 256 + threadIdx.x;  // 4096*512
  const int r = idx >> 9, cc = idx & 511;
  ushort_t v;
  if (r < 2048) {
    v = f2bf(Wih[(size_t)orig_row(r) * 512 + cc]);
  } else {
    const int og = orig_row(r - 2048);
    v = f2bf(Wih[(size_t)og * 512 + cc] + Whh[(size_t)og * 1024 + cc]);
  }
  out[idx] = v;
}

// one pass over live W_hh rows: cols 0-511 -> B2[r*640+k]; 512-1023 -> whhRP[r*512+(k-512)]
__global__ void build_whh_both(const float* __restrict__ W, ushort_t* __restrict__ B2,
                               ushort_t* __restrict__ whhRP) {
  const int idx = blockIdx.x * 256 + threadIdx.x;  // 2048*1024
  const int r = idx >> 10, k = idx & 1023;
  const ushort_t v = f2bf(W[(size_t)orig_row(r) * 1024 + k]);
  if (k < 512) B2[(size_t)r * LDA1 + k] = v;
  else         whhRP[(size_t)r * 512 + (k - 512)] = v;
}

// Q_cat [4096][1536] = [q_hi, q_lo, q_hi]
__global__ void build_qcat(const float* __restrict__ q, ushort_t* __restrict__ out) {
  const int idx = blockIdx.x * 256 + threadIdx.x;  // 4096*512
  const int b = idx >> 9, cc = idx & 511;
  const float v = q[idx];
  const ushort_t hi = f2bf(v);
  const ushort_t lo = f2bf(v - bf2f(hi));
  const size_t ro = (size_t)b * 1536;
  out[ro + cc] = hi;
  out[ro + 512 + cc] = lo;
  out[ro + 1024 + cc] = hi;
}

// B_cat [128][1536] = [s_hi, s_hi, s_lo]
__global__ void build_bcat(const float* __restrict__ s, ushort_t* __restrict__ out) {
  const int idx = blockIdx.x * 256 + threadIdx.x;  // 128*512
  const int n = idx >> 9, cc = idx & 511;
  const float v = s[idx];
  const ushort_t hi = f2bf(v);
  const ushort_t lo = f2bf(v - bf2f(hi));
  const size_t ro = (size_t)n * 1536;
  out[ro + cc] = hi;
  out[ro + 512 + cc] = hi;
  out[ro + 1024 + cc] = lo;
}

extern "C" void kernel_launch(void* const* d_in, const int* in_sizes, int n_in,
                              void* d_out, int out_size, void* d_ws, size_t ws_size,
                              hipStream_t stream) {
  const float* support = (const float*)d_in[0];
  const float* query   = (const float*)d_in[1];
  const float* W_ih    = (const float*)d_in[2];
  const float* W_hh    = (const float*)d_in[3];
  const float* b_ih    = (const float*)d_in[4];
  const float* b_hh    = (const float*)d_in[5];
  float* out = (float*)d_out;

  char* ws = (char*)d_ws;
  size_t off = 0;
  auto alloc = [&](size_t bytes) { char* p = ws + off; off += (bytes + 255) & ~255ull; return p; };
  ushort_t* gates_baseP = (ushort_t*)alloc((size_t)BATCH * GATEN * 2);  // 16MB (interleaved, live)
  ushort_t* cbuf        = (ushort_t*)alloc((size_t)BATCH * CDIM * 2);   // 4MB bf16 (live)
  ushort_t* A1a         = (ushort_t*)alloc((size_t)BATCH * LDA1 * 2);   // 5MB [hr | attn]
  ushort_t* A1b         = (ushort_t*)alloc((size_t)BATCH * LDA1 * 2);   // 5MB
  ushort_t* A2a         = (ushort_t*)alloc((size_t)BATCH * DDIM * 2);   // 4MB lo
  ushort_t* A2b         = (ushort_t*)alloc((size_t)BATCH * DDIM * 2);   // 4MB
  ushort_t* Q_cat       = (ushort_t*)alloc((size_t)BATCH * 1536 * 2);   // 12MB
  ushort_t* wcomb       = (ushort_t*)alloc((size_t)4096 * 512 * 2);     // 4MB
  ushort_t* B2          = (ushort_t*)alloc((size_t)GATEN * LDA1 * 2);   // 2.6MB [WhhL | SW]
  ushort_t* whhRP       = (ushort_t*)alloc((size_t)GATEN * 512 * 2);    // 2MB
  ushort_t* B_cat       = (ushort_t*)alloc((size_t)FEWN * 1536 * 2);
  float*    logits3     = (float*)   alloc((size_t)3 * BATCH * FEWN * 4); // 6MB

  const size_t LOFS = (size_t)BATCH * FEWN;
  const dim3 blk(256);

  // ---- setup ----
  build_wcomb<<<4096 * 512 / 256, blk, 0, stream>>>(W_ih, W_hh, wcomb);
  build_whh_both<<<GATEN * 1024 / 256, blk, 0, stream>>>(W_hh, B2, whhRP);
  build_qcat<<<BATCH * 512 / 256, blk, 0, stream>>>(query, Q_cat);
  build_bcat<<<FEWN * 512 / 256, blk, 0, stream>>>(support, B_cat);

  // logits_base = Q_cat @ B_cat^T via 6-chunk split-K (192 blocks), then broadcast x3
  hipMemsetAsync(logits3, 0, LOFS * 4, stream);
  gemm_splitk6<<<dim3(6, 32), blk, 0, stream>>>(Q_cat, Q_cat + 512, 1536, 1536,
                                                B_cat, logits3);
  broadcast3<<<(int)(LOFS / 4 / 256), blk, 0, stream>>>(logits3);

  // SW = W_hhR_P @ support^T -> bf16 into B2[:, 512:640]  (M = 2048 live rows)
  gemm_bt<2><<<dim3(1, 16), blk, 0, stream>>>(whhRP, B_cat, nullptr, B2 + 512,
                                              512, 512, 1536, LDA1);

  // wide GEMM (N=4096, K=512): left = step-0 gates + cell0; right = gates_base
  gemm_wide<<<dim3(32, 32), blk, 0, stream>>>(
      Q_cat, wcomb, gates_baseP, cbuf, A1a, A2a, b_ih, b_hh, 512, 1536, 512);

  auto attn_phase = [&](int s, ushort_t* A1, ushort_t* A2) {
    float* lg = logits3 + (size_t)s * LOFS;
    gemm_splitk6<<<dim3(6, 32), blk, 0, stream>>>(A1, A2, LDA1, DDIM, B_cat, lg);
    softmax_kernel<<<BATCH / 4, blk, 0, stream>>>(lg, A1);  // attn -> A1[:,512:640]
  };

  attn_phase(0, A1a, A2a);

  // step 1: A = [hr_0 | attn_0] (A1a), N=2048, K=640 -> A1b/A2b
  gemm_fused<1><<<dim3(16, 32), blk, 0, stream>>>(
      A1a, B2, gates_baseP, cbuf, A1b, A2b, nullptr, nullptr, 640, LDA1, LDA1);
  attn_phase(1, A1b, A2b);

  // step 2: A1b -> A1a/A2a
  gemm_fused<1><<<dim3(16, 32), blk, 0, stream>>>(
      A1b, B2, gates_baseP, cbuf, A1a, A2a, nullptr, nullptr, 640, LDA1, LDA1);
  attn_phase(2, A1a, A2a);

  // step 3 (last): out = query + hr
  gemm_fused<2><<<dim3(16, 32), blk, 0, stream>>>(
      A1a, B2, gates_baseP, cbuf, nullptr, nullptr, query, out, 640, LDA1, LDA1);
}